// Round 1
// baseline (4866.227 us; speedup 1.0000x reference)
//
#include <hip/hip_runtime.h>

#define LL 2
#define BB 2
#define SEQL 1024
#define DD 512
#define NN 16
#define HH 8
#define DHH 64
#define PPB 32
#define KCC 4
#define DTRR 32

__device__ __forceinline__ float siluf(float x) { return x / (1.f + expf(-x)); }
__device__ __forceinline__ float softplusf(float x) { return x > 20.f ? x : log1pf(expf(x)); }

// ---------------------------------------------------------------- GEMM (fp32)
// C[m,n] = sum_k A[m,k]*W[k,n] (+bias[n]) (act) (+resid[m,n])
// batched via blockIdx.z with per-operand strides; aflipL!=0 && z==1 flips A
// rows time-wise within groups of aflipL rows.
__global__ __launch_bounds__(256) void gemm_f32(
    const float* __restrict__ A, const float* __restrict__ W,
    const float* __restrict__ bias, const float* __restrict__ resid,
    float* __restrict__ C,
    int M, int N, int K, int lda, int ldc,
    long aBatch, long wBatch, long biasBatch, long cBatch,
    int aflipL, int act)
{
  int g = blockIdx.z;
  A += (long)g * aBatch;
  W += (long)g * wBatch;
  C += (long)g * cBatch;
  if (bias) bias += (long)g * biasBatch;
  const bool flip = (aflipL > 0) && (g == 1);

  __shared__ float As[64][17];
  __shared__ float Bs[16][65];
  int tid = threadIdx.x;
  int tx = tid & 15, ty = tid >> 4;
  int bm = blockIdx.y * 64, bn = blockIdx.x * 64;
  float acc[4][4] = {};

  for (int k0 = 0; k0 < K; k0 += 16) {
    int c = tid & 15, r0 = tid >> 4;
    #pragma unroll
    for (int rr = 0; rr < 4; rr++) {
      int m = bm + r0 + rr * 16;
      float v = 0.f;
      if (m < M) {
        int mm = m;
        if (flip) { int bb = m / aflipL; int t = m - bb * aflipL; mm = bb * aflipL + (aflipL - 1 - t); }
        v = A[(long)mm * lda + k0 + c];
      }
      As[r0 + rr * 16][c] = v;
    }
    int c2 = tid & 63, r2 = tid >> 6;
    #pragma unroll
    for (int rr = 0; rr < 4; rr++) {
      int kk = k0 + r2 + rr * 4;
      int n = bn + c2;
      Bs[r2 + rr * 4][c2] = (kk < K && n < N) ? W[(long)kk * N + n] : 0.f;
    }
    __syncthreads();
    #pragma unroll
    for (int kk = 0; kk < 16; kk++) {
      float a4[4], b4[4];
      #pragma unroll
      for (int i = 0; i < 4; i++) a4[i] = As[ty * 4 + i][kk];
      #pragma unroll
      for (int j = 0; j < 4; j++) b4[j] = Bs[kk][tx * 4 + j];
      #pragma unroll
      for (int i = 0; i < 4; i++)
        #pragma unroll
        for (int j = 0; j < 4; j++) acc[i][j] = fmaf(a4[i], b4[j], acc[i][j]);
    }
    __syncthreads();
  }
  #pragma unroll
  for (int i = 0; i < 4; i++) {
    int m = bm + ty * 4 + i;
    if (m >= M) continue;
    #pragma unroll
    for (int j = 0; j < 4; j++) {
      int n = bn + tx * 4 + j;
      if (n >= N) continue;
      float v = acc[i][j];
      if (bias) v += bias[n];
      if (act == 1) v = softplusf(v);
      if (resid) v += resid[(long)m * ldc + n];
      C[(long)m * ldc + n] = v;
    }
  }
}

// ---------------------------------------------------------------- RMS norm
__global__ __launch_bounds__(256) void rms_kernel(
    const float* __restrict__ x, const float* __restrict__ w, float* __restrict__ out)
{
  int row = blockIdx.x;
  const float* xr = x + (long)row * DD;
  int tid = threadIdx.x;
  float v0 = xr[tid], v1 = xr[tid + 256];
  float s = v0 * v0 + v1 * v1;
  for (int o = 32; o; o >>= 1) s += __shfl_down(s, o);
  __shared__ float sm[4];
  if ((tid & 63) == 0) sm[tid >> 6] = s;
  __syncthreads();
  float tot = sm[0] + sm[1] + sm[2] + sm[3];
  float inv = rsqrtf(tot / (float)DD + 1e-6f);
  out[(long)row * DD + tid] = v0 * inv * w[tid];
  out[(long)row * DD + tid + 256] = v1 * inv * w[tid + 256];
}

// ---------------------------------------------------------------- conv + SiLU
__global__ __launch_bounds__(256) void conv_silu_kernel(
    const float* __restrict__ xz, const float* __restrict__ cw, const float* __restrict__ cb,
    float* __restrict__ xc, int layer)
{
  long idx = (long)blockIdx.x * 256 + threadIdx.x;  // (g,b,t,c)
  int c = idx % DD;
  long r = idx / DD;           // (g*BB+b)*SEQL + t
  int t = r % SEQL;
  long gb = r / SEQL;
  int g = (int)(gb / BB);
  const float* w = cw + ((long)(layer * 2 + g) * DD + c) * KCC;
  float acc = cb[(long)(layer * 2 + g) * DD + c];
  const float* xp = xz + (r - t) * 2 * DD + c;   // start of this sequence, col c
  #pragma unroll
  for (int k = 0; k < KCC; k++) {
    int tt = t - (KCC - 1) + k;
    if (tt >= 0) acc = fmaf(xp[(long)tt * 2 * DD], w[k], acc);
  }
  xc[idx] = siluf(acc);
}

// ---------------------------------------------------------------- selective scan
// 4 lanes per (g,b,d) channel, 4 states each; fused z-gate epilogue.
__global__ __launch_bounds__(256) void scan_kernel(
    const float* __restrict__ dtv, const float* __restrict__ xc, const float* __restrict__ xz,
    const float* __restrict__ dbl, const float* __restrict__ Alog, const float* __restrict__ Dp,
    float* __restrict__ ym, int layer)
{
  int idx = blockIdx.x * 256 + threadIdx.x;   // 2*BB*DD*4 = 8192
  int ng = idx & 3;
  int ch = idx >> 2;          // (g*BB+b)*DD + d
  int d = ch % DD;
  int gb = ch / DD;           // g*BB + b
  int g = gb / BB;
  const float* Al = Alog + ((long)((layer * 2 + g) * DD) + d) * NN + ng * 4;
  float A[4];
  #pragma unroll
  for (int n = 0; n < 4; n++) A[n] = -expf(Al[n]);
  float Dpv = Dp[(long)(layer * 2 + g) * DD + d];
  float h[4] = {0.f, 0.f, 0.f, 0.f};
  long base = ((long)gb * SEQL) * DD + d;
  long zbase = ((long)gb * SEQL) * 2 * DD + DD + d;
  long dbase = ((long)gb * SEQL) * 64 + 32 + ng * 4;
  for (int t = 0; t < SEQL; t++) {
    float dtvv = dtv[base + (long)t * DD];
    float xcv = xc[base + (long)t * DD];
    const float* dr = dbl + dbase + (long)t * 64;
    float y = 0.f;
    #pragma unroll
    for (int n = 0; n < 4; n++) {
      float dA = expf(dtvv * A[n]);
      h[n] = fmaf(dA, h[n], dtvv * dr[n] * xcv);
      y = fmaf(h[n], dr[16 + n], y);
    }
    y += __shfl_xor(y, 1);
    y += __shfl_xor(y, 2);
    if (ng == 0) {
      float zv = xz[zbase + (long)t * 2 * DD];
      ym[base + (long)t * DD] = (y + Dpv * xcv) * siluf(zv);
    }
  }
}

// ---------------------------------------------------------------- dir combine
__global__ __launch_bounds__(256) void combine_kernel(
    const float* __restrict__ yp, const float* __restrict__ proj, float* __restrict__ yc)
{
  long idx = (long)blockIdx.x * 256 + threadIdx.x;  // (b,t,d)
  int d = idx % DD;
  long r = idx / DD;
  int t = r % SEQL;
  long b = r / SEQL;
  float y0 = yp[idx];
  float y1 = yp[(long)BB * SEQL * DD + (b * SEQL + (SEQL - 1 - t)) * (long)DD + d];
  const float* pr = proj + r * 3 * DD;
  float zf = pr[DD + d];
  float zr = pr[2 * DD + d];
  yc[idx] = y0 * siluf(zf) + y1 * siluf(zr);
}

// ---------------------------------------------------------------- attention prep
__global__ void n0_kernel(int* __restrict__ n0tab)
{
  int d = blockIdx.x * blockDim.x + threadIdx.x;
  if (d >= SEQL) return;
  float pr = expf(logf((SEQL + 1) * 0.5f) / 16.0f);
  int n0 = 16;
  for (int n = 15; n >= 0; n--) {
    float cw = powf(pr, (float)(n + 1));
    if ((float)d <= cw) n0 = n;
  }
  n0tab[d] = n0;
}

__global__ __launch_bounds__(64) void qw_suffix_kernel(
    const float* __restrict__ q, const float* __restrict__ w_rel, float* __restrict__ S, int layer)
{
  int idx = blockIdx.x;           // (b*HH + h)*SEQL + i
  int i = idx % SEQL;
  int bh = idx / SEQL;
  int h = bh % HH;
  int b = bh / HH;
  __shared__ float qs[64];
  __shared__ float qwn[32];
  int tid = threadIdx.x;
  qs[tid] = q[((long)(b * SEQL + i) * HH + h) * DHH + tid];
  __syncthreads();
  if (tid < 32) {
    const float* wp = w_rel + ((long)(layer * HH + h) * DHH) * PPB + tid;
    float s = 0.f;
    #pragma unroll 8
    for (int d = 0; d < DHH; d++) s = fmaf(qs[d], wp[d * PPB], s);
    qwn[tid] = s;
  }
  __syncthreads();
  if (tid < 17) {
    float s1 = 0.f, s2 = 0.f;
    for (int n = tid; n < 16; n++) { s1 += qwn[n]; s2 += qwn[16 + n]; }
    float* Sp = S + (long)idx * 34;
    Sp[tid] = s1;
    Sp[17 + tid] = s2;
  }
}

__global__ __launch_bounds__(256) void vw_kernel(
    const float* __restrict__ vparam, const float* __restrict__ w_rel, float* __restrict__ VS, int layer)
{
  __shared__ float vws[HH][PPB];
  int tid = threadIdx.x;
  int h = tid / PPB, n = tid % PPB;
  const float* vp = vparam + (long)(layer * HH + h) * DHH;
  const float* wp = w_rel + ((long)(layer * HH + h) * DHH) * PPB + n;
  float s = 0.f;
  for (int d = 0; d < DHH; d++) s = fmaf(vp[d], wp[d * PPB], s);
  vws[h][n] = s;
  __syncthreads();
  if (tid < HH * 17) {
    int hh = tid / 17, m = tid % 17;
    float s1 = 0.f, s2 = 0.f;
    for (int nn = m; nn < 16; nn++) { s1 += vws[hh][nn]; s2 += vws[hh][16 + nn]; }
    VS[hh * 34 + m] = s1;
    VS[hh * 34 + 17 + m] = s2;
  }
}

__global__ __launch_bounds__(256) void uk_kernel(
    const float* __restrict__ u, const float* __restrict__ k, float* __restrict__ uk, int layer)
{
  int wid = (blockIdx.x * 256 + threadIdx.x) >> 6;
  int lane = threadIdx.x & 63;
  if (wid >= BB * HH * SEQL) return;
  int j = wid % SEQL;
  int bh = wid / SEQL;
  int h = bh % HH;
  int b = bh / HH;
  float vv = u[(long)(layer * HH + h) * DHH + lane] * k[((long)(b * SEQL + j) * HH + h) * DHH + lane];
  for (int o = 32; o; o >>= 1) vv += __shfl_down(vv, o);
  if (lane == 0) uk[(long)bh * SEQL + j] = vv;
}

// ---------------------------------------------------------------- attention main
__global__ __launch_bounds__(256) void attn_kernel(
    const float* __restrict__ q, const float* __restrict__ k, const float* __restrict__ vv,
    const float* __restrict__ S, const float* __restrict__ VS, const float* __restrict__ uk,
    const int* __restrict__ n0tab, float* __restrict__ out)
{
  int idx = blockIdx.x;           // (b*HH + h)*SEQL + i
  int i = idx % SEQL;
  int bh = idx / SEQL;
  int h = bh % HH;
  int b = bh / HH;
  __shared__ float qs[64], sj[SEQL], S1q[34], VSl[34], red[4][64], rtmp[4];
  int tid = threadIdx.x;
  if (tid < 64) qs[tid] = q[((long)(b * SEQL + i) * HH + h) * DHH + tid];
  if (tid >= 64 && tid < 98) S1q[tid - 64] = S[(long)idx * 34 + tid - 64];
  if (tid >= 128 && tid < 162) VSl[tid - 128] = VS[h * 34 + tid - 128];
  __syncthreads();
  const float scale = 0.125f;
  const float* ukp = uk + (long)bh * SEQL;
  float lmax = -1e30f;
  #pragma unroll
  for (int r = 0; r < 4; r++) {
    int j = r * 256 + tid;
    const float* kr = k + ((long)(b * SEQL + j) * HH + h) * DHH;
    float dot = 0.f;
    #pragma unroll
    for (int d = 0; d < DHH; d += 4) {
      float4 kv = *(const float4*)(kr + d);
      dot += qs[d] * kv.x + qs[d + 1] * kv.y + qs[d + 2] * kv.z + qs[d + 3] * kv.w;
    }
    int di = j - i;
    int ad = di < 0 ? -di : di;
    float sg = di > 0 ? 1.f : (di < 0 ? -1.f : 0.f);
    int n0 = n0tab[ad];
    float biasv = S1q[n0] + sg * S1q[17 + n0] + VSl[n0] + sg * VSl[17 + n0] + ukp[j];
    float sv = (dot + biasv) * scale;
    sj[j] = sv;
    lmax = fmaxf(lmax, sv);
  }
  for (int o = 32; o; o >>= 1) lmax = fmaxf(lmax, __shfl_down(lmax, o));
  if ((tid & 63) == 0) rtmp[tid >> 6] = lmax;
  __syncthreads();
  float mx = fmaxf(fmaxf(rtmp[0], rtmp[1]), fmaxf(rtmp[2], rtmp[3]));
  float lsum = 0.f;
  #pragma unroll
  for (int r = 0; r < 4; r++) {
    int j = r * 256 + tid;
    float e = expf(sj[j] - mx);
    sj[j] = e;
    lsum += e;
  }
  for (int o = 32; o; o >>= 1) lsum += __shfl_down(lsum, o);
  __syncthreads();
  if ((tid & 63) == 0) rtmp[tid >> 6] = lsum;
  __syncthreads();
  float inv = 1.f / (rtmp[0] + rtmp[1] + rtmp[2] + rtmp[3]);
  int d = tid & 63, seg = tid >> 6;
  float acc = 0.f;
  const float* vbp = vv + ((long)(b * SEQL) * HH + h) * DHH + d;
  for (int jj = 0; jj < 256; jj++) {
    int j = seg * 256 + jj;
    acc = fmaf(sj[j], vbp[(long)j * HH * DHH], acc);
  }
  red[seg][d] = acc;
  __syncthreads();
  if (tid < 64) {
    float o = (red[0][tid] + red[1][tid] + red[2][tid] + red[3][tid]) * inv;
    out[((long)(b * SEQL + i) * HH + h) * DHH + tid] = o;
  }
}

// ---------------------------------------------------------------- launch
extern "C" void kernel_launch(void* const* d_in, const int* in_sizes, int n_in,
                              void* d_out, int out_size, void* d_ws, size_t ws_size,
                              hipStream_t stream) {
  const float* x_in     = (const float*)d_in[0];
  const float* rms_m    = (const float*)d_in[1];
  const float* W_in     = (const float*)d_in[2];
  const float* b_in     = (const float*)d_in[3];
  const float* m_Win    = (const float*)d_in[4];
  const float* m_conv_w = (const float*)d_in[5];
  const float* m_conv_b = (const float*)d_in[6];
  const float* m_Wx     = (const float*)d_in[7];
  const float* m_Wdt    = (const float*)d_in[8];
  const float* m_bdt    = (const float*)d_in[9];
  const float* m_Alog   = (const float*)d_in[10];
  const float* m_Dp     = (const float*)d_in[11];
  const float* m_Wout   = (const float*)d_in[12];
  const float* W_out    = (const float*)d_in[13];
  const float* b_out    = (const float*)d_in[14];
  const float* rms_a    = (const float*)d_in[15];
  const float* Wq       = (const float*)d_in[16];
  const float* Wk       = (const float*)d_in[17];
  const float* Wv       = (const float*)d_in[18];
  const float* u_p      = (const float*)d_in[19];
  const float* v_p      = (const float*)d_in[20];
  const float* w_rel    = (const float*)d_in[21];
  const float* Wo       = (const float*)d_in[22];
  const float* b_o      = (const float*)d_in[23];
  float* out = (float*)d_out;

  float* ws = (float*)d_ws;
  const long U = (long)BB * SEQL * DD;      // 1,048,576 floats
  float* xA    = ws;
  float* xB    = ws + 1 * U;
  float* xn    = ws + 2 * U;
  float* proj  = ws + 3 * U;                // 3U; later q,k,v
  float* xz    = ws + 6 * U;                // 4U; later yp (2U)
  float* xc    = ws + 10 * U;               // 2U
  float* dtv   = ws + 12 * U;               // 2U
  float* ym    = ws + 14 * U;               // 2U; later attnout
  float* ycomb = ws + 16 * U;               // 1U
  float* smallb= ws + 17 * U;               // 1U of small buffers
  float* dbl   = smallb;                    // 2*BB*SEQL*64 = 262144
  float* ukbuf = smallb + 262144;           // 16384
  float* Sbuf  = smallb + 278528;           // 557056
  float* VSbuf = smallb + 835584;           // 272
  int*   n0tab = (int*)(smallb + 835856);   // 1024
  float* yp = xz;
  float* qb = proj;
  float* kb = proj + U;
  float* vb = proj + 2 * U;
  float* attnout = ym;

  const int M = BB * SEQL;                  // 2048

  n0_kernel<<<4, 256, 0, stream>>>(n0tab);

  for (int layer = 0; layer < LL; layer++) {
    const float* cur = (layer == 0) ? x_in : xA;
    // ---- mamba block ----
    rms_kernel<<<M, 256, 0, stream>>>(cur, rms_m + layer * DD, xn);
    gemm_f32<<<dim3(24, 32, 1), 256, 0, stream>>>(xn, W_in + (long)layer * DD * 3 * DD,
        b_in + layer * 3 * DD, nullptr, proj, M, 3 * DD, DD, DD, 3 * DD, 0, 0, 0, 0, 0, 0);
    gemm_f32<<<dim3(16, 32, 2), 256, 0, stream>>>(proj, m_Win + (long)layer * 2 * DD * 2 * DD,
        nullptr, nullptr, xz, M, 2 * DD, DD, 3 * DD, 2 * DD,
        0, (long)DD * 2 * DD, 0, (long)BB * SEQL * 2 * DD, SEQL, 0);
    conv_silu_kernel<<<(2 * BB * SEQL * DD) / 256, 256, 0, stream>>>(xz, m_conv_w, m_conv_b, xc, layer);
    gemm_f32<<<dim3(1, 32, 2), 256, 0, stream>>>(xc, m_Wx + (long)layer * 2 * DD * 64,
        nullptr, nullptr, dbl, M, 64, DD, DD, 64,
        U, (long)DD * 64, 0, (long)BB * SEQL * 64, 0, 0);
    gemm_f32<<<dim3(8, 32, 2), 256, 0, stream>>>(dbl, m_Wdt + (long)layer * 2 * DTRR * DD,
        m_bdt + (long)layer * 2 * DD, nullptr, dtv, M, DD, DTRR, 64, DD,
        (long)BB * SEQL * 64, (long)DTRR * DD, DD, U, 0, 1);
    scan_kernel<<<(2 * BB * DD * 4) / 256, 256, 0, stream>>>(dtv, xc, xz, dbl, m_Alog, m_Dp, ym, layer);
    gemm_f32<<<dim3(8, 32, 2), 256, 0, stream>>>(ym, m_Wout + (long)layer * 2 * DD * DD,
        nullptr, nullptr, yp, M, DD, DD, DD, DD, U, (long)DD * DD, 0, U, 0, 0);
    combine_kernel<<<(int)(U / 256), 256, 0, stream>>>(yp, proj, ycomb);
    gemm_f32<<<dim3(8, 32, 1), 256, 0, stream>>>(ycomb, W_out + (long)layer * DD * DD,
        b_out + layer * DD, cur, xB, M, DD, DD, DD, DD, 0, 0, 0, 0, 0, 0);
    // ---- attention block ----
    rms_kernel<<<M, 256, 0, stream>>>(xB, rms_a + layer * DD, xn);
    gemm_f32<<<dim3(8, 32, 1), 256, 0, stream>>>(xn, Wq + (long)layer * DD * HH * DHH,
        nullptr, nullptr, qb, M, DD, DD, DD, DD, 0, 0, 0, 0, 0, 0);
    gemm_f32<<<dim3(8, 32, 1), 256, 0, stream>>>(xn, Wk + (long)layer * DD * HH * DHH,
        nullptr, nullptr, kb, M, DD, DD, DD, DD, 0, 0, 0, 0, 0, 0);
    gemm_f32<<<dim3(8, 32, 1), 256, 0, stream>>>(xn, Wv + (long)layer * DD * HH * DHH,
        nullptr, nullptr, vb, M, DD, DD, DD, DD, 0, 0, 0, 0, 0, 0);
    qw_suffix_kernel<<<BB * HH * SEQL, 64, 0, stream>>>(qb, w_rel, Sbuf, layer);
    vw_kernel<<<1, 256, 0, stream>>>(v_p, w_rel, VSbuf, layer);
    uk_kernel<<<(BB * HH * SEQL) / 4, 256, 0, stream>>>(u_p, kb, ukbuf, layer);
    attn_kernel<<<BB * HH * SEQL, 256, 0, stream>>>(qb, kb, vb, Sbuf, VSbuf, ukbuf, n0tab, attnout);
    float* outp = (layer == LL - 1) ? out : xA;
    gemm_f32<<<dim3(8, 32, 1), 256, 0, stream>>>(attnout, Wo + (long)layer * HH * DHH * DD,
        b_o + layer * DD, xB, outp, M, DD, DD, DD, DD, 0, 0, 0, 0, 0, 0);
  }
}

// Round 2
// 3145.964 us; speedup vs baseline: 1.5468x; 1.5468x over previous
//
#include <hip/hip_runtime.h>

#define LL 2
#define BB 2
#define SEQL 1024
#define DD 512
#define NN 16
#define HH 8
#define DHH 64
#define PPB 32
#define KCC 4
#define DTRR 32

#define GBS 4              // g*BB+b combinations
#define TC 64              // scan chunk length
#define NC (SEQL / TC)     // 16 chunks
#define NR (GBS * DD * NN) // 32768 recurrences

__device__ __forceinline__ float siluf(float x) { return x / (1.f + expf(-x)); }
__device__ __forceinline__ float softplusf(float x) { return x > 20.f ? x : log1pf(expf(x)); }

// ---------------------------------------------------------------- GEMM (fp32)
__global__ __launch_bounds__(256) void gemm_f32(
    const float* __restrict__ A, const float* __restrict__ W,
    const float* __restrict__ bias, const float* __restrict__ resid,
    float* __restrict__ C,
    int M, int N, int K, int lda, int ldc,
    long aBatch, long wBatch, long biasBatch, long cBatch,
    int aflipL, int act)
{
  int g = blockIdx.z;
  A += (long)g * aBatch;
  W += (long)g * wBatch;
  C += (long)g * cBatch;
  if (bias) bias += (long)g * biasBatch;
  const bool flip = (aflipL > 0) && (g == 1);

  __shared__ float As[64][17];
  __shared__ float Bs[16][65];
  int tid = threadIdx.x;
  int tx = tid & 15, ty = tid >> 4;
  int bm = blockIdx.y * 64, bn = blockIdx.x * 64;
  float acc[4][4] = {};

  for (int k0 = 0; k0 < K; k0 += 16) {
    int c = tid & 15, r0 = tid >> 4;
    #pragma unroll
    for (int rr = 0; rr < 4; rr++) {
      int m = bm + r0 + rr * 16;
      float v = 0.f;
      if (m < M) {
        int mm = m;
        if (flip) { int bb = m / aflipL; int t = m - bb * aflipL; mm = bb * aflipL + (aflipL - 1 - t); }
        v = A[(long)mm * lda + k0 + c];
      }
      As[r0 + rr * 16][c] = v;
    }
    int c2 = tid & 63, r2 = tid >> 6;
    #pragma unroll
    for (int rr = 0; rr < 4; rr++) {
      int kk = k0 + r2 + rr * 4;
      int n = bn + c2;
      Bs[r2 + rr * 4][c2] = (kk < K && n < N) ? W[(long)kk * N + n] : 0.f;
    }
    __syncthreads();
    #pragma unroll
    for (int kk = 0; kk < 16; kk++) {
      float a4[4], b4[4];
      #pragma unroll
      for (int i = 0; i < 4; i++) a4[i] = As[ty * 4 + i][kk];
      #pragma unroll
      for (int j = 0; j < 4; j++) b4[j] = Bs[kk][tx * 4 + j];
      #pragma unroll
      for (int i = 0; i < 4; i++)
        #pragma unroll
        for (int j = 0; j < 4; j++) acc[i][j] = fmaf(a4[i], b4[j], acc[i][j]);
    }
    __syncthreads();
  }
  #pragma unroll
  for (int i = 0; i < 4; i++) {
    int m = bm + ty * 4 + i;
    if (m >= M) continue;
    #pragma unroll
    for (int j = 0; j < 4; j++) {
      int n = bn + tx * 4 + j;
      if (n >= N) continue;
      float v = acc[i][j];
      if (bias) v += bias[n];
      if (act == 1) v = softplusf(v);
      if (resid) v += resid[(long)m * ldc + n];
      C[(long)m * ldc + n] = v;
    }
  }
}

// ---------------------------------------------------------------- RMS norm
__global__ __launch_bounds__(256) void rms_kernel(
    const float* __restrict__ x, const float* __restrict__ w, float* __restrict__ out)
{
  int row = blockIdx.x;
  const float* xr = x + (long)row * DD;
  int tid = threadIdx.x;
  float v0 = xr[tid], v1 = xr[tid + 256];
  float s = v0 * v0 + v1 * v1;
  for (int o = 32; o; o >>= 1) s += __shfl_down(s, o);
  __shared__ float sm[4];
  if ((tid & 63) == 0) sm[tid >> 6] = s;
  __syncthreads();
  float tot = sm[0] + sm[1] + sm[2] + sm[3];
  float inv = rsqrtf(tot / (float)DD + 1e-6f);
  out[(long)row * DD + tid] = v0 * inv * w[tid];
  out[(long)row * DD + tid + 256] = v1 * inv * w[tid + 256];
}

// ---------------------------------------------------------------- conv + SiLU
__global__ __launch_bounds__(256) void conv_silu_kernel(
    const float* __restrict__ xz, const float* __restrict__ cw, const float* __restrict__ cb,
    float* __restrict__ xc, int layer)
{
  long idx = (long)blockIdx.x * 256 + threadIdx.x;  // (g,b,t,c)
  int c = idx % DD;
  long r = idx / DD;           // (g*BB+b)*SEQL + t
  int t = r % SEQL;
  long gb = r / SEQL;
  int g = (int)(gb / BB);
  const float* w = cw + ((long)(layer * 2 + g) * DD + c) * KCC;
  float acc = cb[(long)(layer * 2 + g) * DD + c];
  const float* xp = xz + (r - t) * 2 * DD + c;
  #pragma unroll
  for (int k = 0; k < KCC; k++) {
    int tt = t - (KCC - 1) + k;
    if (tt >= 0) acc = fmaf(xp[(long)tt * 2 * DD], w[k], acc);
  }
  xc[idx] = siluf(acc);
}

// ---------------------------------------------------------------- chunked scan
// Phase 1: per-chunk local walk from h=0; emit P = prod(dA) = exp(a*sum(dt))
// and Hend. Block = 16 d x 16 n for one (gb, chunk, dtile).
__global__ __launch_bounds__(256) void scan_chunk_kernel(
    const float* __restrict__ dtv, const float* __restrict__ xc,
    const float* __restrict__ dbl, const float* __restrict__ Alog,
    float* __restrict__ P, float* __restrict__ Hend, int layer)
{
  int chunk = blockIdx.x, dtile = blockIdx.y, gb = blockIdx.z;
  int g = gb / BB;
  int tid = threadIdx.x;
  int n = tid & 15, dl = tid >> 4;
  int d = dtile * 16 + dl;
  int t0 = chunk * TC;
  __shared__ float dtv_s[TC][16], xc_s[TC][16], B_s[TC][17];
  {
    int c = tid & 15, rr = tid >> 4;
    long base = ((long)gb * SEQL + t0) * DD + dtile * 16;
    long dbase = ((long)gb * SEQL + t0) * 64 + 32;
    #pragma unroll
    for (int i = 0; i < 4; i++) {
      int tl = rr + i * 16;
      dtv_s[tl][c] = dtv[base + (long)tl * DD + c];
      xc_s[tl][c]  = xc[base + (long)tl * DD + c];
      B_s[tl][c]   = dbl[dbase + (long)tl * 64 + c];
    }
  }
  __syncthreads();
  float a = -expf(Alog[((long)((layer * 2 + g) * DD) + d) * NN + n]);
  float h = 0.f, sdt = 0.f;
  #pragma unroll 4
  for (int t = 0; t < TC; t++) {
    float dt = dtv_s[t][dl];
    float dA = expf(dt * a);
    h = fmaf(dA, h, dt * B_s[t][n] * xc_s[t][dl]);
    sdt += dt;
  }
  int r = (gb * DD + d) * NN + n;
  long o = (long)chunk * NR + r;
  P[o] = expf(a * sdt);
  Hend[o] = h;
}

// Phase 2: serial combine over the 16 chunk summaries per recurrence.
__global__ __launch_bounds__(256) void scan_combine_kernel(
    const float* __restrict__ P, const float* __restrict__ Hend, float* __restrict__ Hin)
{
  int r = blockIdx.x * 256 + threadIdx.x;
  float h = 0.f;
  #pragma unroll
  for (int c = 0; c < NC; c++) {
    Hin[(long)c * NR + r] = h;
    h = fmaf(P[(long)c * NR + r], h, Hend[(long)c * NR + r]);
  }
}

// Phase 3: re-walk with correct h_in, reduce over n, fused gate epilogue.
__global__ __launch_bounds__(256) void scan_apply_kernel(
    const float* __restrict__ dtv, const float* __restrict__ xc, const float* __restrict__ xz,
    const float* __restrict__ dbl, const float* __restrict__ Alog, const float* __restrict__ Dp,
    const float* __restrict__ Hin, float* __restrict__ ym, int layer)
{
  int chunk = blockIdx.x, dtile = blockIdx.y, gb = blockIdx.z;
  int g = gb / BB;
  int tid = threadIdx.x;
  int n = tid & 15, dl = tid >> 4;
  int d = dtile * 16 + dl;
  int t0 = chunk * TC;
  __shared__ float dtv_s[TC][16], xc_s[TC][16], B_s[TC][17], C_s[TC][17], y_s[TC][16];
  {
    int c = tid & 15, rr = tid >> 4;
    long base = ((long)gb * SEQL + t0) * DD + dtile * 16;
    long dbase = ((long)gb * SEQL + t0) * 64 + 32;
    #pragma unroll
    for (int i = 0; i < 4; i++) {
      int tl = rr + i * 16;
      dtv_s[tl][c] = dtv[base + (long)tl * DD + c];
      xc_s[tl][c]  = xc[base + (long)tl * DD + c];
      B_s[tl][c]   = dbl[dbase + (long)tl * 64 + c];
      C_s[tl][c]   = dbl[dbase + (long)tl * 64 + 16 + c];
    }
  }
  __syncthreads();
  float a = -expf(Alog[((long)((layer * 2 + g) * DD) + d) * NN + n]);
  int r = (gb * DD + d) * NN + n;
  float h = Hin[(long)chunk * NR + r];
  #pragma unroll 4
  for (int t = 0; t < TC; t++) {
    float dt = dtv_s[t][dl];
    float dA = expf(dt * a);
    h = fmaf(dA, h, dt * B_s[t][n] * xc_s[t][dl]);
    float val = h * C_s[t][n];
    val += __shfl_xor(val, 1);
    val += __shfl_xor(val, 2);
    val += __shfl_xor(val, 4);
    val += __shfl_xor(val, 8);
    if (n == 0) y_s[t][dl] = val;
  }
  __syncthreads();
  {
    int c = tid & 15, rr = tid >> 4;
    long base = ((long)gb * SEQL + t0) * DD + dtile * 16;
    long zbase = ((long)gb * SEQL + t0) * 2 * DD + DD + dtile * 16;
    float Dpc = Dp[(long)(layer * 2 + g) * DD + dtile * 16 + c];
    #pragma unroll
    for (int i = 0; i < 4; i++) {
      int tl = rr + i * 16;
      float z = xz[zbase + (long)tl * 2 * DD + c];
      ym[base + (long)tl * DD + c] = (y_s[tl][c] + Dpc * xc_s[tl][c]) * siluf(z);
    }
  }
}

// ---------------------------------------------------------------- dir combine
__global__ __launch_bounds__(256) void combine_kernel(
    const float* __restrict__ yp, const float* __restrict__ proj, float* __restrict__ yc)
{
  long idx = (long)blockIdx.x * 256 + threadIdx.x;  // (b,t,d)
  int d = idx % DD;
  long r = idx / DD;
  int t = r % SEQL;
  long b = r / SEQL;
  float y0 = yp[idx];
  float y1 = yp[(long)BB * SEQL * DD + (b * SEQL + (SEQL - 1 - t)) * (long)DD + d];
  const float* pr = proj + r * 3 * DD;
  float zf = pr[DD + d];
  float zr = pr[2 * DD + d];
  yc[idx] = y0 * siluf(zf) + y1 * siluf(zr);
}

// ---------------------------------------------------------------- attention prep
__global__ void n0_kernel(int* __restrict__ n0tab)
{
  int d = blockIdx.x * blockDim.x + threadIdx.x;
  if (d >= SEQL) return;
  float pr = expf(logf((SEQL + 1) * 0.5f) / 16.0f);
  int n0 = 16;
  for (int n = 15; n >= 0; n--) {
    float cw = powf(pr, (float)(n + 1));
    if ((float)d <= cw) n0 = n;
  }
  n0tab[d] = n0;
}

__global__ __launch_bounds__(64) void qw_suffix_kernel(
    const float* __restrict__ q, const float* __restrict__ w_rel, float* __restrict__ S, int layer)
{
  int idx = blockIdx.x;           // (b*HH + h)*SEQL + i
  int i = idx % SEQL;
  int bh = idx / SEQL;
  int h = bh % HH;
  int b = bh / HH;
  __shared__ float qs[64];
  __shared__ float qwn[32];
  int tid = threadIdx.x;
  qs[tid] = q[((long)(b * SEQL + i) * HH + h) * DHH + tid];
  __syncthreads();
  if (tid < 32) {
    const float* wp = w_rel + ((long)(layer * HH + h) * DHH) * PPB + tid;
    float s = 0.f;
    #pragma unroll 8
    for (int d = 0; d < DHH; d++) s = fmaf(qs[d], wp[d * PPB], s);
    qwn[tid] = s;
  }
  __syncthreads();
  if (tid < 17) {
    float s1 = 0.f, s2 = 0.f;
    for (int n = tid; n < 16; n++) { s1 += qwn[n]; s2 += qwn[16 + n]; }
    float* Sp = S + (long)idx * 34;
    Sp[tid] = s1;
    Sp[17 + tid] = s2;
  }
}

__global__ __launch_bounds__(256) void vw_kernel(
    const float* __restrict__ vparam, const float* __restrict__ w_rel, float* __restrict__ VS, int layer)
{
  __shared__ float vws[HH][PPB];
  int tid = threadIdx.x;
  int h = tid / PPB, n = tid % PPB;
  const float* vp = vparam + (long)(layer * HH + h) * DHH;
  const float* wp = w_rel + ((long)(layer * HH + h) * DHH) * PPB + n;
  float s = 0.f;
  for (int d = 0; d < DHH; d++) s = fmaf(vp[d], wp[d * PPB], s);
  vws[h][n] = s;
  __syncthreads();
  if (tid < HH * 17) {
    int hh = tid / 17, m = tid % 17;
    float s1 = 0.f, s2 = 0.f;
    for (int nn = m; nn < 16; nn++) { s1 += vws[hh][nn]; s2 += vws[hh][16 + nn]; }
    VS[hh * 34 + m] = s1;
    VS[hh * 34 + 17 + m] = s2;
  }
}

__global__ __launch_bounds__(256) void uk_kernel(
    const float* __restrict__ u, const float* __restrict__ k, float* __restrict__ uk, int layer)
{
  int wid = (blockIdx.x * 256 + threadIdx.x) >> 6;
  int lane = threadIdx.x & 63;
  if (wid >= BB * HH * SEQL) return;
  int j = wid % SEQL;
  int bh = wid / SEQL;
  int h = bh % HH;
  int b = bh / HH;
  float vv = u[(long)(layer * HH + h) * DHH + lane] * k[((long)(b * SEQL + j) * HH + h) * DHH + lane];
  for (int o = 32; o; o >>= 1) vv += __shfl_down(vv, o);
  if (lane == 0) uk[(long)bh * SEQL + j] = vv;
}

// ---------------------------------------------------------------- attention main
__global__ __launch_bounds__(256) void attn_kernel(
    const float* __restrict__ q, const float* __restrict__ k, const float* __restrict__ vv,
    const float* __restrict__ S, const float* __restrict__ VS, const float* __restrict__ uk,
    const int* __restrict__ n0tab, float* __restrict__ out)
{
  int idx = blockIdx.x;           // (b*HH + h)*SEQL + i
  int i = idx % SEQL;
  int bh = idx / SEQL;
  int h = bh % HH;
  int b = bh / HH;
  __shared__ float qs[64], sj[SEQL], S1q[34], VSl[34], red[4][64], rtmp[4];
  int tid = threadIdx.x;
  if (tid < 64) qs[tid] = q[((long)(b * SEQL + i) * HH + h) * DHH + tid];
  if (tid >= 64 && tid < 98) S1q[tid - 64] = S[(long)idx * 34 + tid - 64];
  if (tid >= 128 && tid < 162) VSl[tid - 128] = VS[h * 34 + tid - 128];
  __syncthreads();
  const float scale = 0.125f;
  const float* ukp = uk + (long)bh * SEQL;
  float lmax = -1e30f;
  #pragma unroll
  for (int r = 0; r < 4; r++) {
    int j = r * 256 + tid;
    const float* kr = k + ((long)(b * SEQL + j) * HH + h) * DHH;
    float dot = 0.f;
    #pragma unroll
    for (int d = 0; d < DHH; d += 4) {
      float4 kv = *(const float4*)(kr + d);
      dot += qs[d] * kv.x + qs[d + 1] * kv.y + qs[d + 2] * kv.z + qs[d + 3] * kv.w;
    }
    int di = j - i;
    int ad = di < 0 ? -di : di;
    float sg = di > 0 ? 1.f : (di < 0 ? -1.f : 0.f);
    int n0 = n0tab[ad];
    float biasv = S1q[n0] + sg * S1q[17 + n0] + VSl[n0] + sg * VSl[17 + n0] + ukp[j];
    float sv = (dot + biasv) * scale;
    sj[j] = sv;
    lmax = fmaxf(lmax, sv);
  }
  for (int o = 32; o; o >>= 1) lmax = fmaxf(lmax, __shfl_down(lmax, o));
  if ((tid & 63) == 0) rtmp[tid >> 6] = lmax;
  __syncthreads();
  float mx = fmaxf(fmaxf(rtmp[0], rtmp[1]), fmaxf(rtmp[2], rtmp[3]));
  float lsum = 0.f;
  #pragma unroll
  for (int r = 0; r < 4; r++) {
    int j = r * 256 + tid;
    float e = expf(sj[j] - mx);
    sj[j] = e;
    lsum += e;
  }
  for (int o = 32; o; o >>= 1) lsum += __shfl_down(lsum, o);
  __syncthreads();
  if ((tid & 63) == 0) rtmp[tid >> 6] = lsum;
  __syncthreads();
  float inv = 1.f / (rtmp[0] + rtmp[1] + rtmp[2] + rtmp[3]);
  int d = tid & 63, seg = tid >> 6;
  float acc = 0.f;
  const float* vbp = vv + ((long)(b * SEQL) * HH + h) * DHH + d;
  for (int jj = 0; jj < 256; jj++) {
    int j = seg * 256 + jj;
    acc = fmaf(sj[j], vbp[(long)j * HH * DHH], acc);
  }
  red[seg][d] = acc;
  __syncthreads();
  if (tid < 64) {
    float o = (red[0][tid] + red[1][tid] + red[2][tid] + red[3][tid]) * inv;
    out[((long)(b * SEQL + i) * HH + h) * DHH + tid] = o;
  }
}

// ---------------------------------------------------------------- launch
extern "C" void kernel_launch(void* const* d_in, const int* in_sizes, int n_in,
                              void* d_out, int out_size, void* d_ws, size_t ws_size,
                              hipStream_t stream) {
  const float* x_in     = (const float*)d_in[0];
  const float* rms_m    = (const float*)d_in[1];
  const float* W_in     = (const float*)d_in[2];
  const float* b_in     = (const float*)d_in[3];
  const float* m_Win    = (const float*)d_in[4];
  const float* m_conv_w = (const float*)d_in[5];
  const float* m_conv_b = (const float*)d_in[6];
  const float* m_Wx     = (const float*)d_in[7];
  const float* m_Wdt    = (const float*)d_in[8];
  const float* m_bdt    = (const float*)d_in[9];
  const float* m_Alog   = (const float*)d_in[10];
  const float* m_Dp     = (const float*)d_in[11];
  const float* m_Wout   = (const float*)d_in[12];
  const float* W_out    = (const float*)d_in[13];
  const float* b_out    = (const float*)d_in[14];
  const float* rms_a    = (const float*)d_in[15];
  const float* Wq       = (const float*)d_in[16];
  const float* Wk       = (const float*)d_in[17];
  const float* Wv       = (const float*)d_in[18];
  const float* u_p      = (const float*)d_in[19];
  const float* v_p      = (const float*)d_in[20];
  const float* w_rel    = (const float*)d_in[21];
  const float* Wo       = (const float*)d_in[22];
  const float* b_o      = (const float*)d_in[23];
  float* out = (float*)d_out;

  float* ws = (float*)d_ws;
  const long U = (long)BB * SEQL * DD;      // 1,048,576 floats
  float* xA    = ws;
  float* xB    = ws + 1 * U;
  float* xn    = ws + 2 * U;                // also scan P/Hend scratch
  float* proj  = ws + 3 * U;                // 3U; later q,k,v
  float* xz    = ws + 6 * U;                // 4U; later yp (2U)
  float* xc    = ws + 10 * U;               // 2U
  float* dtv   = ws + 12 * U;               // 2U
  float* ym    = ws + 14 * U;               // 2U; later attnout
  float* ycomb = ws + 16 * U;               // 1U; also scan Hin scratch
  float* smallb= ws + 17 * U;               // 1U of small buffers
  float* dbl   = smallb;                    // 2*BB*SEQL*64 = 262144
  float* ukbuf = smallb + 262144;           // 16384
  float* Sbuf  = smallb + 278528;           // 557056
  float* VSbuf = smallb + 835584;           // 272
  int*   n0tab = (int*)(smallb + 835856);   // 1024
  float* yp = xz;
  float* qb = proj;
  float* kb = proj + U;
  float* vb = proj + 2 * U;
  float* attnout = ym;
  float* Pbuf = xn;                         // NC*NR = 524288
  float* Hend = xn + (long)NC * NR;         // 524288 (xn = 1U total: exact fit)
  float* Hin  = ycomb;                      // 524288 <= 1U

  const int M = BB * SEQL;                  // 2048

  n0_kernel<<<4, 256, 0, stream>>>(n0tab);

  for (int layer = 0; layer < LL; layer++) {
    const float* cur = (layer == 0) ? x_in : xA;
    // ---- mamba block ----
    rms_kernel<<<M, 256, 0, stream>>>(cur, rms_m + layer * DD, xn);
    gemm_f32<<<dim3(24, 32, 1), 256, 0, stream>>>(xn, W_in + (long)layer * DD * 3 * DD,
        b_in + layer * 3 * DD, nullptr, proj, M, 3 * DD, DD, DD, 3 * DD, 0, 0, 0, 0, 0, 0);
    gemm_f32<<<dim3(16, 32, 2), 256, 0, stream>>>(proj, m_Win + (long)layer * 2 * DD * 2 * DD,
        nullptr, nullptr, xz, M, 2 * DD, DD, 3 * DD, 2 * DD,
        0, (long)DD * 2 * DD, 0, (long)BB * SEQL * 2 * DD, SEQL, 0);
    conv_silu_kernel<<<(2 * BB * SEQL * DD) / 256, 256, 0, stream>>>(xz, m_conv_w, m_conv_b, xc, layer);
    gemm_f32<<<dim3(1, 32, 2), 256, 0, stream>>>(xc, m_Wx + (long)layer * 2 * DD * 64,
        nullptr, nullptr, dbl, M, 64, DD, DD, 64,
        U, (long)DD * 64, 0, (long)BB * SEQL * 64, 0, 0);
    gemm_f32<<<dim3(8, 32, 2), 256, 0, stream>>>(dbl, m_Wdt + (long)layer * 2 * DTRR * DD,
        m_bdt + (long)layer * 2 * DD, nullptr, dtv, M, DD, DTRR, 64, DD,
        (long)BB * SEQL * 64, (long)DTRR * DD, DD, U, 0, 1);
    scan_chunk_kernel<<<dim3(NC, DD / 16, GBS), 256, 0, stream>>>(
        dtv, xc, dbl, m_Alog, Pbuf, Hend, layer);
    scan_combine_kernel<<<NR / 256, 256, 0, stream>>>(Pbuf, Hend, Hin);
    scan_apply_kernel<<<dim3(NC, DD / 16, GBS), 256, 0, stream>>>(
        dtv, xc, xz, dbl, m_Alog, m_Dp, Hin, ym, layer);
    gemm_f32<<<dim3(8, 32, 2), 256, 0, stream>>>(ym, m_Wout + (long)layer * 2 * DD * DD,
        nullptr, nullptr, yp, M, DD, DD, DD, DD, U, (long)DD * DD, 0, U, 0, 0);
    combine_kernel<<<(int)(U / 256), 256, 0, stream>>>(yp, proj, ycomb);
    gemm_f32<<<dim3(8, 32, 1), 256, 0, stream>>>(ycomb, W_out + (long)layer * DD * DD,
        b_out + layer * DD, cur, xB, M, DD, DD, DD, DD, 0, 0, 0, 0, 0, 0);
    // ---- attention block ----
    rms_kernel<<<M, 256, 0, stream>>>(xB, rms_a + layer * DD, xn);
    gemm_f32<<<dim3(8, 32, 1), 256, 0, stream>>>(xn, Wq + (long)layer * DD * HH * DHH,
        nullptr, nullptr, qb, M, DD, DD, DD, DD, 0, 0, 0, 0, 0, 0);
    gemm_f32<<<dim3(8, 32, 1), 256, 0, stream>>>(xn, Wk + (long)layer * DD * HH * DHH,
        nullptr, nullptr, kb, M, DD, DD, DD, DD, 0, 0, 0, 0, 0, 0);
    gemm_f32<<<dim3(8, 32, 1), 256, 0, stream>>>(xn, Wv + (long)layer * DD * HH * DHH,
        nullptr, nullptr, vb, M, DD, DD, DD, DD, 0, 0, 0, 0, 0, 0);
    qw_suffix_kernel<<<BB * HH * SEQL, 64, 0, stream>>>(qb, w_rel, Sbuf, layer);
    vw_kernel<<<1, 256, 0, stream>>>(v_p, w_rel, VSbuf, layer);
    uk_kernel<<<(BB * HH * SEQL) / 4, 256, 0, stream>>>(u_p, kb, ukbuf, layer);
    attn_kernel<<<BB * HH * SEQL, 256, 0, stream>>>(qb, kb, vb, Sbuf, VSbuf, ukbuf, n0tab, attnout);
    float* outp = (layer == LL - 1) ? out : xA;
    gemm_f32<<<dim3(8, 32, 1), 256, 0, stream>>>(attnout, Wo + (long)layer * HH * DHH * DD,
        b_o + layer * DD, xB, outp, M, DD, DD, DD, DD, 0, 0, 0, 0, 0, 0);
  }
}

// Round 3
// 1880.556 us; speedup vs baseline: 2.5877x; 1.6729x over previous
//
#include <hip/hip_runtime.h>

#define LL 2
#define BB 2
#define SEQL 1024
#define DD 512
#define NN 16
#define HH 8
#define DHH 64
#define PPB 32
#define KCC 4
#define DTRR 32

#define GBS 4              // g*BB+b combinations
#define TC 64              // scan chunk length
#define NC (SEQL / TC)     // 16 chunks
#define NR (GBS * DD * NN) // 32768 recurrences

typedef __attribute__((ext_vector_type(8))) short bf16x8;
typedef __attribute__((ext_vector_type(4))) short short4v;
typedef __attribute__((ext_vector_type(4))) float f32x4;

__device__ __forceinline__ float siluf(float x) { return x / (1.f + expf(-x)); }
__device__ __forceinline__ float softplusf(float x) { return x > 20.f ? x : log1pf(expf(x)); }

__device__ __forceinline__ unsigned short f2bf(float x) {
  union { float f; unsigned u; } v; v.f = x;
  unsigned r = v.u + 0x7fff + ((v.u >> 16) & 1);
  return (unsigned short)(r >> 16);
}

// read 8 contiguous bf16 (as shorts) via two 8B loads (rows padded to 68 shorts)
__device__ __forceinline__ bf16x8 ld_frag(const unsigned short* p) {
  short4v a = *(const short4v*)(p);
  short4v b = *(const short4v*)(p + 4);
  bf16x8 r;
  r[0]=a[0]; r[1]=a[1]; r[2]=a[2]; r[3]=a[3];
  r[4]=b[0]; r[5]=b[1]; r[6]=b[2]; r[7]=b[3];
  return r;
}

__device__ __forceinline__ bf16x8 pack8(const float* p) {
  bf16x8 r;
  #pragma unroll
  for (int e = 0; e < 8; e++) r[e] = (short)f2bf(p[e]);
  return r;
}

// ---------------------------------------------------------------- GEMM (fp32)
__global__ __launch_bounds__(256) void gemm_f32(
    const float* __restrict__ A, const float* __restrict__ W,
    const float* __restrict__ bias, const float* __restrict__ resid,
    float* __restrict__ C,
    int M, int N, int K, int lda, int ldc,
    long aBatch, long wBatch, long biasBatch, long cBatch,
    int aflipL, int act)
{
  int g = blockIdx.z;
  A += (long)g * aBatch;
  W += (long)g * wBatch;
  C += (long)g * cBatch;
  if (bias) bias += (long)g * biasBatch;
  const bool flip = (aflipL > 0) && (g == 1);

  __shared__ float As[64][17];
  __shared__ float Bs[16][65];
  int tid = threadIdx.x;
  int tx = tid & 15, ty = tid >> 4;
  int bm = blockIdx.y * 64, bn = blockIdx.x * 64;
  float acc[4][4] = {};

  for (int k0 = 0; k0 < K; k0 += 16) {
    int c = tid & 15, r0 = tid >> 4;
    #pragma unroll
    for (int rr = 0; rr < 4; rr++) {
      int m = bm + r0 + rr * 16;
      float v = 0.f;
      if (m < M) {
        int mm = m;
        if (flip) { int bb = m / aflipL; int t = m - bb * aflipL; mm = bb * aflipL + (aflipL - 1 - t); }
        v = A[(long)mm * lda + k0 + c];
      }
      As[r0 + rr * 16][c] = v;
    }
    int c2 = tid & 63, r2 = tid >> 6;
    #pragma unroll
    for (int rr = 0; rr < 4; rr++) {
      int kk = k0 + r2 + rr * 4;
      int n = bn + c2;
      Bs[r2 + rr * 4][c2] = (kk < K && n < N) ? W[(long)kk * N + n] : 0.f;
    }
    __syncthreads();
    #pragma unroll
    for (int kk = 0; kk < 16; kk++) {
      float a4[4], b4[4];
      #pragma unroll
      for (int i = 0; i < 4; i++) a4[i] = As[ty * 4 + i][kk];
      #pragma unroll
      for (int j = 0; j < 4; j++) b4[j] = Bs[kk][tx * 4 + j];
      #pragma unroll
      for (int i = 0; i < 4; i++)
        #pragma unroll
        for (int j = 0; j < 4; j++) acc[i][j] = fmaf(a4[i], b4[j], acc[i][j]);
    }
    __syncthreads();
  }
  #pragma unroll
  for (int i = 0; i < 4; i++) {
    int m = bm + ty * 4 + i;
    if (m >= M) continue;
    #pragma unroll
    for (int j = 0; j < 4; j++) {
      int n = bn + tx * 4 + j;
      if (n >= N) continue;
      float v = acc[i][j];
      if (bias) v += bias[n];
      if (act == 1) v = softplusf(v);
      if (resid) v += resid[(long)m * ldc + n];
      C[(long)m * ldc + n] = v;
    }
  }
}

// ---------------------------------------------------------------- RMS norm
__global__ __launch_bounds__(256) void rms_kernel(
    const float* __restrict__ x, const float* __restrict__ w, float* __restrict__ out)
{
  int row = blockIdx.x;
  const float* xr = x + (long)row * DD;
  int tid = threadIdx.x;
  float v0 = xr[tid], v1 = xr[tid + 256];
  float s = v0 * v0 + v1 * v1;
  for (int o = 32; o; o >>= 1) s += __shfl_down(s, o);
  __shared__ float sm[4];
  if ((tid & 63) == 0) sm[tid >> 6] = s;
  __syncthreads();
  float tot = sm[0] + sm[1] + sm[2] + sm[3];
  float inv = rsqrtf(tot / (float)DD + 1e-6f);
  out[(long)row * DD + tid] = v0 * inv * w[tid];
  out[(long)row * DD + tid + 256] = v1 * inv * w[tid + 256];
}

// ---------------------------------------------------------------- conv + SiLU
__global__ __launch_bounds__(256) void conv_silu_kernel(
    const float* __restrict__ xz, const float* __restrict__ cw, const float* __restrict__ cb,
    float* __restrict__ xc, int layer)
{
  long idx = (long)blockIdx.x * 256 + threadIdx.x;  // (g,b,t,c)
  int c = idx % DD;
  long r = idx / DD;           // (g*BB+b)*SEQL + t
  int t = r % SEQL;
  long gb = r / SEQL;
  int g = (int)(gb / BB);
  const float* w = cw + ((long)(layer * 2 + g) * DD + c) * KCC;
  float acc = cb[(long)(layer * 2 + g) * DD + c];
  const float* xp = xz + (r - t) * 2 * DD + c;
  #pragma unroll
  for (int k = 0; k < KCC; k++) {
    int tt = t - (KCC - 1) + k;
    if (tt >= 0) acc = fmaf(xp[(long)tt * 2 * DD], w[k], acc);
  }
  xc[idx] = siluf(acc);
}

// ---------------------------------------------------------------- chunked scan
__global__ __launch_bounds__(256) void scan_chunk_kernel(
    const float* __restrict__ dtv, const float* __restrict__ xc,
    const float* __restrict__ dbl, const float* __restrict__ Alog,
    float* __restrict__ P, float* __restrict__ Hend, int layer)
{
  int chunk = blockIdx.x, dtile = blockIdx.y, gb = blockIdx.z;
  int g = gb / BB;
  int tid = threadIdx.x;
  int n = tid & 15, dl = tid >> 4;
  int d = dtile * 16 + dl;
  int t0 = chunk * TC;
  __shared__ float dtv_s[TC][16], xc_s[TC][16], B_s[TC][17];
  {
    int c = tid & 15, rr = tid >> 4;
    long base = ((long)gb * SEQL + t0) * DD + dtile * 16;
    long dbase = ((long)gb * SEQL + t0) * 64 + 32;
    #pragma unroll
    for (int i = 0; i < 4; i++) {
      int tl = rr + i * 16;
      dtv_s[tl][c] = dtv[base + (long)tl * DD + c];
      xc_s[tl][c]  = xc[base + (long)tl * DD + c];
      B_s[tl][c]   = dbl[dbase + (long)tl * 64 + c];
    }
  }
  __syncthreads();
  float a = -expf(Alog[((long)((layer * 2 + g) * DD) + d) * NN + n]);
  float h = 0.f, sdt = 0.f;
  #pragma unroll 4
  for (int t = 0; t < TC; t++) {
    float dt = dtv_s[t][dl];
    float dA = expf(dt * a);
    h = fmaf(dA, h, dt * B_s[t][n] * xc_s[t][dl]);
    sdt += dt;
  }
  int r = (gb * DD + d) * NN + n;
  long o = (long)chunk * NR + r;
  P[o] = expf(a * sdt);
  Hend[o] = h;
}

__global__ __launch_bounds__(256) void scan_combine_kernel(
    const float* __restrict__ P, const float* __restrict__ Hend, float* __restrict__ Hin)
{
  int r = blockIdx.x * 256 + threadIdx.x;
  float h = 0.f;
  #pragma unroll
  for (int c = 0; c < NC; c++) {
    Hin[(long)c * NR + r] = h;
    h = fmaf(P[(long)c * NR + r], h, Hend[(long)c * NR + r]);
  }
}

__global__ __launch_bounds__(256) void scan_apply_kernel(
    const float* __restrict__ dtv, const float* __restrict__ xc, const float* __restrict__ xz,
    const float* __restrict__ dbl, const float* __restrict__ Alog, const float* __restrict__ Dp,
    const float* __restrict__ Hin, float* __restrict__ ym, int layer)
{
  int chunk = blockIdx.x, dtile = blockIdx.y, gb = blockIdx.z;
  int g = gb / BB;
  int tid = threadIdx.x;
  int n = tid & 15, dl = tid >> 4;
  int d = dtile * 16 + dl;
  int t0 = chunk * TC;
  __shared__ float dtv_s[TC][16], xc_s[TC][16], B_s[TC][17], C_s[TC][17], y_s[TC][16];
  {
    int c = tid & 15, rr = tid >> 4;
    long base = ((long)gb * SEQL + t0) * DD + dtile * 16;
    long dbase = ((long)gb * SEQL + t0) * 64 + 32;
    #pragma unroll
    for (int i = 0; i < 4; i++) {
      int tl = rr + i * 16;
      dtv_s[tl][c] = dtv[base + (long)tl * DD + c];
      xc_s[tl][c]  = xc[base + (long)tl * DD + c];
      B_s[tl][c]   = dbl[dbase + (long)tl * 64 + c];
      C_s[tl][c]   = dbl[dbase + (long)tl * 64 + 16 + c];
    }
  }
  __syncthreads();
  float a = -expf(Alog[((long)((layer * 2 + g) * DD) + d) * NN + n]);
  int r = (gb * DD + d) * NN + n;
  float h = Hin[(long)chunk * NR + r];
  #pragma unroll 4
  for (int t = 0; t < TC; t++) {
    float dt = dtv_s[t][dl];
    float dA = expf(dt * a);
    h = fmaf(dA, h, dt * B_s[t][n] * xc_s[t][dl]);
    float val = h * C_s[t][n];
    val += __shfl_xor(val, 1);
    val += __shfl_xor(val, 2);
    val += __shfl_xor(val, 4);
    val += __shfl_xor(val, 8);
    if (n == 0) y_s[t][dl] = val;
  }
  __syncthreads();
  {
    int c = tid & 15, rr = tid >> 4;
    long base = ((long)gb * SEQL + t0) * DD + dtile * 16;
    long zbase = ((long)gb * SEQL + t0) * 2 * DD + DD + dtile * 16;
    float Dpc = Dp[(long)(layer * 2 + g) * DD + dtile * 16 + c];
    #pragma unroll
    for (int i = 0; i < 4; i++) {
      int tl = rr + i * 16;
      float z = xz[zbase + (long)tl * 2 * DD + c];
      ym[base + (long)tl * DD + c] = (y_s[tl][c] + Dpc * xc_s[tl][c]) * siluf(z);
    }
  }
}

// ---------------------------------------------------------------- dir combine
__global__ __launch_bounds__(256) void combine_kernel(
    const float* __restrict__ yp, const float* __restrict__ proj, float* __restrict__ yc)
{
  long idx = (long)blockIdx.x * 256 + threadIdx.x;  // (b,t,d)
  int d = idx % DD;
  long r = idx / DD;
  int t = r % SEQL;
  long b = r / SEQL;
  float y0 = yp[idx];
  float y1 = yp[(long)BB * SEQL * DD + (b * SEQL + (SEQL - 1 - t)) * (long)DD + d];
  const float* pr = proj + r * 3 * DD;
  float zf = pr[DD + d];
  float zr = pr[2 * DD + d];
  yc[idx] = y0 * siluf(zf) + y1 * siluf(zr);
}

// ---------------------------------------------------------------- attention prep
__global__ void n0_kernel(int* __restrict__ n0tab)
{
  int d = blockIdx.x * blockDim.x + threadIdx.x;
  if (d >= SEQL) return;
  float pr = expf(logf((SEQL + 1) * 0.5f) / 16.0f);
  int n0 = 16;
  for (int n = 15; n >= 0; n--) {
    float cw = powf(pr, (float)(n + 1));
    if ((float)d <= cw) n0 = n;
  }
  n0tab[d] = n0;
}

__global__ __launch_bounds__(64) void qw_suffix_kernel(
    const float* __restrict__ q, const float* __restrict__ w_rel, float* __restrict__ S, int layer)
{
  int idx = blockIdx.x;           // (b*HH + h)*SEQL + i
  int i = idx % SEQL;
  int bh = idx / SEQL;
  int h = bh % HH;
  int b = bh / HH;
  __shared__ float qs[64];
  __shared__ float qwn[32];
  int tid = threadIdx.x;
  qs[tid] = q[((long)(b * SEQL + i) * HH + h) * DHH + tid];
  __syncthreads();
  if (tid < 32) {
    const float* wp = w_rel + ((long)(layer * HH + h) * DHH) * PPB + tid;
    float s = 0.f;
    #pragma unroll 8
    for (int d = 0; d < DHH; d++) s = fmaf(qs[d], wp[d * PPB], s);
    qwn[tid] = s;
  }
  __syncthreads();
  if (tid < 17) {
    float s1 = 0.f, s2 = 0.f;
    for (int n = tid; n < 16; n++) { s1 += qwn[n]; s2 += qwn[16 + n]; }
    float* Sp = S + (long)idx * 34;
    Sp[tid] = s1;
    Sp[17 + tid] = s2;
  }
}

__global__ __launch_bounds__(256) void vw_kernel(
    const float* __restrict__ vparam, const float* __restrict__ w_rel, float* __restrict__ VS, int layer)
{
  __shared__ float vws[HH][PPB];
  int tid = threadIdx.x;
  int h = tid / PPB, n = tid % PPB;
  const float* vp = vparam + (long)(layer * HH + h) * DHH;
  const float* wp = w_rel + ((long)(layer * HH + h) * DHH) * PPB + n;
  float s = 0.f;
  for (int d = 0; d < DHH; d++) s = fmaf(vp[d], wp[d * PPB], s);
  vws[h][n] = s;
  __syncthreads();
  if (tid < HH * 17) {
    int hh = tid / 17, m = tid % 17;
    float s1 = 0.f, s2 = 0.f;
    for (int nn = m; nn < 16; nn++) { s1 += vws[hh][nn]; s2 += vws[hh][16 + nn]; }
    VS[hh * 34 + m] = s1;
    VS[hh * 34 + 17 + m] = s2;
  }
}

__global__ __launch_bounds__(256) void uk_kernel(
    const float* __restrict__ u, const float* __restrict__ k, float* __restrict__ uk, int layer)
{
  int wid = (blockIdx.x * 256 + threadIdx.x) >> 6;
  int lane = threadIdx.x & 63;
  if (wid >= BB * HH * SEQL) return;
  int j = wid % SEQL;
  int bh = wid / SEQL;
  int h = bh % HH;
  int b = bh / HH;
  float vv = u[(long)(layer * HH + h) * DHH + lane] * k[((long)(b * SEQL + j) * HH + h) * DHH + lane];
  for (int o = 32; o; o >>= 1) vv += __shfl_down(vv, o);
  if (lane == 0) uk[(long)bh * SEQL + j] = vv;
}

// ---------------------------------------------------------------- MFMA attention
// Block: 256 threads = 4 waves; 64 query rows per block (16 per wave).
// S^T = mfma(K, Q): D[j][i]; softmax over j (in-lane + shfl_xor 16/32);
// P stored bf16 in per-wave PT[i][j]; O^T = mfma(VT, PT).
// LDS layout (bytes):
//   K_lds   [64][68] bf16 @ 0      (8704)
//   VT_lds  [64][68] bf16 @ 8704   (8704)
//   PT_lds  4x[16][68] bf16 @17408 (8704)
//   comb    [64][34] f32  @26112   (8704)
//   n0_s    [1024] int    @34816   (4096)
//   uk_s    [64] f32      @38912   (256)
//   O_lds   [64][68] f32  @0       (17408, aliases K+VT after compute)
__global__ __launch_bounds__(256) void attn_mfma_kernel(
    const float* __restrict__ q, const float* __restrict__ k, const float* __restrict__ vv,
    const float* __restrict__ S, const float* __restrict__ VS, const float* __restrict__ uk,
    const int* __restrict__ n0tab, float* __restrict__ out)
{
  __shared__ __align__(16) char smem[39168];
  unsigned short* K_lds  = (unsigned short*)(smem);
  unsigned short* VT_lds = (unsigned short*)(smem + 8704);
  unsigned short* PT_lds = (unsigned short*)(smem + 17408);
  float* comb            = (float*)(smem + 26112);
  int*   n0_s            = (int*)(smem + 34816);
  float* uk_s            = (float*)(smem + 38912);
  float* O_lds           = (float*)(smem);

  int itile = blockIdx.x;
  int bh = blockIdx.y;
  int h = bh % HH, b = bh / HH;
  int i0 = itile * 64;
  int tid = threadIdx.x;
  int w = tid >> 6;
  int lane = tid & 63;
  int li = lane & 15, lg = lane >> 4;

  // stage combined bias suffix tables + n0 table
  for (int idx = tid; idx < 64 * 17; idx += 256) {
    int il = idx / 17, m = idx % 17;
    long srow = ((long)bh * SEQL + i0 + il) * 34;
    comb[il * 34 + m]      = S[srow + m]      + VS[h * 34 + m];
    comb[il * 34 + 17 + m] = S[srow + 17 + m] + VS[h * 34 + 17 + m];
  }
  for (int idx = tid; idx < SEQL; idx += 256) n0_s[idx] = n0tab[idx];

  // Q fragments (kept in registers): lane holds Q[i][32*ks + 8*lg + e]
  int iq = i0 + w * 16 + li;
  const float* qrow = q + ((long)(b * SEQL + iq)) * DD + h * 64;
  bf16x8 qf0 = pack8(qrow + 8 * lg);
  bf16x8 qf1 = pack8(qrow + 32 + 8 * lg);

  f32x4 oacc[4] = {};
  float mrun = -1e30f, lrun = 0.f;
  const int ibase = i0 + w * 16 + li;
  unsigned short* PTw = PT_lds + w * 16 * 68;

  for (int j0 = 0; j0 < SEQL; j0 += 64) {
    __syncthreads();
    // ---- stage K (row-major) and V (transposed) as bf16 ----
    {
      int jl = tid >> 4;          // 0..15
      int dq = (tid & 15) * 4;    // 0..60
      #pragma unroll
      for (int rr = 0; rr < 4; rr++) {
        int jj = jl + rr * 16;
        long grow = ((long)(b * SEQL + j0 + jj)) * DD + h * 64 + dq;
        float4 kv = *(const float4*)(k + grow);
        short4v kp = { (short)f2bf(kv.x), (short)f2bf(kv.y), (short)f2bf(kv.z), (short)f2bf(kv.w) };
        *(short4v*)(K_lds + jj * 68 + dq) = kp;
        float4 vvv = *(const float4*)(vv + grow);
        VT_lds[(dq + 0) * 68 + jj] = f2bf(vvv.x);
        VT_lds[(dq + 1) * 68 + jj] = f2bf(vvv.y);
        VT_lds[(dq + 2) * 68 + jj] = f2bf(vvv.z);
        VT_lds[(dq + 3) * 68 + jj] = f2bf(vvv.w);
      }
      if (tid < 64) uk_s[tid] = uk[(long)bh * SEQL + j0 + tid];
    }
    __syncthreads();

    // ---- QK^T (S^T fragments) ----
    f32x4 sf[4];
    #pragma unroll
    for (int jj = 0; jj < 4; jj++) {
      f32x4 c = {};
      c = __builtin_amdgcn_mfma_f32_16x16x32_bf16(
            ld_frag(K_lds + (jj * 16 + li) * 68 + 8 * lg), qf0, c, 0, 0, 0);
      c = __builtin_amdgcn_mfma_f32_16x16x32_bf16(
            ld_frag(K_lds + (jj * 16 + li) * 68 + 32 + 8 * lg), qf1, c, 0, 0, 0);
      sf[jj] = c;
    }

    // ---- bias + online softmax ----
    float sv[4][4];
    float tmax = -1e30f;
    const float* crow = comb + (w * 16 + li) * 34;
    #pragma unroll
    for (int jj = 0; jj < 4; jj++) {
      #pragma unroll
      for (int r = 0; r < 4; r++) {
        int jloc = jj * 16 + 4 * lg + r;
        int di = (j0 + jloc) - ibase;
        int ad = di < 0 ? -di : di;
        float sg = di > 0 ? 1.f : (di < 0 ? -1.f : 0.f);
        int n0 = n0_s[ad];
        float val = (sf[jj][r] + crow[n0] + sg * crow[17 + n0] + uk_s[jloc]) * 0.125f;
        sv[jj][r] = val;
        tmax = fmaxf(tmax, val);
      }
    }
    tmax = fmaxf(tmax, __shfl_xor(tmax, 16));
    tmax = fmaxf(tmax, __shfl_xor(tmax, 32));
    float mnew = fmaxf(mrun, tmax);
    float fsc = __expf(mrun - mnew);
    mrun = mnew;
    lrun *= fsc;
    #pragma unroll
    for (int df = 0; df < 4; df++) oacc[df] *= fsc;

    float psum = 0.f;
    #pragma unroll
    for (int jj = 0; jj < 4; jj++) {
      short4v pk;
      #pragma unroll
      for (int r = 0; r < 4; r++) {
        float p = __expf(sv[jj][r] - mnew);
        psum += p;
        pk[r] = (short)f2bf(p);
      }
      *(short4v*)(PTw + li * 68 + jj * 16 + 4 * lg) = pk;
    }
    psum += __shfl_xor(psum, 16);
    psum += __shfl_xor(psum, 32);
    lrun += psum;

    asm volatile("s_waitcnt lgkmcnt(0)" ::: "memory");

    // ---- PV: O^T += VT x P ----
    bf16x8 pf0 = ld_frag(PTw + li * 68 + 8 * lg);
    bf16x8 pf1 = ld_frag(PTw + li * 68 + 32 + 8 * lg);
    #pragma unroll
    for (int df = 0; df < 4; df++) {
      f32x4 c = oacc[df];
      c = __builtin_amdgcn_mfma_f32_16x16x32_bf16(
            ld_frag(VT_lds + (df * 16 + li) * 68 + 8 * lg), pf0, c, 0, 0, 0);
      c = __builtin_amdgcn_mfma_f32_16x16x32_bf16(
            ld_frag(VT_lds + (df * 16 + li) * 68 + 32 + 8 * lg), pf1, c, 0, 0, 0);
      oacc[df] = c;
    }
  }

  // ---- epilogue: normalize, transpose via LDS, coalesced write ----
  __syncthreads();
  float inv = 1.f / lrun;
  #pragma unroll
  for (int df = 0; df < 4; df++) {
    f32x4 o = oacc[df] * inv;
    *(f32x4*)(O_lds + (w * 16 + li) * 68 + df * 16 + 4 * lg) = o;
  }
  __syncthreads();
  {
    int il = tid >> 2, c0 = (tid & 3) * 16;
    long orow = ((long)(b * SEQL + i0 + il)) * DD + h * 64 + c0;
    #pragma unroll
    for (int c4 = 0; c4 < 4; c4++) {
      f32x4 o = *(const f32x4*)(O_lds + il * 68 + c0 + c4 * 4);
      *(f32x4*)(out + orow + c4 * 4) = o;
    }
  }
}

// ---------------------------------------------------------------- launch
extern "C" void kernel_launch(void* const* d_in, const int* in_sizes, int n_in,
                              void* d_out, int out_size, void* d_ws, size_t ws_size,
                              hipStream_t stream) {
  const float* x_in     = (const float*)d_in[0];
  const float* rms_m    = (const float*)d_in[1];
  const float* W_in     = (const float*)d_in[2];
  const float* b_in     = (const float*)d_in[3];
  const float* m_Win    = (const float*)d_in[4];
  const float* m_conv_w = (const float*)d_in[5];
  const float* m_conv_b = (const float*)d_in[6];
  const float* m_Wx     = (const float*)d_in[7];
  const float* m_Wdt    = (const float*)d_in[8];
  const float* m_bdt    = (const float*)d_in[9];
  const float* m_Alog   = (const float*)d_in[10];
  const float* m_Dp     = (const float*)d_in[11];
  const float* m_Wout   = (const float*)d_in[12];
  const float* W_out    = (const float*)d_in[13];
  const float* b_out    = (const float*)d_in[14];
  const float* rms_a    = (const float*)d_in[15];
  const float* Wq       = (const float*)d_in[16];
  const float* Wk       = (const float*)d_in[17];
  const float* Wv       = (const float*)d_in[18];
  const float* u_p      = (const float*)d_in[19];
  const float* v_p      = (const float*)d_in[20];
  const float* w_rel    = (const float*)d_in[21];
  const float* Wo       = (const float*)d_in[22];
  const float* b_o      = (const float*)d_in[23];
  float* out = (float*)d_out;

  float* ws = (float*)d_ws;
  const long U = (long)BB * SEQL * DD;      // 1,048,576 floats
  float* xA    = ws;
  float* xB    = ws + 1 * U;
  float* xn    = ws + 2 * U;                // also scan P/Hend scratch
  float* proj  = ws + 3 * U;                // 3U; later q,k,v
  float* xz    = ws + 6 * U;                // 4U; later yp (2U)
  float* xc    = ws + 10 * U;               // 2U
  float* dtv   = ws + 12 * U;               // 2U
  float* ym    = ws + 14 * U;               // 2U; later attnout
  float* ycomb = ws + 16 * U;               // 1U; also scan Hin scratch
  float* smallb= ws + 17 * U;               // 1U of small buffers
  float* dbl   = smallb;                    // 2*BB*SEQL*64 = 262144
  float* ukbuf = smallb + 262144;           // 16384
  float* Sbuf  = smallb + 278528;           // 557056
  float* VSbuf = smallb + 835584;           // 272
  int*   n0tab = (int*)(smallb + 835856);   // 1024
  float* yp = xz;
  float* qb = proj;
  float* kb = proj + U;
  float* vb = proj + 2 * U;
  float* attnout = ym;
  float* Pbuf = xn;                         // NC*NR = 524288
  float* Hend = xn + (long)NC * NR;         // 524288
  float* Hin  = ycomb;                      // 524288 <= 1U

  const int M = BB * SEQL;                  // 2048

  n0_kernel<<<4, 256, 0, stream>>>(n0tab);

  for (int layer = 0; layer < LL; layer++) {
    const float* cur = (layer == 0) ? x_in : xA;
    // ---- mamba block ----
    rms_kernel<<<M, 256, 0, stream>>>(cur, rms_m + layer * DD, xn);
    gemm_f32<<<dim3(24, 32, 1), 256, 0, stream>>>(xn, W_in + (long)layer * DD * 3 * DD,
        b_in + layer * 3 * DD, nullptr, proj, M, 3 * DD, DD, DD, 3 * DD, 0, 0, 0, 0, 0, 0);
    gemm_f32<<<dim3(16, 32, 2), 256, 0, stream>>>(proj, m_Win + (long)layer * 2 * DD * 2 * DD,
        nullptr, nullptr, xz, M, 2 * DD, DD, 3 * DD, 2 * DD,
        0, (long)DD * 2 * DD, 0, (long)BB * SEQL * 2 * DD, SEQL, 0);
    conv_silu_kernel<<<(2 * BB * SEQL * DD) / 256, 256, 0, stream>>>(xz, m_conv_w, m_conv_b, xc, layer);
    gemm_f32<<<dim3(1, 32, 2), 256, 0, stream>>>(xc, m_Wx + (long)layer * 2 * DD * 64,
        nullptr, nullptr, dbl, M, 64, DD, DD, 64,
        U, (long)DD * 64, 0, (long)BB * SEQL * 64, 0, 0);
    gemm_f32<<<dim3(8, 32, 2), 256, 0, stream>>>(dbl, m_Wdt + (long)layer * 2 * DTRR * DD,
        m_bdt + (long)layer * 2 * DD, nullptr, dtv, M, DD, DTRR, 64, DD,
        (long)BB * SEQL * 64, (long)DTRR * DD, DD, U, 0, 1);
    scan_chunk_kernel<<<dim3(NC, DD / 16, GBS), 256, 0, stream>>>(
        dtv, xc, dbl, m_Alog, Pbuf, Hend, layer);
    scan_combine_kernel<<<NR / 256, 256, 0, stream>>>(Pbuf, Hend, Hin);
    scan_apply_kernel<<<dim3(NC, DD / 16, GBS), 256, 0, stream>>>(
        dtv, xc, xz, dbl, m_Alog, m_Dp, Hin, ym, layer);
    gemm_f32<<<dim3(8, 32, 2), 256, 0, stream>>>(ym, m_Wout + (long)layer * 2 * DD * DD,
        nullptr, nullptr, yp, M, DD, DD, DD, DD, U, (long)DD * DD, 0, U, 0, 0);
    combine_kernel<<<(int)(U / 256), 256, 0, stream>>>(yp, proj, ycomb);
    gemm_f32<<<dim3(8, 32, 1), 256, 0, stream>>>(ycomb, W_out + (long)layer * DD * DD,
        b_out + layer * DD, cur, xB, M, DD, DD, DD, DD, 0, 0, 0, 0, 0, 0);
    // ---- attention block ----
    rms_kernel<<<M, 256, 0, stream>>>(xB, rms_a + layer * DD, xn);
    gemm_f32<<<dim3(8, 32, 1), 256, 0, stream>>>(xn, Wq + (long)layer * DD * HH * DHH,
        nullptr, nullptr, qb, M, DD, DD, DD, DD, 0, 0, 0, 0, 0, 0);
    gemm_f32<<<dim3(8, 32, 1), 256, 0, stream>>>(xn, Wk + (long)layer * DD * HH * DHH,
        nullptr, nullptr, kb, M, DD, DD, DD, DD, 0, 0, 0, 0, 0, 0);
    gemm_f32<<<dim3(8, 32, 1), 256, 0, stream>>>(xn, Wv + (long)layer * DD * HH * DHH,
        nullptr, nullptr, vb, M, DD, DD, DD, DD, 0, 0, 0, 0, 0, 0);
    qw_suffix_kernel<<<BB * HH * SEQL, 64, 0, stream>>>(qb, w_rel, Sbuf, layer);
    vw_kernel<<<1, 256, 0, stream>>>(v_p, w_rel, VSbuf, layer);
    uk_kernel<<<(BB * HH * SEQL) / 4, 256, 0, stream>>>(u_p, kb, ukbuf, layer);
    attn_mfma_kernel<<<dim3(SEQL / 64, BB * HH), 256, 0, stream>>>(
        qb, kb, vb, Sbuf, VSbuf, ukbuf, n0tab, attnout);
    float* outp = (layer == LL - 1) ? out : xA;
    gemm_f32<<<dim3(8, 32, 1), 256, 0, stream>>>(attnout, Wo + (long)layer * HH * DHH * DD,
        b_o + layer * DD, xB, outp, M, DD, DD, DD, DD, 0, 0, 0, 0, 0, 0);
  }
}

// Round 4
// 1041.337 us; speedup vs baseline: 4.6731x; 1.8059x over previous
//
#include <hip/hip_runtime.h>

#define LL 2
#define BB 2
#define SEQL 1024
#define DD 512
#define NN 16
#define HH 8
#define DHH 64
#define PPB 32
#define KCC 4
#define DTRR 32

#define GBS 4              // g*BB+b combinations
#define TC 64              // scan chunk length
#define NC (SEQL / TC)     // 16 chunks
#define NR (GBS * DD * NN) // 32768 recurrences

typedef __attribute__((ext_vector_type(8))) short bf16x8;
typedef __attribute__((ext_vector_type(4))) short short4v;
typedef __attribute__((ext_vector_type(4))) float f32x4;

__device__ __forceinline__ float siluf(float x) { return x / (1.f + expf(-x)); }
__device__ __forceinline__ float softplusf(float x) { return x > 20.f ? x : log1pf(expf(x)); }

__device__ __forceinline__ unsigned short f2bf(float x) {
  union { float f; unsigned u; } v; v.f = x;
  unsigned r = v.u + 0x7fff + ((v.u >> 16) & 1);
  return (unsigned short)(r >> 16);
}

__device__ __forceinline__ bf16x8 ld_frag(const unsigned short* p) {
  short4v a = *(const short4v*)(p);
  short4v b = *(const short4v*)(p + 4);
  bf16x8 r;
  r[0]=a[0]; r[1]=a[1]; r[2]=a[2]; r[3]=a[3];
  r[4]=b[0]; r[5]=b[1]; r[6]=b[2]; r[7]=b[3];
  return r;
}

__device__ __forceinline__ bf16x8 pack8(const float* p) {
  bf16x8 r;
  #pragma unroll
  for (int e = 0; e < 8; e++) r[e] = (short)f2bf(p[e]);
  return r;
}

// ---------------------------------------------------------------- weight transpose fp32[K][N] -> bf16[N][K]
__global__ __launch_bounds__(256) void wtrans_kernel(
    const float* __restrict__ W, unsigned short* __restrict__ WT, int K, int N)
{
  int g = blockIdx.z;
  W  += (long)g * K * N;
  WT += (long)g * K * N;
  __shared__ float t[32][33];
  int tx = threadIdx.x & 31, ty = threadIdx.x >> 5;
  int n0 = blockIdx.x * 32, k0 = blockIdx.y * 32;
  #pragma unroll
  for (int i = 0; i < 4; i++)
    t[ty + 8 * i][tx] = W[(long)(k0 + ty + 8 * i) * N + n0 + tx];
  __syncthreads();
  #pragma unroll
  for (int i = 0; i < 4; i++)
    WT[(long)(n0 + ty + 8 * i) * K + k0 + tx] = f2bf(t[tx][ty + 8 * i]);
}

// ---------------------------------------------------------------- GEMM (bf16 MFMA)
// C[m,n] = A[m,:] (fp32, cvt) . WT[n,:] (bf16) ; 128x128 tile, BK=64, 4 waves.
__global__ __launch_bounds__(256) void gemm_bf16(
    const float* __restrict__ A, const unsigned short* __restrict__ WT,
    const float* __restrict__ bias, const float* __restrict__ resid,
    float* __restrict__ C,
    int M, int N, int K, int lda, int ldc,
    long aBatch, long wBatch, long biasBatch, long cBatch,
    int aflipL, int act)
{
  int g = blockIdx.z;
  A  += (long)g * aBatch;
  WT += (long)g * wBatch;
  C  += (long)g * cBatch;
  if (bias) bias += (long)g * biasBatch;
  const bool flip = (aflipL > 0) && (g == 1);

  __shared__ unsigned short A_lds[128][72];
  __shared__ unsigned short B_lds[128][72];
  int tid = threadIdx.x;
  int w = tid >> 6, lane = tid & 63, li = lane & 15, lg = lane >> 4;
  int bm = blockIdx.y * 128, bn = blockIdx.x * 128;
  int wm = (w & 1) * 64, wn = (w >> 1) * 64;
  f32x4 acc[4][4] = {};

  const int kqA = (tid & 15) * 4, r0A = tid >> 4;   // A staging
  const int kqB = (tid & 7) * 8,  r0B = tid >> 3;   // B staging

  for (int k0 = 0; k0 < K; k0 += 64) {
    __syncthreads();
    #pragma unroll
    for (int i = 0; i < 8; i++) {
      int m = bm + r0A + 16 * i;
      int mm = m;
      if (flip) { int bb = m / aflipL; int t = m - bb * aflipL; mm = bb * aflipL + (aflipL - 1 - t); }
      float4 av = *(const float4*)(A + (long)mm * lda + k0 + kqA);
      short4v ap = { (short)f2bf(av.x), (short)f2bf(av.y), (short)f2bf(av.z), (short)f2bf(av.w) };
      *(short4v*)(&A_lds[r0A + 16 * i][kqA]) = ap;
    }
    #pragma unroll
    for (int i = 0; i < 4; i++) {
      int n = bn + r0B + 32 * i;
      bf16x8 bv = *(const bf16x8*)(WT + (long)n * K + k0 + kqB);
      *(bf16x8*)(&B_lds[r0B + 32 * i][kqB]) = bv;
    }
    __syncthreads();
    #pragma unroll
    for (int ks = 0; ks < 2; ks++) {
      bf16x8 af[4], bfr[4];
      #pragma unroll
      for (int fm = 0; fm < 4; fm++)
        af[fm] = *(const bf16x8*)(&A_lds[wm + fm * 16 + li][ks * 32 + lg * 8]);
      #pragma unroll
      for (int fn = 0; fn < 4; fn++)
        bfr[fn] = *(const bf16x8*)(&B_lds[wn + fn * 16 + li][ks * 32 + lg * 8]);
      #pragma unroll
      for (int fm = 0; fm < 4; fm++)
        #pragma unroll
        for (int fn = 0; fn < 4; fn++)
          acc[fm][fn] = __builtin_amdgcn_mfma_f32_16x16x32_bf16(af[fm], bfr[fn], acc[fm][fn], 0, 0, 0);
    }
  }
  #pragma unroll
  for (int fm = 0; fm < 4; fm++) {
    #pragma unroll
    for (int fn = 0; fn < 4; fn++) {
      int n = bn + wn + fn * 16 + li;
      float bv = bias ? bias[n] : 0.f;
      #pragma unroll
      for (int r = 0; r < 4; r++) {
        int m = bm + wm + fm * 16 + 4 * lg + r;
        float v = acc[fm][fn][r] + bv;
        if (act == 1) v = softplusf(v);
        if (resid) v += resid[(long)m * ldc + n];
        C[(long)m * ldc + n] = v;
      }
    }
  }
}

// ---------------------------------------------------------------- GEMM (fp32, small shapes)
__global__ __launch_bounds__(256) void gemm_f32(
    const float* __restrict__ A, const float* __restrict__ W,
    const float* __restrict__ bias, const float* __restrict__ resid,
    float* __restrict__ C,
    int M, int N, int K, int lda, int ldc,
    long aBatch, long wBatch, long biasBatch, long cBatch,
    int aflipL, int act)
{
  int g = blockIdx.z;
  A += (long)g * aBatch;
  W += (long)g * wBatch;
  C += (long)g * cBatch;
  if (bias) bias += (long)g * biasBatch;
  const bool flip = (aflipL > 0) && (g == 1);

  __shared__ float As[64][17];
  __shared__ float Bs[16][65];
  int tid = threadIdx.x;
  int tx = tid & 15, ty = tid >> 4;
  int bm = blockIdx.y * 64, bn = blockIdx.x * 64;
  float acc[4][4] = {};

  for (int k0 = 0; k0 < K; k0 += 16) {
    int c = tid & 15, r0 = tid >> 4;
    #pragma unroll
    for (int rr = 0; rr < 4; rr++) {
      int m = bm + r0 + rr * 16;
      float v = 0.f;
      if (m < M) {
        int mm = m;
        if (flip) { int bb = m / aflipL; int t = m - bb * aflipL; mm = bb * aflipL + (aflipL - 1 - t); }
        v = A[(long)mm * lda + k0 + c];
      }
      As[r0 + rr * 16][c] = v;
    }
    int c2 = tid & 63, r2 = tid >> 6;
    #pragma unroll
    for (int rr = 0; rr < 4; rr++) {
      int kk = k0 + r2 + rr * 4;
      int n = bn + c2;
      Bs[r2 + rr * 4][c2] = (kk < K && n < N) ? W[(long)kk * N + n] : 0.f;
    }
    __syncthreads();
    #pragma unroll
    for (int kk = 0; kk < 16; kk++) {
      float a4[4], b4[4];
      #pragma unroll
      for (int i = 0; i < 4; i++) a4[i] = As[ty * 4 + i][kk];
      #pragma unroll
      for (int j = 0; j < 4; j++) b4[j] = Bs[kk][tx * 4 + j];
      #pragma unroll
      for (int i = 0; i < 4; i++)
        #pragma unroll
        for (int j = 0; j < 4; j++) acc[i][j] = fmaf(a4[i], b4[j], acc[i][j]);
    }
    __syncthreads();
  }
  #pragma unroll
  for (int i = 0; i < 4; i++) {
    int m = bm + ty * 4 + i;
    if (m >= M) continue;
    #pragma unroll
    for (int j = 0; j < 4; j++) {
      int n = bn + tx * 4 + j;
      if (n >= N) continue;
      float v = acc[i][j];
      if (bias) v += bias[n];
      if (act == 1) v = softplusf(v);
      if (resid) v += resid[(long)m * ldc + n];
      C[(long)m * ldc + n] = v;
    }
  }
}

// ---------------------------------------------------------------- RMS norm
__global__ __launch_bounds__(256) void rms_kernel(
    const float* __restrict__ x, const float* __restrict__ w, float* __restrict__ out)
{
  int row = blockIdx.x;
  const float* xr = x + (long)row * DD;
  int tid = threadIdx.x;
  float v0 = xr[tid], v1 = xr[tid + 256];
  float s = v0 * v0 + v1 * v1;
  for (int o = 32; o; o >>= 1) s += __shfl_down(s, o);
  __shared__ float sm[4];
  if ((tid & 63) == 0) sm[tid >> 6] = s;
  __syncthreads();
  float tot = sm[0] + sm[1] + sm[2] + sm[3];
  float inv = rsqrtf(tot / (float)DD + 1e-6f);
  out[(long)row * DD + tid] = v0 * inv * w[tid];
  out[(long)row * DD + tid + 256] = v1 * inv * w[tid + 256];
}

// ---------------------------------------------------------------- conv + SiLU
__global__ __launch_bounds__(256) void conv_silu_kernel(
    const float* __restrict__ xz, const float* __restrict__ cw, const float* __restrict__ cb,
    float* __restrict__ xc, int layer)
{
  long idx = (long)blockIdx.x * 256 + threadIdx.x;  // (g,b,t,c)
  int c = idx % DD;
  long r = idx / DD;
  int t = r % SEQL;
  long gb = r / SEQL;
  int g = (int)(gb / BB);
  const float* w = cw + ((long)(layer * 2 + g) * DD + c) * KCC;
  float acc = cb[(long)(layer * 2 + g) * DD + c];
  const float* xp = xz + (r - t) * 2 * DD + c;
  #pragma unroll
  for (int k = 0; k < KCC; k++) {
    int tt = t - (KCC - 1) + k;
    if (tt >= 0) acc = fmaf(xp[(long)tt * 2 * DD], w[k], acc);
  }
  xc[idx] = siluf(acc);
}

// ---------------------------------------------------------------- chunked scan
__global__ __launch_bounds__(256) void scan_chunk_kernel(
    const float* __restrict__ dtv, const float* __restrict__ xc,
    const float* __restrict__ dbl, const float* __restrict__ Alog,
    float* __restrict__ P, float* __restrict__ Hend, int layer)
{
  int chunk = blockIdx.x, dtile = blockIdx.y, gb = blockIdx.z;
  int g = gb / BB;
  int tid = threadIdx.x;
  int n = tid & 15, dl = tid >> 4;
  int d = dtile * 16 + dl;
  int t0 = chunk * TC;
  __shared__ float dtv_s[TC][16], xc_s[TC][16], B_s[TC][17];
  {
    int c = tid & 15, rr = tid >> 4;
    long base = ((long)gb * SEQL + t0) * DD + dtile * 16;
    long dbase = ((long)gb * SEQL + t0) * 64 + 32;
    #pragma unroll
    for (int i = 0; i < 4; i++) {
      int tl = rr + i * 16;
      dtv_s[tl][c] = dtv[base + (long)tl * DD + c];
      xc_s[tl][c]  = xc[base + (long)tl * DD + c];
      B_s[tl][c]   = dbl[dbase + (long)tl * 64 + c];
    }
  }
  __syncthreads();
  float a = -expf(Alog[((long)((layer * 2 + g) * DD) + d) * NN + n]);
  float h = 0.f, sdt = 0.f;
  #pragma unroll 4
  for (int t = 0; t < TC; t++) {
    float dt = dtv_s[t][dl];
    float dA = expf(dt * a);
    h = fmaf(dA, h, dt * B_s[t][n] * xc_s[t][dl]);
    sdt += dt;
  }
  int r = (gb * DD + d) * NN + n;
  long o = (long)chunk * NR + r;
  P[o] = expf(a * sdt);
  Hend[o] = h;
}

__global__ __launch_bounds__(256) void scan_combine_kernel(
    const float* __restrict__ P, const float* __restrict__ Hend, float* __restrict__ Hin)
{
  int r = blockIdx.x * 256 + threadIdx.x;
  float h = 0.f;
  #pragma unroll
  for (int c = 0; c < NC; c++) {
    Hin[(long)c * NR + r] = h;
    h = fmaf(P[(long)c * NR + r], h, Hend[(long)c * NR + r]);
  }
}

__global__ __launch_bounds__(256) void scan_apply_kernel(
    const float* __restrict__ dtv, const float* __restrict__ xc, const float* __restrict__ xz,
    const float* __restrict__ dbl, const float* __restrict__ Alog, const float* __restrict__ Dp,
    const float* __restrict__ Hin, float* __restrict__ ym, int layer)
{
  int chunk = blockIdx.x, dtile = blockIdx.y, gb = blockIdx.z;
  int g = gb / BB;
  int tid = threadIdx.x;
  int n = tid & 15, dl = tid >> 4;
  int d = dtile * 16 + dl;
  int t0 = chunk * TC;
  __shared__ float dtv_s[TC][16], xc_s[TC][16], B_s[TC][17], C_s[TC][17], y_s[TC][16];
  {
    int c = tid & 15, rr = tid >> 4;
    long base = ((long)gb * SEQL + t0) * DD + dtile * 16;
    long dbase = ((long)gb * SEQL + t0) * 64 + 32;
    #pragma unroll
    for (int i = 0; i < 4; i++) {
      int tl = rr + i * 16;
      dtv_s[tl][c] = dtv[base + (long)tl * DD + c];
      xc_s[tl][c]  = xc[base + (long)tl * DD + c];
      B_s[tl][c]   = dbl[dbase + (long)tl * 64 + c];
      C_s[tl][c]   = dbl[dbase + (long)tl * 64 + 16 + c];
    }
  }
  __syncthreads();
  float a = -expf(Alog[((long)((layer * 2 + g) * DD) + d) * NN + n]);
  int r = (gb * DD + d) * NN + n;
  float h = Hin[(long)chunk * NR + r];
  #pragma unroll 4
  for (int t = 0; t < TC; t++) {
    float dt = dtv_s[t][dl];
    float dA = expf(dt * a);
    h = fmaf(dA, h, dt * B_s[t][n] * xc_s[t][dl]);
    float val = h * C_s[t][n];
    val += __shfl_xor(val, 1);
    val += __shfl_xor(val, 2);
    val += __shfl_xor(val, 4);
    val += __shfl_xor(val, 8);
    if (n == 0) y_s[t][dl] = val;
  }
  __syncthreads();
  {
    int c = tid & 15, rr = tid >> 4;
    long base = ((long)gb * SEQL + t0) * DD + dtile * 16;
    long zbase = ((long)gb * SEQL + t0) * 2 * DD + DD + dtile * 16;
    float Dpc = Dp[(long)(layer * 2 + g) * DD + dtile * 16 + c];
    #pragma unroll
    for (int i = 0; i < 4; i++) {
      int tl = rr + i * 16;
      float z = xz[zbase + (long)tl * 2 * DD + c];
      ym[base + (long)tl * DD + c] = (y_s[tl][c] + Dpc * xc_s[tl][c]) * siluf(z);
    }
  }
}

// ---------------------------------------------------------------- dir combine
__global__ __launch_bounds__(256) void combine_kernel(
    const float* __restrict__ yp, const float* __restrict__ proj, float* __restrict__ yc)
{
  long idx = (long)blockIdx.x * 256 + threadIdx.x;  // (b,t,d)
  int d = idx % DD;
  long r = idx / DD;
  int t = r % SEQL;
  long b = r / SEQL;
  float y0 = yp[idx];
  float y1 = yp[(long)BB * SEQL * DD + (b * SEQL + (SEQL - 1 - t)) * (long)DD + d];
  const float* pr = proj + r * 3 * DD;
  float zf = pr[DD + d];
  float zr = pr[2 * DD + d];
  yc[idx] = y0 * siluf(zf) + y1 * siluf(zr);
}

// ---------------------------------------------------------------- attention prep
__global__ void n0_kernel(int* __restrict__ n0tab)
{
  int d = blockIdx.x * blockDim.x + threadIdx.x;
  if (d >= SEQL) return;
  float pr = expf(logf((SEQL + 1) * 0.5f) / 16.0f);
  int n0 = 16;
  for (int n = 15; n >= 0; n--) {
    float cw = powf(pr, (float)(n + 1));
    if ((float)d <= cw) n0 = n;
  }
  n0tab[d] = n0;
}

__global__ __launch_bounds__(64) void qw_suffix_kernel(
    const float* __restrict__ q, const float* __restrict__ w_rel, float* __restrict__ S, int layer)
{
  int idx = blockIdx.x;           // (b*HH + h)*SEQL + i
  int i = idx % SEQL;
  int bh = idx / SEQL;
  int h = bh % HH;
  int b = bh / HH;
  __shared__ float qs[64];
  __shared__ float qwn[32];
  int tid = threadIdx.x;
  qs[tid] = q[((long)(b * SEQL + i) * HH + h) * DHH + tid];
  __syncthreads();
  if (tid < 32) {
    const float* wp = w_rel + ((long)(layer * HH + h) * DHH) * PPB + tid;
    float s = 0.f;
    #pragma unroll 8
    for (int d = 0; d < DHH; d++) s = fmaf(qs[d], wp[d * PPB], s);
    qwn[tid] = s;
  }
  __syncthreads();
  if (tid < 17) {
    float s1 = 0.f, s2 = 0.f;
    for (int n = tid; n < 16; n++) { s1 += qwn[n]; s2 += qwn[16 + n]; }
    float* Sp = S + (long)idx * 34;
    Sp[tid] = s1;
    Sp[17 + tid] = s2;
  }
}

__global__ __launch_bounds__(256) void vw_kernel(
    const float* __restrict__ vparam, const float* __restrict__ w_rel, float* __restrict__ VS, int layer)
{
  __shared__ float vws[HH][PPB];
  int tid = threadIdx.x;
  int h = tid / PPB, n = tid % PPB;
  const float* vp = vparam + (long)(layer * HH + h) * DHH;
  const float* wp = w_rel + ((long)(layer * HH + h) * DHH) * PPB + n;
  float s = 0.f;
  for (int d = 0; d < DHH; d++) s = fmaf(vp[d], wp[d * PPB], s);
  vws[h][n] = s;
  __syncthreads();
  if (tid < HH * 17) {
    int hh = tid / 17, m = tid % 17;
    float s1 = 0.f, s2 = 0.f;
    for (int nn = m; nn < 16; nn++) { s1 += vws[hh][nn]; s2 += vws[hh][16 + nn]; }
    VS[hh * 34 + m] = s1;
    VS[hh * 34 + 17 + m] = s2;
  }
}

__global__ __launch_bounds__(256) void uk_kernel(
    const float* __restrict__ u, const float* __restrict__ k, float* __restrict__ uk, int layer)
{
  int wid = (blockIdx.x * 256 + threadIdx.x) >> 6;
  int lane = threadIdx.x & 63;
  if (wid >= BB * HH * SEQL) return;
  int j = wid % SEQL;
  int bh = wid / SEQL;
  int h = bh % HH;
  int b = bh / HH;
  float vv = u[(long)(layer * HH + h) * DHH + lane] * k[((long)(b * SEQL + j) * HH + h) * DHH + lane];
  for (int o = 32; o; o >>= 1) vv += __shfl_down(vv, o);
  if (lane == 0) uk[(long)bh * SEQL + j] = vv;
}

// ---------------------------------------------------------------- MFMA attention
__global__ __launch_bounds__(256) void attn_mfma_kernel(
    const float* __restrict__ q, const float* __restrict__ k, const float* __restrict__ vv,
    const float* __restrict__ S, const float* __restrict__ VS, const float* __restrict__ uk,
    const int* __restrict__ n0tab, float* __restrict__ out)
{
  __shared__ __align__(16) char smem[39168];
  unsigned short* K_lds  = (unsigned short*)(smem);
  unsigned short* VT_lds = (unsigned short*)(smem + 8704);
  unsigned short* PT_lds = (unsigned short*)(smem + 17408);
  float* comb            = (float*)(smem + 26112);
  int*   n0_s            = (int*)(smem + 34816);
  float* uk_s            = (float*)(smem + 38912);
  float* O_lds           = (float*)(smem);

  int itile = blockIdx.x;
  int bh = blockIdx.y;
  int h = bh % HH, b = bh / HH;
  int i0 = itile * 64;
  int tid = threadIdx.x;
  int w = tid >> 6;
  int lane = tid & 63;
  int li = lane & 15, lg = lane >> 4;

  for (int idx = tid; idx < 64 * 17; idx += 256) {
    int il = idx / 17, m = idx % 17;
    long srow = ((long)bh * SEQL + i0 + il) * 34;
    comb[il * 34 + m]      = S[srow + m]      + VS[h * 34 + m];
    comb[il * 34 + 17 + m] = S[srow + 17 + m] + VS[h * 34 + 17 + m];
  }
  for (int idx = tid; idx < SEQL; idx += 256) n0_s[idx] = n0tab[idx];

  int iq = i0 + w * 16 + li;
  const float* qrow = q + ((long)(b * SEQL + iq)) * DD + h * 64;
  bf16x8 qf0 = pack8(qrow + 8 * lg);
  bf16x8 qf1 = pack8(qrow + 32 + 8 * lg);

  f32x4 oacc[4] = {};
  float mrun = -1e30f, lrun = 0.f;
  const int ibase = i0 + w * 16 + li;
  unsigned short* PTw = PT_lds + w * 16 * 68;

  for (int j0 = 0; j0 < SEQL; j0 += 64) {
    __syncthreads();
    {
      int jl = tid >> 4;
      int dq = (tid & 15) * 4;
      #pragma unroll
      for (int rr = 0; rr < 4; rr++) {
        int jj = jl + rr * 16;
        long grow = ((long)(b * SEQL + j0 + jj)) * DD + h * 64 + dq;
        float4 kv = *(const float4*)(k + grow);
        short4v kp = { (short)f2bf(kv.x), (short)f2bf(kv.y), (short)f2bf(kv.z), (short)f2bf(kv.w) };
        *(short4v*)(K_lds + jj * 68 + dq) = kp;
        float4 vvv = *(const float4*)(vv + grow);
        VT_lds[(dq + 0) * 68 + jj] = f2bf(vvv.x);
        VT_lds[(dq + 1) * 68 + jj] = f2bf(vvv.y);
        VT_lds[(dq + 2) * 68 + jj] = f2bf(vvv.z);
        VT_lds[(dq + 3) * 68 + jj] = f2bf(vvv.w);
      }
      if (tid < 64) uk_s[tid] = uk[(long)bh * SEQL + j0 + tid];
    }
    __syncthreads();

    f32x4 sf[4];
    #pragma unroll
    for (int jj = 0; jj < 4; jj++) {
      f32x4 c = {};
      c = __builtin_amdgcn_mfma_f32_16x16x32_bf16(
            ld_frag(K_lds + (jj * 16 + li) * 68 + 8 * lg), qf0, c, 0, 0, 0);
      c = __builtin_amdgcn_mfma_f32_16x16x32_bf16(
            ld_frag(K_lds + (jj * 16 + li) * 68 + 32 + 8 * lg), qf1, c, 0, 0, 0);
      sf[jj] = c;
    }

    float sv[4][4];
    float tmax = -1e30f;
    const float* crow = comb + (w * 16 + li) * 34;
    #pragma unroll
    for (int jj = 0; jj < 4; jj++) {
      #pragma unroll
      for (int r = 0; r < 4; r++) {
        int jloc = jj * 16 + 4 * lg + r;
        int di = (j0 + jloc) - ibase;
        int ad = di < 0 ? -di : di;
        float sg = di > 0 ? 1.f : (di < 0 ? -1.f : 0.f);
        int n0 = n0_s[ad];
        float val = (sf[jj][r] + crow[n0] + sg * crow[17 + n0] + uk_s[jloc]) * 0.125f;
        sv[jj][r] = val;
        tmax = fmaxf(tmax, val);
      }
    }
    tmax = fmaxf(tmax, __shfl_xor(tmax, 16));
    tmax = fmaxf(tmax, __shfl_xor(tmax, 32));
    float mnew = fmaxf(mrun, tmax);
    float fsc = __expf(mrun - mnew);
    mrun = mnew;
    lrun *= fsc;
    #pragma unroll
    for (int df = 0; df < 4; df++) oacc[df] *= fsc;

    float psum = 0.f;
    #pragma unroll
    for (int jj = 0; jj < 4; jj++) {
      short4v pk;
      #pragma unroll
      for (int r = 0; r < 4; r++) {
        float p = __expf(sv[jj][r] - mnew);
        psum += p;
        pk[r] = (short)f2bf(p);
      }
      *(short4v*)(PTw + li * 68 + jj * 16 + 4 * lg) = pk;
    }
    psum += __shfl_xor(psum, 16);
    psum += __shfl_xor(psum, 32);
    lrun += psum;

    asm volatile("s_waitcnt lgkmcnt(0)" ::: "memory");

    bf16x8 pf0 = ld_frag(PTw + li * 68 + 8 * lg);
    bf16x8 pf1 = ld_frag(PTw + li * 68 + 32 + 8 * lg);
    #pragma unroll
    for (int df = 0; df < 4; df++) {
      f32x4 c = oacc[df];
      c = __builtin_amdgcn_mfma_f32_16x16x32_bf16(
            ld_frag(VT_lds + (df * 16 + li) * 68 + 8 * lg), pf0, c, 0, 0, 0);
      c = __builtin_amdgcn_mfma_f32_16x16x32_bf16(
            ld_frag(VT_lds + (df * 16 + li) * 68 + 32 + 8 * lg), pf1, c, 0, 0, 0);
      oacc[df] = c;
    }
  }

  __syncthreads();
  float inv = 1.f / lrun;
  #pragma unroll
  for (int df = 0; df < 4; df++) {
    f32x4 o = oacc[df] * inv;
    *(f32x4*)(O_lds + (w * 16 + li) * 68 + df * 16 + 4 * lg) = o;
  }
  __syncthreads();
  {
    int il = tid >> 2, c0 = (tid & 3) * 16;
    long orow = ((long)(b * SEQL + i0 + il)) * DD + h * 64 + c0;
    #pragma unroll
    for (int c4 = 0; c4 < 4; c4++) {
      f32x4 o = *(const f32x4*)(O_lds + il * 68 + c0 + c4 * 4);
      *(f32x4*)(out + orow + c4 * 4) = o;
    }
  }
}

// ---------------------------------------------------------------- launch
extern "C" void kernel_launch(void* const* d_in, const int* in_sizes, int n_in,
                              void* d_out, int out_size, void* d_ws, size_t ws_size,
                              hipStream_t stream) {
  const float* x_in     = (const float*)d_in[0];
  const float* rms_m    = (const float*)d_in[1];
  const float* W_in     = (const float*)d_in[2];
  const float* b_in     = (const float*)d_in[3];
  const float* m_Win    = (const float*)d_in[4];
  const float* m_conv_w = (const float*)d_in[5];
  const float* m_conv_b = (const float*)d_in[6];
  const float* m_Wx     = (const float*)d_in[7];
  const float* m_Wdt    = (const float*)d_in[8];
  const float* m_bdt    = (const float*)d_in[9];
  const float* m_Alog   = (const float*)d_in[10];
  const float* m_Dp     = (const float*)d_in[11];
  const float* m_Wout   = (const float*)d_in[12];
  const float* W_out    = (const float*)d_in[13];
  const float* b_out    = (const float*)d_in[14];
  const float* rms_a    = (const float*)d_in[15];
  const float* Wq       = (const float*)d_in[16];
  const float* Wk       = (const float*)d_in[17];
  const float* Wv       = (const float*)d_in[18];
  const float* u_p      = (const float*)d_in[19];
  const float* v_p      = (const float*)d_in[20];
  const float* w_rel    = (const float*)d_in[21];
  const float* Wo       = (const float*)d_in[22];
  const float* b_o      = (const float*)d_in[23];
  float* out = (float*)d_out;

  float* ws = (float*)d_ws;
  const long U = (long)BB * SEQL * DD;      // 1,048,576 floats
  float* xA    = ws;
  float* xB    = ws + 1 * U;
  float* xn    = ws + 2 * U;                // also scan P/Hend scratch
  float* proj  = ws + 3 * U;                // 3U; later q,k,v
  float* xz    = ws + 6 * U;                // 4U; later yp (2U)
  float* xc    = ws + 10 * U;               // 2U
  float* dtv   = ws + 12 * U;               // 2U
  float* ym    = ws + 14 * U;               // 2U; later attnout
  float* ycomb = ws + 16 * U;               // 1U; also scan Hin scratch
  float* smallb= ws + 17 * U;               // 1U of small buffers
  float* dbl   = smallb;                    // 262144
  float* ukbuf = smallb + 262144;           // 16384
  float* Sbuf  = smallb + 278528;           // 557056
  float* VSbuf = smallb + 835584;           // 272
  int*   n0tab = (int*)(smallb + 835856);   // 1024
  unsigned short* WTbuf = (unsigned short*)(ws + 18 * U);  // <=1,048,576 bf16
  float* yp = xz;
  float* qb = proj;
  float* kb = proj + U;
  float* vb = proj + 2 * U;
  float* attnout = ym;
  float* Pbuf = xn;
  float* Hend = xn + (long)NC * NR;
  float* Hin  = ycomb;

  const int M = BB * SEQL;                  // 2048

  n0_kernel<<<4, 256, 0, stream>>>(n0tab);

  for (int layer = 0; layer < LL; layer++) {
    const float* cur = (layer == 0) ? x_in : xA;
    // ---- mamba block ----
    rms_kernel<<<M, 256, 0, stream>>>(cur, rms_m + layer * DD, xn);

    wtrans_kernel<<<dim3(48, 16, 1), 256, 0, stream>>>(W_in + (long)layer * DD * 3 * DD, WTbuf, DD, 3 * DD);
    gemm_bf16<<<dim3(12, 16, 1), 256, 0, stream>>>(xn, WTbuf,
        b_in + layer * 3 * DD, nullptr, proj, M, 3 * DD, DD, DD, 3 * DD, 0, 0, 0, 0, 0, 0);

    wtrans_kernel<<<dim3(32, 16, 2), 256, 0, stream>>>(m_Win + (long)layer * 2 * DD * 2 * DD, WTbuf, DD, 2 * DD);
    gemm_bf16<<<dim3(8, 16, 2), 256, 0, stream>>>(proj, WTbuf,
        nullptr, nullptr, xz, M, 2 * DD, DD, 3 * DD, 2 * DD,
        0, (long)DD * 2 * DD, 0, (long)BB * SEQL * 2 * DD, SEQL, 0);

    conv_silu_kernel<<<(2 * BB * SEQL * DD) / 256, 256, 0, stream>>>(xz, m_conv_w, m_conv_b, xc, layer);
    gemm_f32<<<dim3(1, 32, 2), 256, 0, stream>>>(xc, m_Wx + (long)layer * 2 * DD * 64,
        nullptr, nullptr, dbl, M, 64, DD, DD, 64,
        U, (long)DD * 64, 0, (long)BB * SEQL * 64, 0, 0);
    gemm_f32<<<dim3(8, 32, 2), 256, 0, stream>>>(dbl, m_Wdt + (long)layer * 2 * DTRR * DD,
        m_bdt + (long)layer * 2 * DD, nullptr, dtv, M, DD, DTRR, 64, DD,
        (long)BB * SEQL * 64, (long)DTRR * DD, DD, U, 0, 1);
    scan_chunk_kernel<<<dim3(NC, DD / 16, GBS), 256, 0, stream>>>(
        dtv, xc, dbl, m_Alog, Pbuf, Hend, layer);
    scan_combine_kernel<<<NR / 256, 256, 0, stream>>>(Pbuf, Hend, Hin);
    scan_apply_kernel<<<dim3(NC, DD / 16, GBS), 256, 0, stream>>>(
        dtv, xc, xz, dbl, m_Alog, m_Dp, Hin, ym, layer);

    wtrans_kernel<<<dim3(16, 16, 2), 256, 0, stream>>>(m_Wout + (long)layer * 2 * DD * DD, WTbuf, DD, DD);
    gemm_bf16<<<dim3(4, 16, 2), 256, 0, stream>>>(ym, WTbuf,
        nullptr, nullptr, yp, M, DD, DD, DD, DD, U, (long)DD * DD, 0, U, 0, 0);

    combine_kernel<<<(int)(U / 256), 256, 0, stream>>>(yp, proj, ycomb);

    wtrans_kernel<<<dim3(16, 16, 1), 256, 0, stream>>>(W_out + (long)layer * DD * DD, WTbuf, DD, DD);
    gemm_bf16<<<dim3(4, 16, 1), 256, 0, stream>>>(ycomb, WTbuf,
        b_out + layer * DD, cur, xB, M, DD, DD, DD, DD, 0, 0, 0, 0, 0, 0);

    // ---- attention block ----
    rms_kernel<<<M, 256, 0, stream>>>(xB, rms_a + layer * DD, xn);
    wtrans_kernel<<<dim3(16, 16, 1), 256, 0, stream>>>(Wq + (long)layer * DD * DD, WTbuf, DD, DD);
    wtrans_kernel<<<dim3(16, 16, 1), 256, 0, stream>>>(Wk + (long)layer * DD * DD, WTbuf + 262144, DD, DD);
    wtrans_kernel<<<dim3(16, 16, 1), 256, 0, stream>>>(Wv + (long)layer * DD * DD, WTbuf + 524288, DD, DD);
    gemm_bf16<<<dim3(4, 16, 3), 256, 0, stream>>>(xn, WTbuf,
        nullptr, nullptr, qb, M, DD, DD, DD, DD, 0, 262144, 0, U, 0, 0);

    qw_suffix_kernel<<<BB * HH * SEQL, 64, 0, stream>>>(qb, w_rel, Sbuf, layer);
    vw_kernel<<<1, 256, 0, stream>>>(v_p, w_rel, VSbuf, layer);
    uk_kernel<<<(BB * HH * SEQL) / 4, 256, 0, stream>>>(u_p, kb, ukbuf, layer);
    attn_mfma_kernel<<<dim3(SEQL / 64, BB * HH), 256, 0, stream>>>(
        qb, kb, vb, Sbuf, VSbuf, ukbuf, n0tab, attnout);

    float* outp = (layer == LL - 1) ? out : xA;
    wtrans_kernel<<<dim3(16, 16, 1), 256, 0, stream>>>(Wo + (long)layer * DD * DD, WTbuf, DD, DD);
    gemm_bf16<<<dim3(4, 16, 1), 256, 0, stream>>>(attnout, WTbuf,
        b_o + layer * DD, xB, outp, M, DD, DD, DD, DD, 0, 0, 0, 0, 0, 0);
  }
}

// Round 5
// 933.541 us; speedup vs baseline: 5.2127x; 1.1155x over previous
//
#include <hip/hip_runtime.h>

#define LL 2
#define BB 2
#define SEQL 1024
#define DD 512
#define NN 16
#define HH 8
#define DHH 64
#define PPB 32
#define KCC 4
#define DTRR 32

#define GBS 4              // g*BB+b combinations
#define TC 64              // scan chunk length
#define NC (SEQL / TC)     // 16 chunks
#define NR (GBS * DD * NN) // 32768 recurrences

typedef __attribute__((ext_vector_type(8))) short bf16x8;
typedef __attribute__((ext_vector_type(4))) short short4v;
typedef __attribute__((ext_vector_type(4))) float f32x4;

__device__ __forceinline__ float siluf(float x) { return x / (1.f + expf(-x)); }
__device__ __forceinline__ float softplusf(float x) { return x > 20.f ? x : log1pf(expf(x)); }

__device__ __forceinline__ unsigned short f2bf(float x) {
  union { float f; unsigned u; } v; v.f = x;
  unsigned r = v.u + 0x7fff + ((v.u >> 16) & 1);
  return (unsigned short)(r >> 16);
}

__device__ __forceinline__ bf16x8 ld_frag(const unsigned short* p) {
  short4v a = *(const short4v*)(p);
  short4v b = *(const short4v*)(p + 4);
  bf16x8 r;
  r[0]=a[0]; r[1]=a[1]; r[2]=a[2]; r[3]=a[3];
  r[4]=b[0]; r[5]=b[1]; r[6]=b[2]; r[7]=b[3];
  return r;
}

__device__ __forceinline__ bf16x8 pack8(const float* p) {
  bf16x8 r;
  #pragma unroll
  for (int e = 0; e < 8; e++) r[e] = (short)f2bf(p[e]);
  return r;
}

// ---------------------------------------------------------------- weight transpose fp32[K][N] -> bf16[N][K]
__global__ __launch_bounds__(256) void wtrans_kernel(
    const float* __restrict__ W, unsigned short* __restrict__ WT, int K, int N)
{
  int g = blockIdx.z;
  W  += (long)g * K * N;
  WT += (long)g * K * N;
  __shared__ float t[32][33];
  int tx = threadIdx.x & 31, ty = threadIdx.x >> 5;
  int n0 = blockIdx.x * 32, k0 = blockIdx.y * 32;
  #pragma unroll
  for (int i = 0; i < 4; i++)
    t[ty + 8 * i][tx] = W[(long)(k0 + ty + 8 * i) * N + n0 + tx];
  __syncthreads();
  #pragma unroll
  for (int i = 0; i < 4; i++)
    WT[(long)(n0 + ty + 8 * i) * K + k0 + tx] = f2bf(t[tx][ty + 8 * i]);
}

// ---------------------------------------------------------------- Weff = Wx[:, :32] @ Wdt  ->  WT2[n][k] bf16
__global__ __launch_bounds__(256) void weff_kernel(
    const float* __restrict__ Wx, const float* __restrict__ Wdt,
    unsigned short* __restrict__ WT2, int layer)
{
  int g = blockIdx.z;
  const float* wx = Wx + (long)(layer * 2 + g) * DD * 64;
  const float* wd = Wdt + (long)(layer * 2 + g) * DTRR * DD;
  unsigned short* wt = WT2 + (long)g * 640 * DD;
  int n0 = blockIdx.x * 32, k0 = blockIdx.y * 32;
  __shared__ float wx_s[32][33];   // [k_local][r]
  __shared__ float wd_s[32][33];   // [r][n_local]
  int tx = threadIdx.x & 31, ty = threadIdx.x >> 5;
  #pragma unroll
  for (int i = 0; i < 4; i++) {
    wx_s[ty + 8 * i][tx] = wx[(long)(k0 + ty + 8 * i) * 64 + tx];
    wd_s[ty + 8 * i][tx] = wd[(long)(ty + 8 * i) * DD + n0 + tx];
  }
  __syncthreads();
  #pragma unroll
  for (int i = 0; i < 4; i++) {
    int nl = ty + 8 * i;
    float s = 0.f;
    #pragma unroll
    for (int r = 0; r < 32; r++) s = fmaf(wx_s[tx][r], wd_s[r][nl], s);
    wt[(long)(n0 + nl) * DD + k0 + tx] = f2bf(s);
  }
}

// ---------------------------------------------------------------- WT2[512+n][k] = Wx[k][32+n] (B/C slab)
__global__ __launch_bounds__(256) void wbc_kernel(
    const float* __restrict__ Wx, unsigned short* __restrict__ WT2, int layer)
{
  int g = blockIdx.y;
  const float* wx = Wx + (long)(layer * 2 + g) * DD * 64;
  unsigned short* wt = WT2 + (long)g * 640 * DD;
  int k0 = blockIdx.x * 32;
  __shared__ float t[32][33];
  int tx = threadIdx.x & 31, ty = threadIdx.x >> 5;
  #pragma unroll
  for (int i = 0; i < 4; i++)
    t[ty + 8 * i][tx] = wx[(long)(k0 + ty + 8 * i) * 64 + 32 + tx];
  __syncthreads();
  #pragma unroll
  for (int i = 0; i < 4; i++)
    wt[(long)(512 + ty + 8 * i) * DD + k0 + tx] = f2bf(t[tx][ty + 8 * i]);
}

// ---------------------------------------------------------------- GEMM (bf16 MFMA)
// C[m,n] = A[m,:] (fp32, cvt) . WT[n,:] (bf16) ; 128x128 tile, BK=64, 4 waves.
__global__ __launch_bounds__(256) void gemm_bf16(
    const float* __restrict__ A, const unsigned short* __restrict__ WT,
    const float* __restrict__ bias, const float* __restrict__ resid,
    float* __restrict__ C,
    int M, int N, int K, int lda, int ldc,
    long aBatch, long wBatch, long biasBatch, long cBatch,
    int aflipL, int act)
{
  int g = blockIdx.z;
  A  += (long)g * aBatch;
  WT += (long)g * wBatch;
  C  += (long)g * cBatch;
  if (bias) bias += (long)g * biasBatch;
  const bool flip = (aflipL > 0) && (g == 1);

  __shared__ unsigned short A_lds[128][72];
  __shared__ unsigned short B_lds[128][72];
  int tid = threadIdx.x;
  int w = tid >> 6, lane = tid & 63, li = lane & 15, lg = lane >> 4;
  int bm = blockIdx.y * 128, bn = blockIdx.x * 128;
  int wm = (w & 1) * 64, wn = (w >> 1) * 64;
  f32x4 acc[4][4] = {};

  const int kqA = (tid & 15) * 4, r0A = tid >> 4;
  const int kqB = (tid & 7) * 8,  r0B = tid >> 3;

  for (int k0 = 0; k0 < K; k0 += 64) {
    __syncthreads();
    #pragma unroll
    for (int i = 0; i < 8; i++) {
      int m = bm + r0A + 16 * i;
      int mm = m;
      if (flip) { int bb = m / aflipL; int t = m - bb * aflipL; mm = bb * aflipL + (aflipL - 1 - t); }
      float4 av = *(const float4*)(A + (long)mm * lda + k0 + kqA);
      short4v ap = { (short)f2bf(av.x), (short)f2bf(av.y), (short)f2bf(av.z), (short)f2bf(av.w) };
      *(short4v*)(&A_lds[r0A + 16 * i][kqA]) = ap;
    }
    #pragma unroll
    for (int i = 0; i < 4; i++) {
      int n = bn + r0B + 32 * i;
      bf16x8 bv = *(const bf16x8*)(WT + (long)n * K + k0 + kqB);
      *(bf16x8*)(&B_lds[r0B + 32 * i][kqB]) = bv;
    }
    __syncthreads();
    #pragma unroll
    for (int ks = 0; ks < 2; ks++) {
      bf16x8 af[4], bfr[4];
      #pragma unroll
      for (int fm = 0; fm < 4; fm++)
        af[fm] = *(const bf16x8*)(&A_lds[wm + fm * 16 + li][ks * 32 + lg * 8]);
      #pragma unroll
      for (int fn = 0; fn < 4; fn++)
        bfr[fn] = *(const bf16x8*)(&B_lds[wn + fn * 16 + li][ks * 32 + lg * 8]);
      #pragma unroll
      for (int fm = 0; fm < 4; fm++)
        #pragma unroll
        for (int fn = 0; fn < 4; fn++)
          acc[fm][fn] = __builtin_amdgcn_mfma_f32_16x16x32_bf16(af[fm], bfr[fn], acc[fm][fn], 0, 0, 0);
    }
  }
  #pragma unroll
  for (int fm = 0; fm < 4; fm++) {
    #pragma unroll
    for (int fn = 0; fn < 4; fn++) {
      int n = bn + wn + fn * 16 + li;
      float bv = bias ? bias[n] : 0.f;
      #pragma unroll
      for (int r = 0; r < 4; r++) {
        int m = bm + wm + fm * 16 + 4 * lg + r;
        float v = acc[fm][fn][r] + bv;
        if (act == 1) v = softplusf(v);
        if (resid) v += resid[(long)m * ldc + n];
        C[(long)m * ldc + n] = v;
      }
    }
  }
}

// ---------------------------------------------------------------- fused dt/B/C GEMM
// A = xc (fp32), WT2 = [640][512] bf16 per dir (rows 0-511 Weff^T, 512-543 Wx_BC^T).
// n<512: dtv[m][n] = softplus(acc + bdt[n]); 512<=n<544: bc[m][n-512] = acc.
__global__ __launch_bounds__(256) void gemm_dtbc(
    const float* __restrict__ A, const unsigned short* __restrict__ WT2,
    const float* __restrict__ bdt, float* __restrict__ dtv, float* __restrict__ bc,
    int layer)
{
  int g = blockIdx.z;
  A   += (long)g * BB * SEQL * DD;
  WT2 += (long)g * 640 * DD;
  dtv += (long)g * BB * SEQL * DD;
  bc  += (long)g * BB * SEQL * 32;
  bdt += (long)(layer * 2 + g) * DD;

  __shared__ unsigned short A_lds[128][72];
  __shared__ unsigned short B_lds[128][72];
  int tid = threadIdx.x;
  int w = tid >> 6, lane = tid & 63, li = lane & 15, lg = lane >> 4;
  int bm = blockIdx.y * 128, bn = blockIdx.x * 128;
  int wm = (w & 1) * 64, wn = (w >> 1) * 64;
  f32x4 acc[4][4] = {};

  const int kqA = (tid & 15) * 4, r0A = tid >> 4;
  const int kqB = (tid & 7) * 8,  r0B = tid >> 3;

  for (int k0 = 0; k0 < DD; k0 += 64) {
    __syncthreads();
    #pragma unroll
    for (int i = 0; i < 8; i++) {
      int m = bm + r0A + 16 * i;
      float4 av = *(const float4*)(A + (long)m * DD + k0 + kqA);
      short4v ap = { (short)f2bf(av.x), (short)f2bf(av.y), (short)f2bf(av.z), (short)f2bf(av.w) };
      *(short4v*)(&A_lds[r0A + 16 * i][kqA]) = ap;
    }
    #pragma unroll
    for (int i = 0; i < 4; i++) {
      int n = bn + r0B + 32 * i;     // <= 639: within WT2 allocation
      bf16x8 bv = *(const bf16x8*)(WT2 + (long)n * DD + k0 + kqB);
      *(bf16x8*)(&B_lds[r0B + 32 * i][kqB]) = bv;
    }
    __syncthreads();
    #pragma unroll
    for (int ks = 0; ks < 2; ks++) {
      bf16x8 af[4], bfr[4];
      #pragma unroll
      for (int fm = 0; fm < 4; fm++)
        af[fm] = *(const bf16x8*)(&A_lds[wm + fm * 16 + li][ks * 32 + lg * 8]);
      #pragma unroll
      for (int fn = 0; fn < 4; fn++)
        bfr[fn] = *(const bf16x8*)(&B_lds[wn + fn * 16 + li][ks * 32 + lg * 8]);
      #pragma unroll
      for (int fm = 0; fm < 4; fm++)
        #pragma unroll
        for (int fn = 0; fn < 4; fn++)
          acc[fm][fn] = __builtin_amdgcn_mfma_f32_16x16x32_bf16(af[fm], bfr[fn], acc[fm][fn], 0, 0, 0);
    }
  }
  #pragma unroll
  for (int fm = 0; fm < 4; fm++) {
    #pragma unroll
    for (int fn = 0; fn < 4; fn++) {
      int n = bn + wn + fn * 16 + li;
      if (n < 512) {
        float bv = bdt[n];
        #pragma unroll
        for (int r = 0; r < 4; r++) {
          int m = bm + wm + fm * 16 + 4 * lg + r;
          dtv[(long)m * DD + n] = softplusf(acc[fm][fn][r] + bv);
        }
      } else if (n < 544) {
        #pragma unroll
        for (int r = 0; r < 4; r++) {
          int m = bm + wm + fm * 16 + 4 * lg + r;
          bc[(long)m * 32 + (n - 512)] = acc[fm][fn][r];
        }
      }
    }
  }
}

// ---------------------------------------------------------------- RMS norm
__global__ __launch_bounds__(256) void rms_kernel(
    const float* __restrict__ x, const float* __restrict__ w, float* __restrict__ out)
{
  int row = blockIdx.x;
  const float* xr = x + (long)row * DD;
  int tid = threadIdx.x;
  float v0 = xr[tid], v1 = xr[tid + 256];
  float s = v0 * v0 + v1 * v1;
  for (int o = 32; o; o >>= 1) s += __shfl_down(s, o);
  __shared__ float sm[4];
  if ((tid & 63) == 0) sm[tid >> 6] = s;
  __syncthreads();
  float tot = sm[0] + sm[1] + sm[2] + sm[3];
  float inv = rsqrtf(tot / (float)DD + 1e-6f);
  out[(long)row * DD + tid] = v0 * inv * w[tid];
  out[(long)row * DD + tid + 256] = v1 * inv * w[tid + 256];
}

// ---------------------------------------------------------------- conv + SiLU
__global__ __launch_bounds__(256) void conv_silu_kernel(
    const float* __restrict__ xz, const float* __restrict__ cw, const float* __restrict__ cb,
    float* __restrict__ xc, int layer)
{
  long idx = (long)blockIdx.x * 256 + threadIdx.x;  // (g,b,t,c)
  int c = idx % DD;
  long r = idx / DD;
  int t = r % SEQL;
  long gb = r / SEQL;
  int g = (int)(gb / BB);
  const float* w = cw + ((long)(layer * 2 + g) * DD + c) * KCC;
  float acc = cb[(long)(layer * 2 + g) * DD + c];
  const float* xp = xz + (r - t) * 2 * DD + c;
  #pragma unroll
  for (int k = 0; k < KCC; k++) {
    int tt = t - (KCC - 1) + k;
    if (tt >= 0) acc = fmaf(xp[(long)tt * 2 * DD], w[k], acc);
  }
  xc[idx] = siluf(acc);
}

// ---------------------------------------------------------------- chunked scan
__global__ __launch_bounds__(256) void scan_chunk_kernel(
    const float* __restrict__ dtv, const float* __restrict__ xc,
    const float* __restrict__ bc, const float* __restrict__ Alog,
    float* __restrict__ P, float* __restrict__ Hend, int layer)
{
  int chunk = blockIdx.x, dtile = blockIdx.y, gb = blockIdx.z;
  int g = gb / BB;
  int tid = threadIdx.x;
  int n = tid & 15, dl = tid >> 4;
  int d = dtile * 16 + dl;
  int t0 = chunk * TC;
  __shared__ float dtv_s[TC][16], xc_s[TC][16], B_s[TC][17];
  {
    int c = tid & 15, rr = tid >> 4;
    long base = ((long)gb * SEQL + t0) * DD + dtile * 16;
    long dbase = ((long)gb * SEQL + t0) * 32;
    #pragma unroll
    for (int i = 0; i < 4; i++) {
      int tl = rr + i * 16;
      dtv_s[tl][c] = dtv[base + (long)tl * DD + c];
      xc_s[tl][c]  = xc[base + (long)tl * DD + c];
      B_s[tl][c]   = bc[dbase + (long)tl * 32 + c];
    }
  }
  __syncthreads();
  float a = -expf(Alog[((long)((layer * 2 + g) * DD) + d) * NN + n]);
  float h = 0.f, sdt = 0.f;
  #pragma unroll 4
  for (int t = 0; t < TC; t++) {
    float dt = dtv_s[t][dl];
    float dA = expf(dt * a);
    h = fmaf(dA, h, dt * B_s[t][n] * xc_s[t][dl]);
    sdt += dt;
  }
  int r = (gb * DD + d) * NN + n;
  long o = (long)chunk * NR + r;
  P[o] = expf(a * sdt);
  Hend[o] = h;
}

__global__ __launch_bounds__(256) void scan_combine_kernel(
    const float* __restrict__ P, const float* __restrict__ Hend, float* __restrict__ Hin)
{
  int r = blockIdx.x * 256 + threadIdx.x;
  float h = 0.f;
  #pragma unroll
  for (int c = 0; c < NC; c++) {
    Hin[(long)c * NR + r] = h;
    h = fmaf(P[(long)c * NR + r], h, Hend[(long)c * NR + r]);
  }
}

__global__ __launch_bounds__(256) void scan_apply_kernel(
    const float* __restrict__ dtv, const float* __restrict__ xc, const float* __restrict__ xz,
    const float* __restrict__ bc, const float* __restrict__ Alog, const float* __restrict__ Dp,
    const float* __restrict__ Hin, float* __restrict__ ym, int layer)
{
  int chunk = blockIdx.x, dtile = blockIdx.y, gb = blockIdx.z;
  int g = gb / BB;
  int tid = threadIdx.x;
  int n = tid & 15, dl = tid >> 4;
  int d = dtile * 16 + dl;
  int t0 = chunk * TC;
  __shared__ float dtv_s[TC][16], xc_s[TC][16], B_s[TC][17], C_s[TC][17], y_s[TC][16];
  {
    int c = tid & 15, rr = tid >> 4;
    long base = ((long)gb * SEQL + t0) * DD + dtile * 16;
    long dbase = ((long)gb * SEQL + t0) * 32;
    #pragma unroll
    for (int i = 0; i < 4; i++) {
      int tl = rr + i * 16;
      dtv_s[tl][c] = dtv[base + (long)tl * DD + c];
      xc_s[tl][c]  = xc[base + (long)tl * DD + c];
      B_s[tl][c]   = bc[dbase + (long)tl * 32 + c];
      C_s[tl][c]   = bc[dbase + (long)tl * 32 + 16 + c];
    }
  }
  __syncthreads();
  float a = -expf(Alog[((long)((layer * 2 + g) * DD) + d) * NN + n]);
  int r = (gb * DD + d) * NN + n;
  float h = Hin[(long)chunk * NR + r];
  #pragma unroll 4
  for (int t = 0; t < TC; t++) {
    float dt = dtv_s[t][dl];
    float dA = expf(dt * a);
    h = fmaf(dA, h, dt * B_s[t][n] * xc_s[t][dl]);
    float val = h * C_s[t][n];
    val += __shfl_xor(val, 1);
    val += __shfl_xor(val, 2);
    val += __shfl_xor(val, 4);
    val += __shfl_xor(val, 8);
    if (n == 0) y_s[t][dl] = val;
  }
  __syncthreads();
  {
    int c = tid & 15, rr = tid >> 4;
    long base = ((long)gb * SEQL + t0) * DD + dtile * 16;
    long zbase = ((long)gb * SEQL + t0) * 2 * DD + DD + dtile * 16;
    float Dpc = Dp[(long)(layer * 2 + g) * DD + dtile * 16 + c];
    #pragma unroll
    for (int i = 0; i < 4; i++) {
      int tl = rr + i * 16;
      float z = xz[zbase + (long)tl * 2 * DD + c];
      ym[base + (long)tl * DD + c] = (y_s[tl][c] + Dpc * xc_s[tl][c]) * siluf(z);
    }
  }
}

// ---------------------------------------------------------------- dir combine
__global__ __launch_bounds__(256) void combine_kernel(
    const float* __restrict__ yp, const float* __restrict__ proj, float* __restrict__ yc)
{
  long idx = (long)blockIdx.x * 256 + threadIdx.x;  // (b,t,d)
  int d = idx % DD;
  long r = idx / DD;
  int t = r % SEQL;
  long b = r / SEQL;
  float y0 = yp[idx];
  float y1 = yp[(long)BB * SEQL * DD + (b * SEQL + (SEQL - 1 - t)) * (long)DD + d];
  const float* pr = proj + r * 3 * DD;
  float zf = pr[DD + d];
  float zr = pr[2 * DD + d];
  yc[idx] = y0 * siluf(zf) + y1 * siluf(zr);
}

// ---------------------------------------------------------------- attention prep
__global__ void n0_kernel(int* __restrict__ n0tab)
{
  int d = blockIdx.x * blockDim.x + threadIdx.x;
  if (d >= SEQL) return;
  float pr = expf(logf((SEQL + 1) * 0.5f) / 16.0f);
  int n0 = 16;
  for (int n = 15; n >= 0; n--) {
    float cw = powf(pr, (float)(n + 1));
    if ((float)d <= cw) n0 = n;
  }
  n0tab[d] = n0;
}

__global__ __launch_bounds__(64) void qw_suffix_kernel(
    const float* __restrict__ q, const float* __restrict__ w_rel, float* __restrict__ S, int layer)
{
  int idx = blockIdx.x;           // (b*HH + h)*SEQL + i
  int i = idx % SEQL;
  int bh = idx / SEQL;
  int h = bh % HH;
  int b = bh / HH;
  __shared__ float qs[64];
  __shared__ float qwn[32];
  int tid = threadIdx.x;
  qs[tid] = q[((long)(b * SEQL + i) * HH + h) * DHH + tid];
  __syncthreads();
  if (tid < 32) {
    const float* wp = w_rel + ((long)(layer * HH + h) * DHH) * PPB + tid;
    float s = 0.f;
    #pragma unroll 8
    for (int d = 0; d < DHH; d++) s = fmaf(qs[d], wp[d * PPB], s);
    qwn[tid] = s;
  }
  __syncthreads();
  if (tid < 17) {
    float s1 = 0.f, s2 = 0.f;
    for (int n = tid; n < 16; n++) { s1 += qwn[n]; s2 += qwn[16 + n]; }
    float* Sp = S + (long)idx * 34;
    Sp[tid] = s1;
    Sp[17 + tid] = s2;
  }
}

__global__ __launch_bounds__(256) void vw_kernel(
    const float* __restrict__ vparam, const float* __restrict__ w_rel, float* __restrict__ VS, int layer)
{
  __shared__ float vws[HH][PPB];
  int tid = threadIdx.x;
  int h = tid / PPB, n = tid % PPB;
  const float* vp = vparam + (long)(layer * HH + h) * DHH;
  const float* wp = w_rel + ((long)(layer * HH + h) * DHH) * PPB + n;
  float s = 0.f;
  for (int d = 0; d < DHH; d++) s = fmaf(vp[d], wp[d * PPB], s);
  vws[h][n] = s;
  __syncthreads();
  if (tid < HH * 17) {
    int hh = tid / 17, m = tid % 17;
    float s1 = 0.f, s2 = 0.f;
    for (int nn = m; nn < 16; nn++) { s1 += vws[hh][nn]; s2 += vws[hh][16 + nn]; }
    VS[hh * 34 + m] = s1;
    VS[hh * 34 + 17 + m] = s2;
  }
}

__global__ __launch_bounds__(256) void uk_kernel(
    const float* __restrict__ u, const float* __restrict__ k, float* __restrict__ uk, int layer)
{
  int wid = (blockIdx.x * 256 + threadIdx.x) >> 6;
  int lane = threadIdx.x & 63;
  if (wid >= BB * HH * SEQL) return;
  int j = wid % SEQL;
  int bh = wid / SEQL;
  int h = bh % HH;
  int b = bh / HH;
  float vv = u[(long)(layer * HH + h) * DHH + lane] * k[((long)(b * SEQL + j) * HH + h) * DHH + lane];
  for (int o = 32; o; o >>= 1) vv += __shfl_down(vv, o);
  if (lane == 0) uk[(long)bh * SEQL + j] = vv;
}

// ---------------------------------------------------------------- MFMA attention
__global__ __launch_bounds__(256) void attn_mfma_kernel(
    const float* __restrict__ q, const float* __restrict__ k, const float* __restrict__ vv,
    const float* __restrict__ S, const float* __restrict__ VS, const float* __restrict__ uk,
    const int* __restrict__ n0tab, float* __restrict__ out)
{
  __shared__ __align__(16) char smem[39168];
  unsigned short* K_lds  = (unsigned short*)(smem);
  unsigned short* VT_lds = (unsigned short*)(smem + 8704);
  unsigned short* PT_lds = (unsigned short*)(smem + 17408);
  float* comb            = (float*)(smem + 26112);
  int*   n0_s            = (int*)(smem + 34816);
  float* uk_s            = (float*)(smem + 38912);
  float* O_lds           = (float*)(smem);

  int itile = blockIdx.x;
  int bh = blockIdx.y;
  int h = bh % HH, b = bh / HH;
  int i0 = itile * 64;
  int tid = threadIdx.x;
  int w = tid >> 6;
  int lane = tid & 63;
  int li = lane & 15, lg = lane >> 4;

  for (int idx = tid; idx < 64 * 17; idx += 256) {
    int il = idx / 17, m = idx % 17;
    long srow = ((long)bh * SEQL + i0 + il) * 34;
    comb[il * 34 + m]      = S[srow + m]      + VS[h * 34 + m];
    comb[il * 34 + 17 + m] = S[srow + 17 + m] + VS[h * 34 + 17 + m];
  }
  for (int idx = tid; idx < SEQL; idx += 256) n0_s[idx] = n0tab[idx];

  int iq = i0 + w * 16 + li;
  const float* qrow = q + ((long)(b * SEQL + iq)) * DD + h * 64;
  bf16x8 qf0 = pack8(qrow + 8 * lg);
  bf16x8 qf1 = pack8(qrow + 32 + 8 * lg);

  f32x4 oacc[4] = {};
  float mrun = -1e30f, lrun = 0.f;
  const int ibase = i0 + w * 16 + li;
  unsigned short* PTw = PT_lds + w * 16 * 68;

  for (int j0 = 0; j0 < SEQL; j0 += 64) {
    __syncthreads();
    {
      int jl = tid >> 4;
      int dq = (tid & 15) * 4;
      #pragma unroll
      for (int rr = 0; rr < 4; rr++) {
        int jj = jl + rr * 16;
        long grow = ((long)(b * SEQL + j0 + jj)) * DD + h * 64 + dq;
        float4 kv = *(const float4*)(k + grow);
        short4v kp = { (short)f2bf(kv.x), (short)f2bf(kv.y), (short)f2bf(kv.z), (short)f2bf(kv.w) };
        *(short4v*)(K_lds + jj * 68 + dq) = kp;
        float4 vvv = *(const float4*)(vv + grow);
        VT_lds[(dq + 0) * 68 + jj] = f2bf(vvv.x);
        VT_lds[(dq + 1) * 68 + jj] = f2bf(vvv.y);
        VT_lds[(dq + 2) * 68 + jj] = f2bf(vvv.z);
        VT_lds[(dq + 3) * 68 + jj] = f2bf(vvv.w);
      }
      if (tid < 64) uk_s[tid] = uk[(long)bh * SEQL + j0 + tid];
    }
    __syncthreads();

    f32x4 sf[4];
    #pragma unroll
    for (int jj = 0; jj < 4; jj++) {
      f32x4 c = {};
      c = __builtin_amdgcn_mfma_f32_16x16x32_bf16(
            ld_frag(K_lds + (jj * 16 + li) * 68 + 8 * lg), qf0, c, 0, 0, 0);
      c = __builtin_amdgcn_mfma_f32_16x16x32_bf16(
            ld_frag(K_lds + (jj * 16 + li) * 68 + 32 + 8 * lg), qf1, c, 0, 0, 0);
      sf[jj] = c;
    }

    float sv[4][4];
    float tmax = -1e30f;
    const float* crow = comb + (w * 16 + li) * 34;
    #pragma unroll
    for (int jj = 0; jj < 4; jj++) {
      #pragma unroll
      for (int r = 0; r < 4; r++) {
        int jloc = jj * 16 + 4 * lg + r;
        int di = (j0 + jloc) - ibase;
        int ad = di < 0 ? -di : di;
        float sg = di > 0 ? 1.f : (di < 0 ? -1.f : 0.f);
        int n0 = n0_s[ad];
        float val = (sf[jj][r] + crow[n0] + sg * crow[17 + n0] + uk_s[jloc]) * 0.125f;
        sv[jj][r] = val;
        tmax = fmaxf(tmax, val);
      }
    }
    tmax = fmaxf(tmax, __shfl_xor(tmax, 16));
    tmax = fmaxf(tmax, __shfl_xor(tmax, 32));
    float mnew = fmaxf(mrun, tmax);
    float fsc = __expf(mrun - mnew);
    mrun = mnew;
    lrun *= fsc;
    #pragma unroll
    for (int df = 0; df < 4; df++) oacc[df] *= fsc;

    float psum = 0.f;
    #pragma unroll
    for (int jj = 0; jj < 4; jj++) {
      short4v pk;
      #pragma unroll
      for (int r = 0; r < 4; r++) {
        float p = __expf(sv[jj][r] - mnew);
        psum += p;
        pk[r] = (short)f2bf(p);
      }
      *(short4v*)(PTw + li * 68 + jj * 16 + 4 * lg) = pk;
    }
    psum += __shfl_xor(psum, 16);
    psum += __shfl_xor(psum, 32);
    lrun += psum;

    asm volatile("s_waitcnt lgkmcnt(0)" ::: "memory");

    bf16x8 pf0 = ld_frag(PTw + li * 68 + 8 * lg);
    bf16x8 pf1 = ld_frag(PTw + li * 68 + 32 + 8 * lg);
    #pragma unroll
    for (int df = 0; df < 4; df++) {
      f32x4 c = oacc[df];
      c = __builtin_amdgcn_mfma_f32_16x16x32_bf16(
            ld_frag(VT_lds + (df * 16 + li) * 68 + 8 * lg), pf0, c, 0, 0, 0);
      c = __builtin_amdgcn_mfma_f32_16x16x32_bf16(
            ld_frag(VT_lds + (df * 16 + li) * 68 + 32 + 8 * lg), pf1, c, 0, 0, 0);
      oacc[df] = c;
    }
  }

  __syncthreads();
  float inv = 1.f / lrun;
  #pragma unroll
  for (int df = 0; df < 4; df++) {
    f32x4 o = oacc[df] * inv;
    *(f32x4*)(O_lds + (w * 16 + li) * 68 + df * 16 + 4 * lg) = o;
  }
  __syncthreads();
  {
    int il = tid >> 2, c0 = (tid & 3) * 16;
    long orow = ((long)(b * SEQL + i0 + il)) * DD + h * 64 + c0;
    #pragma unroll
    for (int c4 = 0; c4 < 4; c4++) {
      f32x4 o = *(const f32x4*)(O_lds + il * 68 + c0 + c4 * 4);
      *(f32x4*)(out + orow + c4 * 4) = o;
    }
  }
}

// ---------------------------------------------------------------- launch
extern "C" void kernel_launch(void* const* d_in, const int* in_sizes, int n_in,
                              void* d_out, int out_size, void* d_ws, size_t ws_size,
                              hipStream_t stream) {
  const float* x_in     = (const float*)d_in[0];
  const float* rms_m    = (const float*)d_in[1];
  const float* W_in     = (const float*)d_in[2];
  const float* b_in     = (const float*)d_in[3];
  const float* m_Win    = (const float*)d_in[4];
  const float* m_conv_w = (const float*)d_in[5];
  const float* m_conv_b = (const float*)d_in[6];
  const float* m_Wx     = (const float*)d_in[7];
  const float* m_Wdt    = (const float*)d_in[8];
  const float* m_bdt    = (const float*)d_in[9];
  const float* m_Alog   = (const float*)d_in[10];
  const float* m_Dp     = (const float*)d_in[11];
  const float* m_Wout   = (const float*)d_in[12];
  const float* W_out    = (const float*)d_in[13];
  const float* b_out    = (const float*)d_in[14];
  const float* rms_a    = (const float*)d_in[15];
  const float* Wq       = (const float*)d_in[16];
  const float* Wk       = (const float*)d_in[17];
  const float* Wv       = (const float*)d_in[18];
  const float* u_p      = (const float*)d_in[19];
  const float* v_p      = (const float*)d_in[20];
  const float* w_rel    = (const float*)d_in[21];
  const float* Wo       = (const float*)d_in[22];
  const float* b_o      = (const float*)d_in[23];
  float* out = (float*)d_out;

  float* ws = (float*)d_ws;
  const long U = (long)BB * SEQL * DD;      // 1,048,576 floats
  float* xA    = ws;
  float* xB    = ws + 1 * U;
  float* xn    = ws + 2 * U;                // also scan P/Hend scratch
  float* proj  = ws + 3 * U;                // 3U; later q,k,v
  float* xz    = ws + 6 * U;                // 4U; later yp (2U)
  float* xc    = ws + 10 * U;               // 2U
  float* dtv   = ws + 12 * U;               // 2U
  float* ym    = ws + 14 * U;               // 2U; later attnout
  float* ycomb = ws + 16 * U;               // 1U; also scan Hin scratch
  float* smallb= ws + 17 * U;               // 1U of small buffers
  float* bcbuf = smallb;                    // GBS*SEQL*32 = 131072
  float* ukbuf = smallb + 262144;           // 16384
  float* Sbuf  = smallb + 278528;           // 557056
  float* VSbuf = smallb + 835584;           // 272
  int*   n0tab = (int*)(smallb + 835856);   // 1024
  unsigned short* WTbuf = (unsigned short*)(ws + 18 * U);  // 2M bf16 capacity
  float* yp = xz;
  float* qb = proj;
  float* kb = proj + U;
  float* vb = proj + 2 * U;
  float* attnout = ym;
  float* Pbuf = xn;
  float* Hend = xn + (long)NC * NR;
  float* Hin  = ycomb;

  const int M = BB * SEQL;                  // 2048

  n0_kernel<<<4, 256, 0, stream>>>(n0tab);

  for (int layer = 0; layer < LL; layer++) {
    const float* cur = (layer == 0) ? x_in : xA;
    // ---- mamba block ----
    rms_kernel<<<M, 256, 0, stream>>>(cur, rms_m + layer * DD, xn);

    wtrans_kernel<<<dim3(48, 16, 1), 256, 0, stream>>>(W_in + (long)layer * DD * 3 * DD, WTbuf, DD, 3 * DD);
    gemm_bf16<<<dim3(12, 16, 1), 256, 0, stream>>>(xn, WTbuf,
        b_in + layer * 3 * DD, nullptr, proj, M, 3 * DD, DD, DD, 3 * DD, 0, 0, 0, 0, 0, 0);

    wtrans_kernel<<<dim3(32, 16, 2), 256, 0, stream>>>(m_Win + (long)layer * 2 * DD * 2 * DD, WTbuf, DD, 2 * DD);
    gemm_bf16<<<dim3(8, 16, 2), 256, 0, stream>>>(proj, WTbuf,
        nullptr, nullptr, xz, M, 2 * DD, DD, 3 * DD, 2 * DD,
        0, (long)DD * 2 * DD, 0, (long)BB * SEQL * 2 * DD, SEQL, 0);

    conv_silu_kernel<<<(2 * BB * SEQL * DD) / 256, 256, 0, stream>>>(xz, m_conv_w, m_conv_b, xc, layer);

    // fused dt/B/C: build composite weights, one MFMA GEMM
    weff_kernel<<<dim3(16, 16, 2), 256, 0, stream>>>(m_Wx, m_Wdt, WTbuf, layer);
    wbc_kernel<<<dim3(16, 2), 256, 0, stream>>>(m_Wx, WTbuf, layer);
    gemm_dtbc<<<dim3(5, 16, 2), 256, 0, stream>>>(xc, WTbuf, m_bdt, dtv, bcbuf, layer);

    scan_chunk_kernel<<<dim3(NC, DD / 16, GBS), 256, 0, stream>>>(
        dtv, xc, bcbuf, m_Alog, Pbuf, Hend, layer);
    scan_combine_kernel<<<NR / 256, 256, 0, stream>>>(Pbuf, Hend, Hin);
    scan_apply_kernel<<<dim3(NC, DD / 16, GBS), 256, 0, stream>>>(
        dtv, xc, xz, bcbuf, m_Alog, m_Dp, Hin, ym, layer);

    wtrans_kernel<<<dim3(16, 16, 2), 256, 0, stream>>>(m_Wout + (long)layer * 2 * DD * DD, WTbuf, DD, DD);
    gemm_bf16<<<dim3(4, 16, 2), 256, 0, stream>>>(ym, WTbuf,
        nullptr, nullptr, yp, M, DD, DD, DD, DD, U, (long)DD * DD, 0, U, 0, 0);

    combine_kernel<<<(int)(U / 256), 256, 0, stream>>>(yp, proj, ycomb);

    wtrans_kernel<<<dim3(16, 16, 1), 256, 0, stream>>>(W_out + (long)layer * DD * DD, WTbuf, DD, DD);
    gemm_bf16<<<dim3(4, 16, 1), 256, 0, stream>>>(ycomb, WTbuf,
        b_out + layer * DD, cur, xB, M, DD, DD, DD, DD, 0, 0, 0, 0, 0, 0);

    // ---- attention block ----
    rms_kernel<<<M, 256, 0, stream>>>(xB, rms_a + layer * DD, xn);
    wtrans_kernel<<<dim3(16, 16, 1), 256, 0, stream>>>(Wq + (long)layer * DD * DD, WTbuf, DD, DD);
    wtrans_kernel<<<dim3(16, 16, 1), 256, 0, stream>>>(Wk + (long)layer * DD * DD, WTbuf + 262144, DD, DD);
    wtrans_kernel<<<dim3(16, 16, 1), 256, 0, stream>>>(Wv + (long)layer * DD * DD, WTbuf + 524288, DD, DD);
    gemm_bf16<<<dim3(4, 16, 3), 256, 0, stream>>>(xn, WTbuf,
        nullptr, nullptr, qb, M, DD, DD, DD, DD, 0, 262144, 0, U, 0, 0);

    qw_suffix_kernel<<<BB * HH * SEQL, 64, 0, stream>>>(qb, w_rel, Sbuf, layer);
    vw_kernel<<<1, 256, 0, stream>>>(v_p, w_rel, VSbuf, layer);
    uk_kernel<<<(BB * HH * SEQL) / 4, 256, 0, stream>>>(u_p, kb, ukbuf, layer);
    attn_mfma_kernel<<<dim3(SEQL / 64, BB * HH), 256, 0, stream>>>(
        qb, kb, vb, Sbuf, VSbuf, ukbuf, n0tab, attnout);

    float* outp = (layer == LL - 1) ? out : xA;
    wtrans_kernel<<<dim3(16, 16, 1), 256, 0, stream>>>(Wo + (long)layer * DD * DD, WTbuf, DD, DD);
    gemm_bf16<<<dim3(4, 16, 1), 256, 0, stream>>>(attnout, WTbuf,
        b_o + layer * DD, xB, outp, M, DD, DD, DD, DD, 0, 0, 0, 0, 0, 0);
  }
}

// Round 6
// 906.031 us; speedup vs baseline: 5.3709x; 1.0304x over previous
//
#include <hip/hip_runtime.h>

#define LL 2
#define BB 2
#define SEQL 1024
#define DD 512
#define NN 16
#define HH 8
#define DHH 64
#define PPB 32
#define KCC 4
#define DTRR 32

#define GBS 4              // g*BB+b combinations
#define TC 64              // scan chunk length
#define NC (SEQL / TC)     // 16 chunks
#define NR (GBS * DD * NN) // 32768 recurrences

// weight arena (shorts), per layer
#define AR_L     4325376L
#define OFF_WIN  0L
#define OFF_MWIN 786432L
#define OFF_WT2  1835008L
#define OFF_MWOUT 2490368L
#define OFF_WOUT 3014656L
#define OFF_QKV  3276800L
#define OFF_WO   4063232L

typedef __attribute__((ext_vector_type(8))) short bf16x8;
typedef __attribute__((ext_vector_type(4))) short short4v;
typedef __attribute__((ext_vector_type(4))) float f32x4;

__device__ __forceinline__ float siluf(float x) { return x / (1.f + expf(-x)); }
__device__ __forceinline__ float softplusf(float x) { return x > 20.f ? x : log1pf(expf(x)); }

__device__ __forceinline__ unsigned short f2bf(float x) {
  union { float f; unsigned u; } v; v.f = x;
  unsigned r = v.u + 0x7fff + ((v.u >> 16) & 1);
  return (unsigned short)(r >> 16);
}

__device__ __forceinline__ bf16x8 ld_frag(const unsigned short* p) {
  short4v a = *(const short4v*)(p);
  short4v b = *(const short4v*)(p + 4);
  bf16x8 r;
  r[0]=a[0]; r[1]=a[1]; r[2]=a[2]; r[3]=a[3];
  r[4]=b[0]; r[5]=b[1]; r[6]=b[2]; r[7]=b[3];
  return r;
}

__device__ __forceinline__ bf16x8 pack8(const float* p) {
  bf16x8 r;
  #pragma unroll
  for (int e = 0; e < 8; e++) r[e] = (short)f2bf(p[e]);
  return r;
}

// ---------------------------------------------------------------- batched weight transpose
struct TD { const float* src; unsigned short* dst; int ldsrc; int K; int N; int t0; };
struct TDs { TD a[24]; };

__global__ __launch_bounds__(256) void wtrans_all(TDs ds)
{
  int bid = blockIdx.x;
  int mi = 0;
  #pragma unroll 1
  for (int i = 1; i < 24; i++) if (bid >= ds.a[i].t0) mi = i;
  TD d = ds.a[mi];
  int local = bid - d.t0;
  int tilesN = d.N >> 5;
  int tn = local % tilesN, tk = local / tilesN;
  __shared__ float t[32][33];
  int tx = threadIdx.x & 31, ty = threadIdx.x >> 5;
  int n0 = tn * 32, k0 = tk * 32;
  #pragma unroll
  for (int i = 0; i < 4; i++)
    t[ty + 8 * i][tx] = d.src[(long)(k0 + ty + 8 * i) * d.ldsrc + n0 + tx];
  __syncthreads();
  #pragma unroll
  for (int i = 0; i < 4; i++)
    d.dst[(long)(n0 + ty + 8 * i) * d.K + k0 + tx] = f2bf(t[tx][ty + 8 * i]);
}

// ---------------------------------------------------------------- Weff = Wx[:, :32] @ Wdt  ->  arena WT2 rows 0..511
__global__ __launch_bounds__(256) void weff_kernel(
    const float* __restrict__ Wx, const float* __restrict__ Wdt,
    unsigned short* __restrict__ WTA)
{
  int lg = blockIdx.z;
  int l = lg >> 1, g = lg & 1;
  const float* wx = Wx + (long)(l * 2 + g) * DD * 64;
  const float* wd = Wdt + (long)(l * 2 + g) * DTRR * DD;
  unsigned short* wt = WTA + (long)l * AR_L + OFF_WT2 + (long)g * 327680;
  int n0 = blockIdx.x * 32, k0 = blockIdx.y * 32;
  __shared__ float wx_s[32][33];
  __shared__ float wd_s[32][33];
  int tx = threadIdx.x & 31, ty = threadIdx.x >> 5;
  #pragma unroll
  for (int i = 0; i < 4; i++) {
    wx_s[ty + 8 * i][tx] = wx[(long)(k0 + ty + 8 * i) * 64 + tx];
    wd_s[ty + 8 * i][tx] = wd[(long)(ty + 8 * i) * DD + n0 + tx];
  }
  __syncthreads();
  #pragma unroll
  for (int i = 0; i < 4; i++) {
    int nl = ty + 8 * i;
    float s = 0.f;
    #pragma unroll
    for (int r = 0; r < 32; r++) s = fmaf(wx_s[tx][r], wd_s[r][nl], s);
    wt[(long)(n0 + nl) * DD + k0 + tx] = f2bf(s);
  }
}

// ---------------------------------------------------------------- RMS inverse-norm (per row)
__global__ __launch_bounds__(256) void rmsinv_kernel(
    const float* __restrict__ x, float* __restrict__ inv)
{
  int row = blockIdx.x * 4 + (threadIdx.x >> 6);
  int lane = threadIdx.x & 63;
  const float* xr = x + (long)row * DD;
  float4 a = *(const float4*)(xr + lane * 4);
  float4 b = *(const float4*)(xr + 256 + lane * 4);
  float s = a.x*a.x + a.y*a.y + a.z*a.z + a.w*a.w + b.x*b.x + b.y*b.y + b.z*b.z + b.w*b.w;
  for (int o = 32; o; o >>= 1) s += __shfl_down(s, o);
  if (lane == 0) inv[row] = rsqrtf(s / (float)DD + 1e-6f);
}

// ---------------------------------------------------------------- GEMM (bf16 MFMA)
// C[m,n] = (A[m,:]*invrow[m]*colw[:]) . WT[n,:] ; 128x128 tile, BK=64, 4 waves.
__global__ __launch_bounds__(256) void gemm_bf16(
    const float* __restrict__ A, const unsigned short* __restrict__ WT,
    const float* __restrict__ bias, const float* __restrict__ resid,
    const float* __restrict__ invrow, const float* __restrict__ colw,
    float* __restrict__ C,
    int M, int N, int K, int lda, int ldc,
    long aBatch, long wBatch, long biasBatch, long cBatch,
    int aflipL, int act)
{
  int g = blockIdx.z;
  A  += (long)g * aBatch;
  WT += (long)g * wBatch;
  C  += (long)g * cBatch;
  if (bias) bias += (long)g * biasBatch;
  const bool flip = (aflipL > 0) && (g == 1);

  __shared__ unsigned short A_lds[128][72];
  __shared__ unsigned short B_lds[128][72];
  int tid = threadIdx.x;
  int w = tid >> 6, lane = tid & 63, li = lane & 15, lg = lane >> 4;
  int bm = blockIdx.y * 128, bn = blockIdx.x * 128;
  int wm = (w & 1) * 64, wn = (w >> 1) * 64;
  f32x4 acc[4][4] = {};

  const int kqA = (tid & 15) * 4, r0A = tid >> 4;
  const int kqB = (tid & 7) * 8,  r0B = tid >> 3;

  for (int k0 = 0; k0 < K; k0 += 64) {
    __syncthreads();
    float4 cw4 = {1.f, 1.f, 1.f, 1.f};
    if (colw) cw4 = *(const float4*)(colw + k0 + kqA);
    #pragma unroll
    for (int i = 0; i < 8; i++) {
      int m = bm + r0A + 16 * i;
      int mm = m;
      if (flip) { int bb = m / aflipL; int t = m - bb * aflipL; mm = bb * aflipL + (aflipL - 1 - t); }
      float4 av = *(const float4*)(A + (long)mm * lda + k0 + kqA);
      float sc = invrow ? invrow[mm] : 1.f;
      short4v ap = { (short)f2bf(av.x * sc * cw4.x), (short)f2bf(av.y * sc * cw4.y),
                     (short)f2bf(av.z * sc * cw4.z), (short)f2bf(av.w * sc * cw4.w) };
      *(short4v*)(&A_lds[r0A + 16 * i][kqA]) = ap;
    }
    #pragma unroll
    for (int i = 0; i < 4; i++) {
      int n = bn + r0B + 32 * i;
      bf16x8 bv = *(const bf16x8*)(WT + (long)n * K + k0 + kqB);
      *(bf16x8*)(&B_lds[r0B + 32 * i][kqB]) = bv;
    }
    __syncthreads();
    #pragma unroll
    for (int ks = 0; ks < 2; ks++) {
      bf16x8 af[4], bfr[4];
      #pragma unroll
      for (int fm = 0; fm < 4; fm++)
        af[fm] = *(const bf16x8*)(&A_lds[wm + fm * 16 + li][ks * 32 + lg * 8]);
      #pragma unroll
      for (int fn = 0; fn < 4; fn++)
        bfr[fn] = *(const bf16x8*)(&B_lds[wn + fn * 16 + li][ks * 32 + lg * 8]);
      #pragma unroll
      for (int fm = 0; fm < 4; fm++)
        #pragma unroll
        for (int fn = 0; fn < 4; fn++)
          acc[fm][fn] = __builtin_amdgcn_mfma_f32_16x16x32_bf16(af[fm], bfr[fn], acc[fm][fn], 0, 0, 0);
    }
  }
  #pragma unroll
  for (int fm = 0; fm < 4; fm++) {
    #pragma unroll
    for (int fn = 0; fn < 4; fn++) {
      int n = bn + wn + fn * 16 + li;
      float bv = bias ? bias[n] : 0.f;
      #pragma unroll
      for (int r = 0; r < 4; r++) {
        int m = bm + wm + fm * 16 + 4 * lg + r;
        float v = acc[fm][fn][r] + bv;
        if (act == 1) v = softplusf(v);
        if (resid) v += resid[(long)m * ldc + n];
        C[(long)m * ldc + n] = v;
      }
    }
  }
}

// ---------------------------------------------------------------- fused dt/B/C GEMM
__global__ __launch_bounds__(256) void gemm_dtbc(
    const float* __restrict__ A, const unsigned short* __restrict__ WT2,
    const float* __restrict__ bdt, float* __restrict__ dtv, float* __restrict__ bc,
    int layer)
{
  int g = blockIdx.z;
  A   += (long)g * BB * SEQL * DD;
  WT2 += (long)g * 640 * DD;
  dtv += (long)g * BB * SEQL * DD;
  bc  += (long)g * BB * SEQL * 32;
  bdt += (long)(layer * 2 + g) * DD;

  __shared__ unsigned short A_lds[128][72];
  __shared__ unsigned short B_lds[128][72];
  int tid = threadIdx.x;
  int w = tid >> 6, lane = tid & 63, li = lane & 15, lg = lane >> 4;
  int bm = blockIdx.y * 128, bn = blockIdx.x * 128;
  int wm = (w & 1) * 64, wn = (w >> 1) * 64;
  f32x4 acc[4][4] = {};

  const int kqA = (tid & 15) * 4, r0A = tid >> 4;
  const int kqB = (tid & 7) * 8,  r0B = tid >> 3;

  for (int k0 = 0; k0 < DD; k0 += 64) {
    __syncthreads();
    #pragma unroll
    for (int i = 0; i < 8; i++) {
      int m = bm + r0A + 16 * i;
      float4 av = *(const float4*)(A + (long)m * DD + k0 + kqA);
      short4v ap = { (short)f2bf(av.x), (short)f2bf(av.y), (short)f2bf(av.z), (short)f2bf(av.w) };
      *(short4v*)(&A_lds[r0A + 16 * i][kqA]) = ap;
    }
    #pragma unroll
    for (int i = 0; i < 4; i++) {
      int n = bn + r0B + 32 * i;
      bf16x8 bv = *(const bf16x8*)(WT2 + (long)n * DD + k0 + kqB);
      *(bf16x8*)(&B_lds[r0B + 32 * i][kqB]) = bv;
    }
    __syncthreads();
    #pragma unroll
    for (int ks = 0; ks < 2; ks++) {
      bf16x8 af[4], bfr[4];
      #pragma unroll
      for (int fm = 0; fm < 4; fm++)
        af[fm] = *(const bf16x8*)(&A_lds[wm + fm * 16 + li][ks * 32 + lg * 8]);
      #pragma unroll
      for (int fn = 0; fn < 4; fn++)
        bfr[fn] = *(const bf16x8*)(&B_lds[wn + fn * 16 + li][ks * 32 + lg * 8]);
      #pragma unroll
      for (int fm = 0; fm < 4; fm++)
        #pragma unroll
        for (int fn = 0; fn < 4; fn++)
          acc[fm][fn] = __builtin_amdgcn_mfma_f32_16x16x32_bf16(af[fm], bfr[fn], acc[fm][fn], 0, 0, 0);
    }
  }
  #pragma unroll
  for (int fm = 0; fm < 4; fm++) {
    #pragma unroll
    for (int fn = 0; fn < 4; fn++) {
      int n = bn + wn + fn * 16 + li;
      if (n < 512) {
        float bv = bdt[n];
        #pragma unroll
        for (int r = 0; r < 4; r++) {
          int m = bm + wm + fm * 16 + 4 * lg + r;
          dtv[(long)m * DD + n] = softplusf(acc[fm][fn][r] + bv);
        }
      } else if (n < 544) {
        #pragma unroll
        for (int r = 0; r < 4; r++) {
          int m = bm + wm + fm * 16 + 4 * lg + r;
          bc[(long)m * 32 + (n - 512)] = acc[fm][fn][r];
        }
      }
    }
  }
}

// ---------------------------------------------------------------- conv + SiLU
__global__ __launch_bounds__(256) void conv_silu_kernel(
    const float* __restrict__ xz, const float* __restrict__ cw, const float* __restrict__ cb,
    float* __restrict__ xc, int layer)
{
  long idx = (long)blockIdx.x * 256 + threadIdx.x;  // (g,b,t,c)
  int c = idx % DD;
  long r = idx / DD;
  int t = r % SEQL;
  long gb = r / SEQL;
  int g = (int)(gb / BB);
  const float* w = cw + ((long)(layer * 2 + g) * DD + c) * KCC;
  float acc = cb[(long)(layer * 2 + g) * DD + c];
  const float* xp = xz + (r - t) * 2 * DD + c;
  #pragma unroll
  for (int k = 0; k < KCC; k++) {
    int tt = t - (KCC - 1) + k;
    if (tt >= 0) acc = fmaf(xp[(long)tt * 2 * DD], w[k], acc);
  }
  xc[idx] = siluf(acc);
}

// ---------------------------------------------------------------- chunked scan
__global__ __launch_bounds__(256) void scan_chunk_kernel(
    const float* __restrict__ dtv, const float* __restrict__ xc,
    const float* __restrict__ bc, const float* __restrict__ Alog,
    float* __restrict__ P, float* __restrict__ Hend, int layer)
{
  int chunk = blockIdx.x, dtile = blockIdx.y, gb = blockIdx.z;
  int g = gb / BB;
  int tid = threadIdx.x;
  int n = tid & 15, dl = tid >> 4;
  int d = dtile * 16 + dl;
  int t0 = chunk * TC;
  __shared__ float dtv_s[TC][16], xc_s[TC][16], B_s[TC][17];
  {
    int c = tid & 15, rr = tid >> 4;
    long base = ((long)gb * SEQL + t0) * DD + dtile * 16;
    long dbase = ((long)gb * SEQL + t0) * 32;
    #pragma unroll
    for (int i = 0; i < 4; i++) {
      int tl = rr + i * 16;
      dtv_s[tl][c] = dtv[base + (long)tl * DD + c];
      xc_s[tl][c]  = xc[base + (long)tl * DD + c];
      B_s[tl][c]   = bc[dbase + (long)tl * 32 + c];
    }
  }
  __syncthreads();
  float a = -expf(Alog[((long)((layer * 2 + g) * DD) + d) * NN + n]);
  float h = 0.f, sdt = 0.f;
  #pragma unroll 4
  for (int t = 0; t < TC; t++) {
    float dt = dtv_s[t][dl];
    float dA = expf(dt * a);
    h = fmaf(dA, h, dt * B_s[t][n] * xc_s[t][dl]);
    sdt += dt;
  }
  int r = (gb * DD + d) * NN + n;
  long o = (long)chunk * NR + r;
  P[o] = expf(a * sdt);
  Hend[o] = h;
}

__global__ __launch_bounds__(256) void scan_combine_kernel(
    const float* __restrict__ P, const float* __restrict__ Hend, float* __restrict__ Hin)
{
  int r = blockIdx.x * 256 + threadIdx.x;
  float h = 0.f;
  #pragma unroll
  for (int c = 0; c < NC; c++) {
    Hin[(long)c * NR + r] = h;
    h = fmaf(P[(long)c * NR + r], h, Hend[(long)c * NR + r]);
  }
}

__global__ __launch_bounds__(256) void scan_apply_kernel(
    const float* __restrict__ dtv, const float* __restrict__ xc, const float* __restrict__ xz,
    const float* __restrict__ bc, const float* __restrict__ Alog, const float* __restrict__ Dp,
    const float* __restrict__ Hin, float* __restrict__ ym, int layer)
{
  int chunk = blockIdx.x, dtile = blockIdx.y, gb = blockIdx.z;
  int g = gb / BB;
  int tid = threadIdx.x;
  int n = tid & 15, dl = tid >> 4;
  int d = dtile * 16 + dl;
  int t0 = chunk * TC;
  __shared__ float dtv_s[TC][16], xc_s[TC][16], B_s[TC][17], C_s[TC][17], y_s[TC][16];
  {
    int c = tid & 15, rr = tid >> 4;
    long base = ((long)gb * SEQL + t0) * DD + dtile * 16;
    long dbase = ((long)gb * SEQL + t0) * 32;
    #pragma unroll
    for (int i = 0; i < 4; i++) {
      int tl = rr + i * 16;
      dtv_s[tl][c] = dtv[base + (long)tl * DD + c];
      xc_s[tl][c]  = xc[base + (long)tl * DD + c];
      B_s[tl][c]   = bc[dbase + (long)tl * 32 + c];
      C_s[tl][c]   = bc[dbase + (long)tl * 32 + 16 + c];
    }
  }
  __syncthreads();
  float a = -expf(Alog[((long)((layer * 2 + g) * DD) + d) * NN + n]);
  int r = (gb * DD + d) * NN + n;
  float h = Hin[(long)chunk * NR + r];
  #pragma unroll 4
  for (int t = 0; t < TC; t++) {
    float dt = dtv_s[t][dl];
    float dA = expf(dt * a);
    h = fmaf(dA, h, dt * B_s[t][n] * xc_s[t][dl]);
    float val = h * C_s[t][n];
    val += __shfl_xor(val, 1);
    val += __shfl_xor(val, 2);
    val += __shfl_xor(val, 4);
    val += __shfl_xor(val, 8);
    if (n == 0) y_s[t][dl] = val;
  }
  __syncthreads();
  {
    int c = tid & 15, rr = tid >> 4;
    long base = ((long)gb * SEQL + t0) * DD + dtile * 16;
    long zbase = ((long)gb * SEQL + t0) * 2 * DD + DD + dtile * 16;
    float Dpc = Dp[(long)(layer * 2 + g) * DD + dtile * 16 + c];
    #pragma unroll
    for (int i = 0; i < 4; i++) {
      int tl = rr + i * 16;
      float z = xz[zbase + (long)tl * 2 * DD + c];
      ym[base + (long)tl * DD + c] = (y_s[tl][c] + Dpc * xc_s[tl][c]) * siluf(z);
    }
  }
}

// ---------------------------------------------------------------- dir combine
__global__ __launch_bounds__(256) void combine_kernel(
    const float* __restrict__ yp, const float* __restrict__ proj, float* __restrict__ yc)
{
  long idx = (long)blockIdx.x * 256 + threadIdx.x;  // (b,t,d)
  int d = idx % DD;
  long r = idx / DD;
  int t = r % SEQL;
  long b = r / SEQL;
  float y0 = yp[idx];
  float y1 = yp[(long)BB * SEQL * DD + (b * SEQL + (SEQL - 1 - t)) * (long)DD + d];
  const float* pr = proj + r * 3 * DD;
  float zf = pr[DD + d];
  float zr = pr[2 * DD + d];
  yc[idx] = y0 * siluf(zf) + y1 * siluf(zr);
}

// ---------------------------------------------------------------- bias index table
__global__ void tab_kernel(unsigned short* __restrict__ tab)
{
  int idx = blockIdx.x * blockDim.x + threadIdx.x;
  if (idx >= 2047) return;
  int di = idx - 1023;
  int ad = di < 0 ? -di : di;
  float pr = expf(logf((SEQL + 1) * 0.5f) / 16.0f);
  int n0 = 16;
  for (int n = 15; n >= 0; n--) {
    float cw = powf(pr, (float)(n + 1));
    if ((float)ad <= cw) n0 = n;
  }
  tab[idx] = (unsigned short)(di == 0 ? 34 : (di < 0 ? n0 : 17 + n0));
}

// ---------------------------------------------------------------- qw suffix (dense)
__global__ __launch_bounds__(256) void qw_kernel(
    const float* __restrict__ q, const float* __restrict__ w_rel, float* __restrict__ S, int layer)
{
  int itile = blockIdx.x;   // 16
  int bh = blockIdx.y;      // 16
  int h = bh % HH, b = bh / HH;
  int i0 = itile * 64;
  __shared__ float q_s[64][65];
  __shared__ float w_s[64][33];
  __shared__ float qwn[64][33];
  int tid = threadIdx.x;
  {
    int r = tid >> 2, c4 = (tid & 3) * 16;
    const float* qr = q + ((long)(b * SEQL + i0 + r)) * DD + h * 64 + c4;
    #pragma unroll
    for (int e = 0; e < 4; e++) {
      float4 v = *(const float4*)(qr + e * 4);
      q_s[r][c4 + e * 4 + 0] = v.x; q_s[r][c4 + e * 4 + 1] = v.y;
      q_s[r][c4 + e * 4 + 2] = v.z; q_s[r][c4 + e * 4 + 3] = v.w;
    }
  }
  for (int idx = tid; idx < 64 * 32; idx += 256) {
    int d = idx >> 5, n = idx & 31;
    w_s[d][n] = w_rel[((long)(layer * HH + h) * DHH + d) * PPB + n];
  }
  __syncthreads();
  {
    int i = tid & 63, ngrp = tid >> 6;
    float acc[8] = {};
    #pragma unroll 8
    for (int d = 0; d < 64; d++) {
      float qv = q_s[i][d];
      #pragma unroll
      for (int e = 0; e < 8; e++) acc[e] = fmaf(qv, w_s[d][ngrp * 8 + e], acc[e]);
    }
    #pragma unroll
    for (int e = 0; e < 8; e++) qwn[i][ngrp * 8 + e] = acc[e];
  }
  __syncthreads();
  for (int idx = tid; idx < 64 * 17; idx += 256) {
    int il = idx / 17, m = idx % 17;
    float s1 = 0.f, s2 = 0.f;
    for (int n = m; n < 16; n++) { s1 += qwn[il][n]; s2 += qwn[il][16 + n]; }
    float* Sp = S + ((long)bh * SEQL + i0 + il) * 34;
    Sp[m] = s1;
    Sp[17 + m] = s2;
  }
}

__global__ __launch_bounds__(256) void vw_kernel(
    const float* __restrict__ vparam, const float* __restrict__ w_rel, float* __restrict__ VS, int layer)
{
  __shared__ float vws[HH][PPB];
  int tid = threadIdx.x;
  int h = tid / PPB, n = tid % PPB;
  const float* vp = vparam + (long)(layer * HH + h) * DHH;
  const float* wp = w_rel + ((long)(layer * HH + h) * DHH) * PPB + n;
  float s = 0.f;
  for (int d = 0; d < DHH; d++) s = fmaf(vp[d], wp[d * PPB], s);
  vws[h][n] = s;
  __syncthreads();
  if (tid < HH * 17) {
    int hh = tid / 17, m = tid % 17;
    float s1 = 0.f, s2 = 0.f;
    for (int nn = m; nn < 16; nn++) { s1 += vws[hh][nn]; s2 += vws[hh][16 + nn]; }
    VS[hh * 34 + m] = s1;
    VS[hh * 34 + 17 + m] = s2;
  }
}

__global__ __launch_bounds__(256) void uk_kernel(
    const float* __restrict__ u, const float* __restrict__ k, float* __restrict__ uk, int layer)
{
  int wid = (blockIdx.x * 256 + threadIdx.x) >> 6;
  int lane = threadIdx.x & 63;
  if (wid >= BB * HH * SEQL) return;
  int j = wid % SEQL;
  int bh = wid / SEQL;
  int h = bh % HH;
  int b = bh / HH;
  float vv = u[(long)(layer * HH + h) * DHH + lane] * k[((long)(b * SEQL + j) * HH + h) * DHH + lane];
  for (int o = 32; o; o >>= 1) vv += __shfl_down(vv, o);
  if (lane == 0) uk[(long)bh * SEQL + j] = vv;
}

// ---------------------------------------------------------------- MFMA attention
// LDS: K 0..8704, VT 8704..17408, PT 17408..26112, E(64x36 f32) 26112..35328,
//      tab(2048 u16) 35328..39424, uk 39424..39680. O_lds aliases 0..17408.
__global__ __launch_bounds__(256) void attn_mfma_kernel(
    const float* __restrict__ q, const float* __restrict__ k, const float* __restrict__ vv,
    const float* __restrict__ S, const float* __restrict__ VS, const float* __restrict__ uk,
    const unsigned short* __restrict__ tab, float* __restrict__ out)
{
  __shared__ __align__(16) char smem[39680];
  unsigned short* K_lds  = (unsigned short*)(smem);
  unsigned short* VT_lds = (unsigned short*)(smem + 8704);
  unsigned short* PT_lds = (unsigned short*)(smem + 17408);
  float* E               = (float*)(smem + 26112);
  unsigned short* tab_s  = (unsigned short*)(smem + 35328);
  float* uk_s            = (float*)(smem + 39424);
  float* O_lds           = (float*)(smem);

  int itile = blockIdx.x;
  int bh = blockIdx.y;
  int h = bh % HH, b = bh / HH;
  int i0 = itile * 64;
  int tid = threadIdx.x;
  int w = tid >> 6;
  int lane = tid & 63;
  int li = lane & 15, lg = lane >> 4;

  for (int idx = tid; idx < 64 * 17; idx += 256) {
    int il = idx / 17, m = idx % 17;
    long srow = ((long)bh * SEQL + i0 + il) * 34;
    float c0 = S[srow + m]      + VS[h * 34 + m];
    float c1 = S[srow + 17 + m] + VS[h * 34 + 17 + m];
    E[il * 36 + m]      = c0 - c1;
    E[il * 36 + 17 + m] = c0 + c1;
    if (m == 0) E[il * 36 + 34] = c0;
  }
  for (int idx = tid; idx < 2047; idx += 256) tab_s[idx] = tab[idx];

  int iq = i0 + w * 16 + li;
  const float* qrow = q + ((long)(b * SEQL + iq)) * DD + h * 64;
  bf16x8 qf0 = pack8(qrow + 8 * lg);
  bf16x8 qf1 = pack8(qrow + 32 + 8 * lg);

  f32x4 oacc[4] = {};
  float mrun = -1e30f, lrun = 0.f;
  const int ibase = i0 + w * 16 + li;
  unsigned short* PTw = PT_lds + w * 16 * 68;
  const float* Erow = E + (w * 16 + li) * 36;

  for (int j0 = 0; j0 < SEQL; j0 += 64) {
    __syncthreads();
    {
      int jl = tid >> 4;
      int dq = (tid & 15) * 4;
      #pragma unroll
      for (int rr = 0; rr < 4; rr++) {
        int jj = jl + rr * 16;
        long grow = ((long)(b * SEQL + j0 + jj)) * DD + h * 64 + dq;
        float4 kv = *(const float4*)(k + grow);
        short4v kp = { (short)f2bf(kv.x), (short)f2bf(kv.y), (short)f2bf(kv.z), (short)f2bf(kv.w) };
        *(short4v*)(K_lds + jj * 68 + dq) = kp;
        float4 vvv = *(const float4*)(vv + grow);
        VT_lds[(dq + 0) * 68 + jj] = f2bf(vvv.x);
        VT_lds[(dq + 1) * 68 + jj] = f2bf(vvv.y);
        VT_lds[(dq + 2) * 68 + jj] = f2bf(vvv.z);
        VT_lds[(dq + 3) * 68 + jj] = f2bf(vvv.w);
      }
      if (tid < 64) uk_s[tid] = uk[(long)bh * SEQL + j0 + tid];
    }
    __syncthreads();

    f32x4 sf[4];
    #pragma unroll
    for (int jj = 0; jj < 4; jj++) {
      f32x4 c = {};
      c = __builtin_amdgcn_mfma_f32_16x16x32_bf16(
            ld_frag(K_lds + (jj * 16 + li) * 68 + 8 * lg), qf0, c, 0, 0, 0);
      c = __builtin_amdgcn_mfma_f32_16x16x32_bf16(
            ld_frag(K_lds + (jj * 16 + li) * 68 + 32 + 8 * lg), qf1, c, 0, 0, 0);
      sf[jj] = c;
    }

    float sv[4][4];
    float tmax = -1e30f;
    #pragma unroll
    for (int jj = 0; jj < 4; jj++) {
      #pragma unroll
      for (int r = 0; r < 4; r++) {
        int jloc = jj * 16 + 4 * lg + r;
        int di = (j0 + jloc) - ibase;
        int id = tab_s[1023 + di];
        float val = (sf[jj][r] + Erow[id] + uk_s[jloc]) * 0.125f;
        sv[jj][r] = val;
        tmax = fmaxf(tmax, val);
      }
    }
    tmax = fmaxf(tmax, __shfl_xor(tmax, 16));
    tmax = fmaxf(tmax, __shfl_xor(tmax, 32));
    float mnew = fmaxf(mrun, tmax);
    float fsc = __expf(mrun - mnew);
    mrun = mnew;
    lrun *= fsc;
    #pragma unroll
    for (int df = 0; df < 4; df++) oacc[df] *= fsc;

    float psum = 0.f;
    #pragma unroll
    for (int jj = 0; jj < 4; jj++) {
      short4v pk;
      #pragma unroll
      for (int r = 0; r < 4; r++) {
        float p = __expf(sv[jj][r] - mnew);
        psum += p;
        pk[r] = (short)f2bf(p);
      }
      *(short4v*)(PTw + li * 68 + jj * 16 + 4 * lg) = pk;
    }
    psum += __shfl_xor(psum, 16);
    psum += __shfl_xor(psum, 32);
    lrun += psum;

    asm volatile("s_waitcnt lgkmcnt(0)" ::: "memory");

    bf16x8 pf0 = ld_frag(PTw + li * 68 + 8 * lg);
    bf16x8 pf1 = ld_frag(PTw + li * 68 + 32 + 8 * lg);
    #pragma unroll
    for (int df = 0; df < 4; df++) {
      f32x4 c = oacc[df];
      c = __builtin_amdgcn_mfma_f32_16x16x32_bf16(
            ld_frag(VT_lds + (df * 16 + li) * 68 + 8 * lg), pf0, c, 0, 0, 0);
      c = __builtin_amdgcn_mfma_f32_16x16x32_bf16(
            ld_frag(VT_lds + (df * 16 + li) * 68 + 32 + 8 * lg), pf1, c, 0, 0, 0);
      oacc[df] = c;
    }
  }

  __syncthreads();
  float inv = 1.f / lrun;
  #pragma unroll
  for (int df = 0; df < 4; df++) {
    f32x4 o = oacc[df] * inv;
    *(f32x4*)(O_lds + (w * 16 + li) * 68 + df * 16 + 4 * lg) = o;
  }
  __syncthreads();
  {
    int il = tid >> 2, c0 = (tid & 3) * 16;
    long orow = ((long)(b * SEQL + i0 + il)) * DD + h * 64 + c0;
    #pragma unroll
    for (int c4 = 0; c4 < 4; c4++) {
      f32x4 o = *(const f32x4*)(O_lds + il * 68 + c0 + c4 * 4);
      *(f32x4*)(out + orow + c4 * 4) = o;
    }
  }
}

// ---------------------------------------------------------------- launch
extern "C" void kernel_launch(void* const* d_in, const int* in_sizes, int n_in,
                              void* d_out, int out_size, void* d_ws, size_t ws_size,
                              hipStream_t stream) {
  const float* x_in     = (const float*)d_in[0];
  const float* rms_m    = (const float*)d_in[1];
  const float* W_in     = (const float*)d_in[2];
  const float* b_in     = (const float*)d_in[3];
  const float* m_Win    = (const float*)d_in[4];
  const float* m_conv_w = (const float*)d_in[5];
  const float* m_conv_b = (const float*)d_in[6];
  const float* m_Wx     = (const float*)d_in[7];
  const float* m_Wdt    = (const float*)d_in[8];
  const float* m_bdt    = (const float*)d_in[9];
  const float* m_Alog   = (const float*)d_in[10];
  const float* m_Dp     = (const float*)d_in[11];
  const float* m_Wout   = (const float*)d_in[12];
  const float* W_out    = (const float*)d_in[13];
  const float* b_out    = (const float*)d_in[14];
  const float* rms_a    = (const float*)d_in[15];
  const float* Wq       = (const float*)d_in[16];
  const float* Wk       = (const float*)d_in[17];
  const float* Wv       = (const float*)d_in[18];
  const float* u_p      = (const float*)d_in[19];
  const float* v_p      = (const float*)d_in[20];
  const float* w_rel    = (const float*)d_in[21];
  const float* Wo       = (const float*)d_in[22];
  const float* b_o      = (const float*)d_in[23];
  float* out = (float*)d_out;

  float* ws = (float*)d_ws;
  const long U = (long)BB * SEQL * DD;      // 1,048,576 floats
  float* xA    = ws;
  float* xB    = ws + 1 * U;
  float* xn    = ws + 2 * U;                // scan P/Hend scratch
  float* proj  = ws + 3 * U;                // 3U; later q,k,v
  float* xz    = ws + 6 * U;                // 4U; later yp (2U)
  float* xc    = ws + 10 * U;               // 2U
  float* dtv   = ws + 12 * U;               // 2U
  float* ym    = ws + 14 * U;               // 2U; later attnout
  float* ycomb = ws + 16 * U;               // 1U; also scan Hin scratch
  float* smallb= ws + 17 * U;               // 1U of small buffers
  float* bcbuf = smallb;                    // 131072
  float* ukbuf = smallb + 262144;           // 16384
  float* Sbuf  = smallb + 278528;           // 557056
  float* VSbuf = smallb + 835584;           // 272
  unsigned short* tabg = (unsigned short*)(smallb + 835856);  // 2047 u16
  float* invm  = smallb + 836880;           // 2048
  float* inva  = smallb + 838928;           // 2048
  unsigned short* WTA = (unsigned short*)(ws + 18 * U);       // 2 * AR_L shorts
  float* yp = xz;
  float* qb = proj;
  float* kb = proj + U;
  float* vb = proj + 2 * U;
  float* attnout = ym;
  float* Pbuf = xn;
  float* Hend = xn + (long)NC * NR;
  float* Hin  = ycomb;

  const int M = BB * SEQL;                  // 2048

  // ---- preamble: bias table + all weight preprocessing ----
  tab_kernel<<<8, 256, 0, stream>>>(tabg);

  TDs td;
  int cum = 0, idx = 0;
  auto add = [&](const float* s, unsigned short* dst, int ldsrc, int K, int N) {
    td.a[idx].src = s; td.a[idx].dst = dst; td.a[idx].ldsrc = ldsrc;
    td.a[idx].K = K; td.a[idx].N = N; td.a[idx].t0 = cum;
    cum += (N / 32) * (K / 32); idx++;
  };
  for (int l = 0; l < LL; l++) {
    unsigned short* base = WTA + (long)l * AR_L;
    add(W_in   + (long)l * DD * 3 * DD,        base + OFF_WIN,            3 * DD, DD, 3 * DD);
    add(m_Win  + (long)(l * 2 + 0) * DD * 2 * DD, base + OFF_MWIN,          2 * DD, DD, 2 * DD);
    add(m_Win  + (long)(l * 2 + 1) * DD * 2 * DD, base + OFF_MWIN + 524288, 2 * DD, DD, 2 * DD);
    add(m_Wout + (long)(l * 2 + 0) * DD * DD,  base + OFF_MWOUT,          DD, DD, DD);
    add(m_Wout + (long)(l * 2 + 1) * DD * DD,  base + OFF_MWOUT + 262144, DD, DD, DD);
    add(W_out  + (long)l * DD * DD,            base + OFF_WOUT,           DD, DD, DD);
    add(Wq     + (long)l * DD * DD,            base + OFF_QKV,            DD, DD, DD);
    add(Wk     + (long)l * DD * DD,            base + OFF_QKV + 262144,   DD, DD, DD);
    add(Wv     + (long)l * DD * DD,            base + OFF_QKV + 524288,   DD, DD, DD);
    add(Wo     + (long)l * DD * DD,            base + OFF_WO,             DD, DD, DD);
    add(m_Wx   + (long)(l * 2 + 0) * DD * 64 + 32, base + OFF_WT2 + 262144,          64, DD, 32);
    add(m_Wx   + (long)(l * 2 + 1) * DD * 64 + 32, base + OFF_WT2 + 327680 + 262144, 64, DD, 32);
  }
  wtrans_all<<<cum, 256, 0, stream>>>(td);
  weff_kernel<<<dim3(16, 16, 2 * LL), 256, 0, stream>>>(m_Wx, m_Wdt, WTA);

  for (int layer = 0; layer < LL; layer++) {
    const float* cur = (layer == 0) ? x_in : xA;
    unsigned short* base = WTA + (long)layer * AR_L;
    // ---- mamba block ----
    rmsinv_kernel<<<M / 4, 256, 0, stream>>>(cur, invm);
    gemm_bf16<<<dim3(12, 16, 1), 256, 0, stream>>>(cur, base + OFF_WIN,
        b_in + layer * 3 * DD, nullptr, invm, rms_m + layer * DD, proj,
        M, 3 * DD, DD, DD, 3 * DD, 0, 0, 0, 0, 0, 0);
    gemm_bf16<<<dim3(8, 16, 2), 256, 0, stream>>>(proj, base + OFF_MWIN,
        nullptr, nullptr, nullptr, nullptr, xz, M, 2 * DD, DD, 3 * DD, 2 * DD,
        0, 524288, 0, (long)BB * SEQL * 2 * DD, SEQL, 0);
    conv_silu_kernel<<<(2 * BB * SEQL * DD) / 256, 256, 0, stream>>>(xz, m_conv_w, m_conv_b, xc, layer);
    gemm_dtbc<<<dim3(5, 16, 2), 256, 0, stream>>>(xc, base + OFF_WT2, m_bdt, dtv, bcbuf, layer);
    scan_chunk_kernel<<<dim3(NC, DD / 16, GBS), 256, 0, stream>>>(
        dtv, xc, bcbuf, m_Alog, Pbuf, Hend, layer);
    scan_combine_kernel<<<NR / 256, 256, 0, stream>>>(Pbuf, Hend, Hin);
    scan_apply_kernel<<<dim3(NC, DD / 16, GBS), 256, 0, stream>>>(
        dtv, xc, xz, bcbuf, m_Alog, m_Dp, Hin, ym, layer);
    gemm_bf16<<<dim3(4, 16, 2), 256, 0, stream>>>(ym, base + OFF_MWOUT,
        nullptr, nullptr, nullptr, nullptr, yp, M, DD, DD, DD, DD,
        U, 262144, 0, U, 0, 0);
    combine_kernel<<<(int)(U / 256), 256, 0, stream>>>(yp, proj, ycomb);
    gemm_bf16<<<dim3(4, 16, 1), 256, 0, stream>>>(ycomb, base + OFF_WOUT,
        b_out + layer * DD, cur, nullptr, nullptr, xB, M, DD, DD, DD, DD, 0, 0, 0, 0, 0, 0);

    // ---- attention block ----
    rmsinv_kernel<<<M / 4, 256, 0, stream>>>(xB, inva);
    gemm_bf16<<<dim3(4, 16, 3), 256, 0, stream>>>(xB, base + OFF_QKV,
        nullptr, nullptr, inva, rms_a + layer * DD, qb, M, DD, DD, DD, DD,
        0, 262144, 0, U, 0, 0);
    qw_kernel<<<dim3(16, 16), 256, 0, stream>>>(qb, w_rel, Sbuf, layer);
    vw_kernel<<<1, 256, 0, stream>>>(v_p, w_rel, VSbuf, layer);
    uk_kernel<<<(BB * HH * SEQL) / 4, 256, 0, stream>>>(u_p, kb, ukbuf, layer);
    attn_mfma_kernel<<<dim3(SEQL / 64, BB * HH), 256, 0, stream>>>(
        qb, kb, vb, Sbuf, VSbuf, ukbuf, tabg, attnout);

    float* outp = (layer == LL - 1) ? out : xA;
    gemm_bf16<<<dim3(4, 16, 1), 256, 0, stream>>>(attnout, base + OFF_WO,
        b_o + layer * DD, xB, nullptr, nullptr, outp, M, DD, DD, DD, DD, 0, 0, 0, 0, 0, 0);
  }
}

// Round 7
// 657.226 us; speedup vs baseline: 7.4042x; 1.3786x over previous
//
#include <hip/hip_runtime.h>

#define LL 2
#define BB 2
#define SEQL 1024
#define DD 512
#define NN 16
#define HH 8
#define DHH 64
#define PPB 32
#define KCC 4
#define DTRR 32

#define GBS 4              // g*BB+b combinations
#define TC 64              // scan chunk length
#define NC (SEQL / TC)     // 16 chunks
#define NR (GBS * DD * NN) // 32768 recurrences

// weight arena (shorts), per layer
#define AR_L     4325376L
#define OFF_WIN  0L
#define OFF_MWIN 786432L
#define OFF_WT2  1835008L
#define OFF_MWOUT 2490368L
#define OFF_WOUT 3014656L
#define OFF_QKV  3276800L
#define OFF_WO   4063232L

typedef __attribute__((ext_vector_type(8))) short bf16x8;
typedef __attribute__((ext_vector_type(4))) short short4v;
typedef __attribute__((ext_vector_type(4))) float f32x4;

__device__ __forceinline__ float siluf(float x) { return x / (1.f + expf(-x)); }
__device__ __forceinline__ float softplusf(float x) { return x > 20.f ? x : log1pf(expf(x)); }

__device__ __forceinline__ unsigned short f2bf(float x) {
  union { float f; unsigned u; } v; v.f = x;
  unsigned r = v.u + 0x7fff + ((v.u >> 16) & 1);
  return (unsigned short)(r >> 16);
}

__device__ __forceinline__ bf16x8 ld_frag(const unsigned short* p) {
  short4v a = *(const short4v*)(p);
  short4v b = *(const short4v*)(p + 4);
  bf16x8 r;
  r[0]=a[0]; r[1]=a[1]; r[2]=a[2]; r[3]=a[3];
  r[4]=b[0]; r[5]=b[1]; r[6]=b[2]; r[7]=b[3];
  return r;
}

__device__ __forceinline__ bf16x8 pack8(const float* p) {
  bf16x8 r;
  #pragma unroll
  for (int e = 0; e < 8; e++) r[e] = (short)f2bf(p[e]);
  return r;
}

// ---------------------------------------------------------------- batched weight transpose
struct TD { const float* src; unsigned short* dst; int ldsrc; int K; int N; int t0; };
struct TDs { TD a[24]; };

__global__ __launch_bounds__(256) void wtrans_all(TDs ds)
{
  int bid = blockIdx.x;
  int mi = 0;
  #pragma unroll 1
  for (int i = 1; i < 24; i++) if (bid >= ds.a[i].t0) mi = i;
  TD d = ds.a[mi];
  int local = bid - d.t0;
  int tilesN = d.N >> 5;
  int tn = local % tilesN, tk = local / tilesN;
  __shared__ float t[32][33];
  int tx = threadIdx.x & 31, ty = threadIdx.x >> 5;
  int n0 = tn * 32, k0 = tk * 32;
  #pragma unroll
  for (int i = 0; i < 4; i++)
    t[ty + 8 * i][tx] = d.src[(long)(k0 + ty + 8 * i) * d.ldsrc + n0 + tx];
  __syncthreads();
  #pragma unroll
  for (int i = 0; i < 4; i++)
    d.dst[(long)(n0 + ty + 8 * i) * d.K + k0 + tx] = f2bf(t[tx][ty + 8 * i]);
}

// ---------------------------------------------------------------- Weff = Wx[:, :32] @ Wdt
__global__ __launch_bounds__(256) void weff_kernel(
    const float* __restrict__ Wx, const float* __restrict__ Wdt,
    unsigned short* __restrict__ WTA)
{
  int lg = blockIdx.z;
  int l = lg >> 1, g = lg & 1;
  const float* wx = Wx + (long)(l * 2 + g) * DD * 64;
  const float* wd = Wdt + (long)(l * 2 + g) * DTRR * DD;
  unsigned short* wt = WTA + (long)l * AR_L + OFF_WT2 + (long)g * 327680;
  int n0 = blockIdx.x * 32, k0 = blockIdx.y * 32;
  __shared__ float wx_s[32][33];
  __shared__ float wd_s[32][33];
  int tx = threadIdx.x & 31, ty = threadIdx.x >> 5;
  #pragma unroll
  for (int i = 0; i < 4; i++) {
    wx_s[ty + 8 * i][tx] = wx[(long)(k0 + ty + 8 * i) * 64 + tx];
    wd_s[ty + 8 * i][tx] = wd[(long)(ty + 8 * i) * DD + n0 + tx];
  }
  __syncthreads();
  #pragma unroll
  for (int i = 0; i < 4; i++) {
    int nl = ty + 8 * i;
    float s = 0.f;
    #pragma unroll
    for (int r = 0; r < 32; r++) s = fmaf(wx_s[tx][r], wd_s[r][nl], s);
    wt[(long)(n0 + nl) * DD + k0 + tx] = f2bf(s);
  }
}

// ---------------------------------------------------------------- RMS inverse-norm (per row)
__global__ __launch_bounds__(256) void rmsinv_kernel(
    const float* __restrict__ x, float* __restrict__ inv)
{
  int row = blockIdx.x * 4 + (threadIdx.x >> 6);
  int lane = threadIdx.x & 63;
  const float* xr = x + (long)row * DD;
  float4 a = *(const float4*)(xr + lane * 4);
  float4 b = *(const float4*)(xr + 256 + lane * 4);
  float s = a.x*a.x + a.y*a.y + a.z*a.z + a.w*a.w + b.x*b.x + b.y*b.y + b.z*b.z + b.w*b.w;
  for (int o = 32; o; o >>= 1) s += __shfl_down(s, o);
  if (lane == 0) inv[row] = rsqrtf(s / (float)DD + 1e-6f);
}

// ---------------------------------------------------------------- GEMM (bf16 MFMA, tiled)
// 4 waves arranged 2x2; each wave computes (BM/2)x(BN/2).
template<int BM, int BN>
__global__ __launch_bounds__(256) void gemm_bf16_t(
    const float* __restrict__ A, const unsigned short* __restrict__ WT,
    const float* __restrict__ bias, const float* __restrict__ resid,
    const float* __restrict__ invrow, const float* __restrict__ colw,
    float* __restrict__ C,
    int M, int N, int K, int lda, int ldc,
    long aBatch, long wBatch, long biasBatch, long cBatch,
    int aflipL, int act)
{
  constexpr int FM = BM / 32;   // fragments per wave in m
  constexpr int FN = BN / 32;
  int g = blockIdx.z;
  A  += (long)g * aBatch;
  WT += (long)g * wBatch;
  C  += (long)g * cBatch;
  if (bias) bias += (long)g * biasBatch;
  const bool flip = (aflipL > 0) && (g == 1);

  __shared__ unsigned short A_lds[BM][72];
  __shared__ unsigned short B_lds[BN][72];
  int tid = threadIdx.x;
  int w = tid >> 6, lane = tid & 63, li = lane & 15, lg = lane >> 4;
  int bm = blockIdx.y * BM, bn = blockIdx.x * BN;
  int wm = (w & 1) * (BM / 2), wn = (w >> 1) * (BN / 2);
  f32x4 acc[FM][FN] = {};

  const int kqA = (tid & 15) * 4, r0A = tid >> 4;
  const int kqB = (tid & 7) * 8,  r0B = tid >> 3;

  for (int k0 = 0; k0 < K; k0 += 64) {
    __syncthreads();
    float4 cw4 = {1.f, 1.f, 1.f, 1.f};
    if (colw) cw4 = *(const float4*)(colw + k0 + kqA);
    #pragma unroll
    for (int i = 0; i < BM / 16; i++) {
      int m = bm + r0A + 16 * i;
      int mm = m;
      if (flip) { int bb = m / aflipL; int t = m - bb * aflipL; mm = bb * aflipL + (aflipL - 1 - t); }
      float4 av = *(const float4*)(A + (long)mm * lda + k0 + kqA);
      float sc = invrow ? invrow[mm] : 1.f;
      short4v ap = { (short)f2bf(av.x * sc * cw4.x), (short)f2bf(av.y * sc * cw4.y),
                     (short)f2bf(av.z * sc * cw4.z), (short)f2bf(av.w * sc * cw4.w) };
      *(short4v*)(&A_lds[r0A + 16 * i][kqA]) = ap;
    }
    #pragma unroll
    for (int i = 0; i < BN / 32; i++) {
      int n = bn + r0B + 32 * i;
      bf16x8 bv = *(const bf16x8*)(WT + (long)n * K + k0 + kqB);
      *(bf16x8*)(&B_lds[r0B + 32 * i][kqB]) = bv;
    }
    __syncthreads();
    #pragma unroll
    for (int ks = 0; ks < 2; ks++) {
      bf16x8 af[FM], bfr[FN];
      #pragma unroll
      for (int fm = 0; fm < FM; fm++)
        af[fm] = *(const bf16x8*)(&A_lds[wm + fm * 16 + li][ks * 32 + lg * 8]);
      #pragma unroll
      for (int fn = 0; fn < FN; fn++)
        bfr[fn] = *(const bf16x8*)(&B_lds[wn + fn * 16 + li][ks * 32 + lg * 8]);
      #pragma unroll
      for (int fm = 0; fm < FM; fm++)
        #pragma unroll
        for (int fn = 0; fn < FN; fn++)
          acc[fm][fn] = __builtin_amdgcn_mfma_f32_16x16x32_bf16(af[fm], bfr[fn], acc[fm][fn], 0, 0, 0);
    }
  }
  #pragma unroll
  for (int fm = 0; fm < FM; fm++) {
    #pragma unroll
    for (int fn = 0; fn < FN; fn++) {
      int n = bn + wn + fn * 16 + li;
      float bv = bias ? bias[n] : 0.f;
      #pragma unroll
      for (int r = 0; r < 4; r++) {
        int m = bm + wm + fm * 16 + 4 * lg + r;
        float v = acc[fm][fn][r] + bv;
        if (act == 1) v = softplusf(v);
        if (resid) v += resid[(long)m * ldc + n];
        C[(long)m * ldc + n] = v;
      }
    }
  }
}

// ---------------------------------------------------------------- fused dt/B/C GEMM (64x64 tile)
__global__ __launch_bounds__(256) void gemm_dtbc(
    const float* __restrict__ A, const unsigned short* __restrict__ WT2,
    const float* __restrict__ bdt, float* __restrict__ dtv, float* __restrict__ bc,
    int layer)
{
  int g = blockIdx.z;
  A   += (long)g * BB * SEQL * DD;
  WT2 += (long)g * 640 * DD;
  dtv += (long)g * BB * SEQL * DD;
  bc  += (long)g * BB * SEQL * 32;
  bdt += (long)(layer * 2 + g) * DD;

  __shared__ unsigned short A_lds[64][72];
  __shared__ unsigned short B_lds[64][72];
  int tid = threadIdx.x;
  int w = tid >> 6, lane = tid & 63, li = lane & 15, lg = lane >> 4;
  int bm = blockIdx.y * 64, bn = blockIdx.x * 64;
  int wm = (w & 1) * 32, wn = (w >> 1) * 32;
  f32x4 acc[2][2] = {};

  const int kqA = (tid & 15) * 4, r0A = tid >> 4;
  const int kqB = (tid & 7) * 8,  r0B = tid >> 3;

  for (int k0 = 0; k0 < DD; k0 += 64) {
    __syncthreads();
    #pragma unroll
    for (int i = 0; i < 4; i++) {
      int m = bm + r0A + 16 * i;
      float4 av = *(const float4*)(A + (long)m * DD + k0 + kqA);
      short4v ap = { (short)f2bf(av.x), (short)f2bf(av.y), (short)f2bf(av.z), (short)f2bf(av.w) };
      *(short4v*)(&A_lds[r0A + 16 * i][kqA]) = ap;
    }
    #pragma unroll
    for (int i = 0; i < 2; i++) {
      int n = bn + r0B + 32 * i;   // <= 639, within arena
      bf16x8 bv = *(const bf16x8*)(WT2 + (long)n * DD + k0 + kqB);
      *(bf16x8*)(&B_lds[r0B + 32 * i][kqB]) = bv;
    }
    __syncthreads();
    #pragma unroll
    for (int ks = 0; ks < 2; ks++) {
      bf16x8 af[2], bfr[2];
      #pragma unroll
      for (int fm = 0; fm < 2; fm++)
        af[fm] = *(const bf16x8*)(&A_lds[wm + fm * 16 + li][ks * 32 + lg * 8]);
      #pragma unroll
      for (int fn = 0; fn < 2; fn++)
        bfr[fn] = *(const bf16x8*)(&B_lds[wn + fn * 16 + li][ks * 32 + lg * 8]);
      #pragma unroll
      for (int fm = 0; fm < 2; fm++)
        #pragma unroll
        for (int fn = 0; fn < 2; fn++)
          acc[fm][fn] = __builtin_amdgcn_mfma_f32_16x16x32_bf16(af[fm], bfr[fn], acc[fm][fn], 0, 0, 0);
    }
  }
  #pragma unroll
  for (int fm = 0; fm < 2; fm++) {
    #pragma unroll
    for (int fn = 0; fn < 2; fn++) {
      int n = bn + wn + fn * 16 + li;
      if (n < 512) {
        float bv = bdt[n];
        #pragma unroll
        for (int r = 0; r < 4; r++) {
          int m = bm + wm + fm * 16 + 4 * lg + r;
          dtv[(long)m * DD + n] = softplusf(acc[fm][fn][r] + bv);
        }
      } else if (n < 544) {
        #pragma unroll
        for (int r = 0; r < 4; r++) {
          int m = bm + wm + fm * 16 + 4 * lg + r;
          bc[(long)m * 32 + (n - 512)] = acc[fm][fn][r];
        }
      }
    }
  }
}

// ---------------------------------------------------------------- conv + SiLU
__global__ __launch_bounds__(256) void conv_silu_kernel(
    const float* __restrict__ xz, const float* __restrict__ cw, const float* __restrict__ cb,
    float* __restrict__ xc, int layer)
{
  long idx = (long)blockIdx.x * 256 + threadIdx.x;  // (g,b,t,c)
  int c = idx % DD;
  long r = idx / DD;
  int t = r % SEQL;
  long gb = r / SEQL;
  int g = (int)(gb / BB);
  const float* w = cw + ((long)(layer * 2 + g) * DD + c) * KCC;
  float acc = cb[(long)(layer * 2 + g) * DD + c];
  const float* xp = xz + (r - t) * 2 * DD + c;
  #pragma unroll
  for (int k = 0; k < KCC; k++) {
    int tt = t - (KCC - 1) + k;
    if (tt >= 0) acc = fmaf(xp[(long)tt * 2 * DD], w[k], acc);
  }
  xc[idx] = siluf(acc);
}

// ---------------------------------------------------------------- chunked scan
__global__ __launch_bounds__(256) void scan_chunk_kernel(
    const float* __restrict__ dtv, const float* __restrict__ xc,
    const float* __restrict__ bc, const float* __restrict__ Alog,
    float* __restrict__ P, float* __restrict__ Hend, int layer)
{
  int chunk = blockIdx.x, dtile = blockIdx.y, gb = blockIdx.z;
  int g = gb / BB;
  int tid = threadIdx.x;
  int n = tid & 15, dl = tid >> 4;
  int d = dtile * 16 + dl;
  int t0 = chunk * TC;
  __shared__ float dtv_s[TC][16], xc_s[TC][16], B_s[TC][17];
  {
    int c = tid & 15, rr = tid >> 4;
    long base = ((long)gb * SEQL + t0) * DD + dtile * 16;
    long dbase = ((long)gb * SEQL + t0) * 32;
    #pragma unroll
    for (int i = 0; i < 4; i++) {
      int tl = rr + i * 16;
      dtv_s[tl][c] = dtv[base + (long)tl * DD + c];
      xc_s[tl][c]  = xc[base + (long)tl * DD + c];
      B_s[tl][c]   = bc[dbase + (long)tl * 32 + c];
    }
  }
  __syncthreads();
  float a = -expf(Alog[((long)((layer * 2 + g) * DD) + d) * NN + n]);
  float h = 0.f, sdt = 0.f;
  #pragma unroll 4
  for (int t = 0; t < TC; t++) {
    float dt = dtv_s[t][dl];
    float dA = expf(dt * a);
    h = fmaf(dA, h, dt * B_s[t][n] * xc_s[t][dl]);
    sdt += dt;
  }
  int r = (gb * DD + d) * NN + n;
  long o = (long)chunk * NR + r;
  P[o] = expf(a * sdt);
  Hend[o] = h;
}

__global__ __launch_bounds__(256) void scan_combine_kernel(
    const float* __restrict__ P, const float* __restrict__ Hend, float* __restrict__ Hin)
{
  int r = blockIdx.x * 256 + threadIdx.x;
  float h = 0.f;
  #pragma unroll
  for (int c = 0; c < NC; c++) {
    Hin[(long)c * NR + r] = h;
    h = fmaf(P[(long)c * NR + r], h, Hend[(long)c * NR + r]);
  }
}

__global__ __launch_bounds__(256) void scan_apply_kernel(
    const float* __restrict__ dtv, const float* __restrict__ xc, const float* __restrict__ xz,
    const float* __restrict__ bc, const float* __restrict__ Alog, const float* __restrict__ Dp,
    const float* __restrict__ Hin, float* __restrict__ ym, int layer)
{
  int chunk = blockIdx.x, dtile = blockIdx.y, gb = blockIdx.z;
  int g = gb / BB;
  int tid = threadIdx.x;
  int n = tid & 15, dl = tid >> 4;
  int d = dtile * 16 + dl;
  int t0 = chunk * TC;
  __shared__ float dtv_s[TC][16], xc_s[TC][16], B_s[TC][17], C_s[TC][17], y_s[TC][16];
  {
    int c = tid & 15, rr = tid >> 4;
    long base = ((long)gb * SEQL + t0) * DD + dtile * 16;
    long dbase = ((long)gb * SEQL + t0) * 32;
    #pragma unroll
    for (int i = 0; i < 4; i++) {
      int tl = rr + i * 16;
      dtv_s[tl][c] = dtv[base + (long)tl * DD + c];
      xc_s[tl][c]  = xc[base + (long)tl * DD + c];
      B_s[tl][c]   = bc[dbase + (long)tl * 32 + c];
      C_s[tl][c]   = bc[dbase + (long)tl * 32 + 16 + c];
    }
  }
  __syncthreads();
  float a = -expf(Alog[((long)((layer * 2 + g) * DD) + d) * NN + n]);
  int r = (gb * DD + d) * NN + n;
  float h = Hin[(long)chunk * NR + r];
  #pragma unroll 4
  for (int t = 0; t < TC; t++) {
    float dt = dtv_s[t][dl];
    float dA = expf(dt * a);
    h = fmaf(dA, h, dt * B_s[t][n] * xc_s[t][dl]);
    float val = h * C_s[t][n];
    val += __shfl_xor(val, 1);
    val += __shfl_xor(val, 2);
    val += __shfl_xor(val, 4);
    val += __shfl_xor(val, 8);
    if (n == 0) y_s[t][dl] = val;
  }
  __syncthreads();
  {
    int c = tid & 15, rr = tid >> 4;
    long base = ((long)gb * SEQL + t0) * DD + dtile * 16;
    long zbase = ((long)gb * SEQL + t0) * 2 * DD + DD + dtile * 16;
    float Dpc = Dp[(long)(layer * 2 + g) * DD + dtile * 16 + c];
    #pragma unroll
    for (int i = 0; i < 4; i++) {
      int tl = rr + i * 16;
      float z = xz[zbase + (long)tl * 2 * DD + c];
      ym[base + (long)tl * DD + c] = (y_s[tl][c] + Dpc * xc_s[tl][c]) * siluf(z);
    }
  }
}

// ---------------------------------------------------------------- dir combine
__global__ __launch_bounds__(256) void combine_kernel(
    const float* __restrict__ yp, const float* __restrict__ proj, float* __restrict__ yc)
{
  long idx = (long)blockIdx.x * 256 + threadIdx.x;  // (b,t,d)
  int d = idx % DD;
  long r = idx / DD;
  int t = r % SEQL;
  long b = r / SEQL;
  float y0 = yp[idx];
  float y1 = yp[(long)BB * SEQL * DD + (b * SEQL + (SEQL - 1 - t)) * (long)DD + d];
  const float* pr = proj + r * 3 * DD;
  float zf = pr[DD + d];
  float zr = pr[2 * DD + d];
  yc[idx] = y0 * siluf(zf) + y1 * siluf(zr);
}

// ---------------------------------------------------------------- bias index table
__global__ void tab_kernel(unsigned short* __restrict__ tab)
{
  int idx = blockIdx.x * blockDim.x + threadIdx.x;
  if (idx >= 2047) return;
  int di = idx - 1023;
  int ad = di < 0 ? -di : di;
  float pr = expf(logf((SEQL + 1) * 0.5f) / 16.0f);
  int n0 = 16;
  for (int n = 15; n >= 0; n--) {
    float cw = powf(pr, (float)(n + 1));
    if ((float)ad <= cw) n0 = n;
  }
  tab[idx] = (unsigned short)(di == 0 ? 34 : (di < 0 ? n0 : 17 + n0));
}

// ---------------------------------------------------------------- qw suffix (dense)
__global__ __launch_bounds__(256) void qw_kernel(
    const float* __restrict__ q, const float* __restrict__ w_rel, float* __restrict__ S, int layer)
{
  int itile = blockIdx.x;   // 16
  int bh = blockIdx.y;      // 16
  int h = bh % HH, b = bh / HH;
  int i0 = itile * 64;
  __shared__ float q_s[64][65];
  __shared__ float w_s[64][33];
  __shared__ float qwn[64][33];
  int tid = threadIdx.x;
  {
    int r = tid >> 2, c4 = (tid & 3) * 16;
    const float* qr = q + ((long)(b * SEQL + i0 + r)) * DD + h * 64 + c4;
    #pragma unroll
    for (int e = 0; e < 4; e++) {
      float4 v = *(const float4*)(qr + e * 4);
      q_s[r][c4 + e * 4 + 0] = v.x; q_s[r][c4 + e * 4 + 1] = v.y;
      q_s[r][c4 + e * 4 + 2] = v.z; q_s[r][c4 + e * 4 + 3] = v.w;
    }
  }
  for (int idx = tid; idx < 64 * 32; idx += 256) {
    int d = idx >> 5, n = idx & 31;
    w_s[d][n] = w_rel[((long)(layer * HH + h) * DHH + d) * PPB + n];
  }
  __syncthreads();
  {
    int i = tid & 63, ngrp = tid >> 6;
    float acc[8] = {};
    #pragma unroll 8
    for (int d = 0; d < 64; d++) {
      float qv = q_s[i][d];
      #pragma unroll
      for (int e = 0; e < 8; e++) acc[e] = fmaf(qv, w_s[d][ngrp * 8 + e], acc[e]);
    }
    #pragma unroll
    for (int e = 0; e < 8; e++) qwn[i][ngrp * 8 + e] = acc[e];
  }
  __syncthreads();
  for (int idx = tid; idx < 64 * 17; idx += 256) {
    int il = idx / 17, m = idx % 17;
    float s1 = 0.f, s2 = 0.f;
    for (int n = m; n < 16; n++) { s1 += qwn[il][n]; s2 += qwn[il][16 + n]; }
    float* Sp = S + ((long)bh * SEQL + i0 + il) * 34;
    Sp[m] = s1;
    Sp[17 + m] = s2;
  }
}

__global__ __launch_bounds__(256) void vw_kernel(
    const float* __restrict__ vparam, const float* __restrict__ w_rel, float* __restrict__ VS, int layer)
{
  __shared__ float vws[HH][PPB];
  int tid = threadIdx.x;
  int h = tid / PPB, n = tid % PPB;
  const float* vp = vparam + (long)(layer * HH + h) * DHH;
  const float* wp = w_rel + ((long)(layer * HH + h) * DHH) * PPB + n;
  float s = 0.f;
  for (int d = 0; d < DHH; d++) s = fmaf(vp[d], wp[d * PPB], s);
  vws[h][n] = s;
  __syncthreads();
  if (tid < HH * 17) {
    int hh = tid / 17, m = tid % 17;
    float s1 = 0.f, s2 = 0.f;
    for (int nn = m; nn < 16; nn++) { s1 += vws[hh][nn]; s2 += vws[hh][16 + nn]; }
    VS[hh * 34 + m] = s1;
    VS[hh * 34 + 17 + m] = s2;
  }
}

__global__ __launch_bounds__(256) void uk_kernel(
    const float* __restrict__ u, const float* __restrict__ k, float* __restrict__ uk, int layer)
{
  int wid = (blockIdx.x * 256 + threadIdx.x) >> 6;
  int lane = threadIdx.x & 63;
  if (wid >= BB * HH * SEQL) return;
  int j = wid % SEQL;
  int bh = wid / SEQL;
  int h = bh % HH;
  int b = bh / HH;
  float vv = u[(long)(layer * HH + h) * DHH + lane] * k[((long)(b * SEQL + j) * HH + h) * DHH + lane];
  for (int o = 32; o; o >>= 1) vv += __shfl_down(vv, o);
  if (lane == 0) uk[(long)bh * SEQL + j] = vv;
}

// ---------------------------------------------------------------- MFMA attention
__global__ __launch_bounds__(256) void attn_mfma_kernel(
    const float* __restrict__ q, const float* __restrict__ k, const float* __restrict__ vv,
    const float* __restrict__ S, const float* __restrict__ VS, const float* __restrict__ uk,
    const unsigned short* __restrict__ tab, float* __restrict__ out)
{
  __shared__ __align__(16) char smem[39680];
  unsigned short* K_lds  = (unsigned short*)(smem);
  unsigned short* VT_lds = (unsigned short*)(smem + 8704);
  unsigned short* PT_lds = (unsigned short*)(smem + 17408);
  float* E               = (float*)(smem + 26112);
  unsigned short* tab_s  = (unsigned short*)(smem + 35328);
  float* uk_s            = (float*)(smem + 39424);
  float* O_lds           = (float*)(smem);

  int itile = blockIdx.x;
  int bh = blockIdx.y;
  int h = bh % HH, b = bh / HH;
  int i0 = itile * 64;
  int tid = threadIdx.x;
  int w = tid >> 6;
  int lane = tid & 63;
  int li = lane & 15, lg = lane >> 4;

  for (int idx = tid; idx < 64 * 17; idx += 256) {
    int il = idx / 17, m = idx % 17;
    long srow = ((long)bh * SEQL + i0 + il) * 34;
    float c0 = S[srow + m]      + VS[h * 34 + m];
    float c1 = S[srow + 17 + m] + VS[h * 34 + 17 + m];
    E[il * 36 + m]      = c0 - c1;
    E[il * 36 + 17 + m] = c0 + c1;
    if (m == 0) E[il * 36 + 34] = c0;
  }
  for (int idx = tid; idx < 2047; idx += 256) tab_s[idx] = tab[idx];

  int iq = i0 + w * 16 + li;
  const float* qrow = q + ((long)(b * SEQL + iq)) * DD + h * 64;
  bf16x8 qf0 = pack8(qrow + 8 * lg);
  bf16x8 qf1 = pack8(qrow + 32 + 8 * lg);

  f32x4 oacc[4] = {};
  float mrun = -1e30f, lrun = 0.f;
  const int ibase = i0 + w * 16 + li;
  unsigned short* PTw = PT_lds + w * 16 * 68;
  const float* Erow = E + (w * 16 + li) * 36;

  for (int j0 = 0; j0 < SEQL; j0 += 64) {
    __syncthreads();
    {
      int jl = tid >> 4;
      int dq = (tid & 15) * 4;
      #pragma unroll
      for (int rr = 0; rr < 4; rr++) {
        int jj = jl + rr * 16;
        long grow = ((long)(b * SEQL + j0 + jj)) * DD + h * 64 + dq;
        float4 kv = *(const float4*)(k + grow);
        short4v kp = { (short)f2bf(kv.x), (short)f2bf(kv.y), (short)f2bf(kv.z), (short)f2bf(kv.w) };
        *(short4v*)(K_lds + jj * 68 + dq) = kp;
        float4 vvv = *(const float4*)(vv + grow);
        VT_lds[(dq + 0) * 68 + jj] = f2bf(vvv.x);
        VT_lds[(dq + 1) * 68 + jj] = f2bf(vvv.y);
        VT_lds[(dq + 2) * 68 + jj] = f2bf(vvv.z);
        VT_lds[(dq + 3) * 68 + jj] = f2bf(vvv.w);
      }
      if (tid < 64) uk_s[tid] = uk[(long)bh * SEQL + j0 + tid];
    }
    __syncthreads();

    f32x4 sf[4];
    #pragma unroll
    for (int jj = 0; jj < 4; jj++) {
      f32x4 c = {};
      c = __builtin_amdgcn_mfma_f32_16x16x32_bf16(
            ld_frag(K_lds + (jj * 16 + li) * 68 + 8 * lg), qf0, c, 0, 0, 0);
      c = __builtin_amdgcn_mfma_f32_16x16x32_bf16(
            ld_frag(K_lds + (jj * 16 + li) * 68 + 32 + 8 * lg), qf1, c, 0, 0, 0);
      sf[jj] = c;
    }

    float sv[4][4];
    float tmax = -1e30f;
    #pragma unroll
    for (int jj = 0; jj < 4; jj++) {
      #pragma unroll
      for (int r = 0; r < 4; r++) {
        int jloc = jj * 16 + 4 * lg + r;
        int di = (j0 + jloc) - ibase;
        int id = tab_s[1023 + di];
        float val = (sf[jj][r] + Erow[id] + uk_s[jloc]) * 0.125f;
        sv[jj][r] = val;
        tmax = fmaxf(tmax, val);
      }
    }
    tmax = fmaxf(tmax, __shfl_xor(tmax, 16));
    tmax = fmaxf(tmax, __shfl_xor(tmax, 32));
    float mnew = fmaxf(mrun, tmax);
    float fsc = __expf(mrun - mnew);
    mrun = mnew;
    lrun *= fsc;
    #pragma unroll
    for (int df = 0; df < 4; df++) oacc[df] *= fsc;

    float psum = 0.f;
    #pragma unroll
    for (int jj = 0; jj < 4; jj++) {
      short4v pk;
      #pragma unroll
      for (int r = 0; r < 4; r++) {
        float p = __expf(sv[jj][r] - mnew);
        psum += p;
        pk[r] = (short)f2bf(p);
      }
      *(short4v*)(PTw + li * 68 + jj * 16 + 4 * lg) = pk;
    }
    psum += __shfl_xor(psum, 16);
    psum += __shfl_xor(psum, 32);
    lrun += psum;

    asm volatile("s_waitcnt lgkmcnt(0)" ::: "memory");

    bf16x8 pf0 = ld_frag(PTw + li * 68 + 8 * lg);
    bf16x8 pf1 = ld_frag(PTw + li * 68 + 32 + 8 * lg);
    #pragma unroll
    for (int df = 0; df < 4; df++) {
      f32x4 c = oacc[df];
      c = __builtin_amdgcn_mfma_f32_16x16x32_bf16(
            ld_frag(VT_lds + (df * 16 + li) * 68 + 8 * lg), pf0, c, 0, 0, 0);
      c = __builtin_amdgcn_mfma_f32_16x16x32_bf16(
            ld_frag(VT_lds + (df * 16 + li) * 68 + 32 + 8 * lg), pf1, c, 0, 0, 0);
      oacc[df] = c;
    }
  }

  __syncthreads();
  float inv = 1.f / lrun;
  #pragma unroll
  for (int df = 0; df < 4; df++) {
    f32x4 o = oacc[df] * inv;
    *(f32x4*)(O_lds + (w * 16 + li) * 68 + df * 16 + 4 * lg) = o;
  }
  __syncthreads();
  {
    int il = tid >> 2, c0 = (tid & 3) * 16;
    long orow = ((long)(b * SEQL + i0 + il)) * DD + h * 64 + c0;
    #pragma unroll
    for (int c4 = 0; c4 < 4; c4++) {
      f32x4 o = *(const f32x4*)(O_lds + il * 68 + c0 + c4 * 4);
      *(f32x4*)(out + orow + c4 * 4) = o;
    }
  }
}

// ---------------------------------------------------------------- launch
extern "C" void kernel_launch(void* const* d_in, const int* in_sizes, int n_in,
                              void* d_out, int out_size, void* d_ws, size_t ws_size,
                              hipStream_t stream) {
  const float* x_in     = (const float*)d_in[0];
  const float* rms_m    = (const float*)d_in[1];
  const float* W_in     = (const float*)d_in[2];
  const float* b_in     = (const float*)d_in[3];
  const float* m_Win    = (const float*)d_in[4];
  const float* m_conv_w = (const float*)d_in[5];
  const float* m_conv_b = (const float*)d_in[6];
  const float* m_Wx     = (const float*)d_in[7];
  const float* m_Wdt    = (const float*)d_in[8];
  const float* m_bdt    = (const float*)d_in[9];
  const float* m_Alog   = (const float*)d_in[10];
  const float* m_Dp     = (const float*)d_in[11];
  const float* m_Wout   = (const float*)d_in[12];
  const float* W_out    = (const float*)d_in[13];
  const float* b_out    = (const float*)d_in[14];
  const float* rms_a    = (const float*)d_in[15];
  const float* Wq       = (const float*)d_in[16];
  const float* Wk       = (const float*)d_in[17];
  const float* Wv       = (const float*)d_in[18];
  const float* u_p      = (const float*)d_in[19];
  const float* v_p      = (const float*)d_in[20];
  const float* w_rel    = (const float*)d_in[21];
  const float* Wo       = (const float*)d_in[22];
  const float* b_o      = (const float*)d_in[23];
  float* out = (float*)d_out;

  float* ws = (float*)d_ws;
  const long U = (long)BB * SEQL * DD;      // 1,048,576 floats
  float* xA    = ws;
  float* xB    = ws + 1 * U;
  float* xn    = ws + 2 * U;                // scan P/Hend scratch
  float* proj  = ws + 3 * U;                // 3U; later q,k,v
  float* xz    = ws + 6 * U;                // 4U; later yp (2U)
  float* xc    = ws + 10 * U;               // 2U
  float* dtv   = ws + 12 * U;               // 2U
  float* ym    = ws + 14 * U;               // 2U; later attnout
  float* ycomb = ws + 16 * U;               // 1U; also scan Hin scratch
  float* smallb= ws + 17 * U;               // 1U of small buffers
  float* bcbuf = smallb;                    // 131072
  float* ukbuf = smallb + 262144;           // 16384
  float* Sbuf  = smallb + 278528;           // 557056
  float* VSbuf = smallb + 835584;           // 272
  unsigned short* tabg = (unsigned short*)(smallb + 835856);  // 2047 u16
  float* invm  = smallb + 836880;           // 2048
  float* inva  = smallb + 838928;           // 2048
  unsigned short* WTA = (unsigned short*)(ws + 18 * U);       // 2 * AR_L shorts
  float* yp = xz;
  float* qb = proj;
  float* kb = proj + U;
  float* vb = proj + 2 * U;
  float* attnout = ym;
  float* Pbuf = xn;
  float* Hend = xn + (long)NC * NR;
  float* Hin  = ycomb;

  const int M = BB * SEQL;                  // 2048

  // ---- preamble: bias table + all weight preprocessing ----
  tab_kernel<<<8, 256, 0, stream>>>(tabg);

  TDs td;
  int cum = 0, idx = 0;
  auto add = [&](const float* s, unsigned short* dst, int ldsrc, int K, int N) {
    td.a[idx].src = s; td.a[idx].dst = dst; td.a[idx].ldsrc = ldsrc;
    td.a[idx].K = K; td.a[idx].N = N; td.a[idx].t0 = cum;
    cum += (N / 32) * (K / 32); idx++;
  };
  for (int l = 0; l < LL; l++) {
    unsigned short* base = WTA + (long)l * AR_L;
    add(W_in   + (long)l * DD * 3 * DD,        base + OFF_WIN,            3 * DD, DD, 3 * DD);
    add(m_Win  + (long)(l * 2 + 0) * DD * 2 * DD, base + OFF_MWIN,          2 * DD, DD, 2 * DD);
    add(m_Win  + (long)(l * 2 + 1) * DD * 2 * DD, base + OFF_MWIN + 524288, 2 * DD, DD, 2 * DD);
    add(m_Wout + (long)(l * 2 + 0) * DD * DD,  base + OFF_MWOUT,          DD, DD, DD);
    add(m_Wout + (long)(l * 2 + 1) * DD * DD,  base + OFF_MWOUT + 262144, DD, DD, DD);
    add(W_out  + (long)l * DD * DD,            base + OFF_WOUT,           DD, DD, DD);
    add(Wq     + (long)l * DD * DD,            base + OFF_QKV,            DD, DD, DD);
    add(Wk     + (long)l * DD * DD,            base + OFF_QKV + 262144,   DD, DD, DD);
    add(Wv     + (long)l * DD * DD,            base + OFF_QKV + 524288,   DD, DD, DD);
    add(Wo     + (long)l * DD * DD,            base + OFF_WO,             DD, DD, DD);
    add(m_Wx   + (long)(l * 2 + 0) * DD * 64 + 32, base + OFF_WT2 + 262144,          64, DD, 32);
    add(m_Wx   + (long)(l * 2 + 1) * DD * 64 + 32, base + OFF_WT2 + 327680 + 262144, 64, DD, 32);
  }
  wtrans_all<<<cum, 256, 0, stream>>>(td);
  weff_kernel<<<dim3(16, 16, 2 * LL), 256, 0, stream>>>(m_Wx, m_Wdt, WTA);

  for (int layer = 0; layer < LL; layer++) {
    const float* cur = (layer == 0) ? x_in : xA;
    unsigned short* base = WTA + (long)layer * AR_L;
    // ---- mamba block ----
    rmsinv_kernel<<<M / 4, 256, 0, stream>>>(cur, invm);
    gemm_bf16_t<64, 64><<<dim3(24, 32, 1), 256, 0, stream>>>(cur, base + OFF_WIN,
        b_in + layer * 3 * DD, nullptr, invm, rms_m + layer * DD, proj,
        M, 3 * DD, DD, DD, 3 * DD, 0, 0, 0, 0, 0, 0);
    gemm_bf16_t<64, 64><<<dim3(16, 32, 2), 256, 0, stream>>>(proj, base + OFF_MWIN,
        nullptr, nullptr, nullptr, nullptr, xz, M, 2 * DD, DD, 3 * DD, 2 * DD,
        0, 524288, 0, (long)BB * SEQL * 2 * DD, SEQL, 0);
    conv_silu_kernel<<<(2 * BB * SEQL * DD) / 256, 256, 0, stream>>>(xz, m_conv_w, m_conv_b, xc, layer);
    gemm_dtbc<<<dim3(9, 32, 2), 256, 0, stream>>>(xc, base + OFF_WT2, m_bdt, dtv, bcbuf, layer);
    scan_chunk_kernel<<<dim3(NC, DD / 16, GBS), 256, 0, stream>>>(
        dtv, xc, bcbuf, m_Alog, Pbuf, Hend, layer);
    scan_combine_kernel<<<NR / 256, 256, 0, stream>>>(Pbuf, Hend, Hin);
    scan_apply_kernel<<<dim3(NC, DD / 16, GBS), 256, 0, stream>>>(
        dtv, xc, xz, bcbuf, m_Alog, m_Dp, Hin, ym, layer);
    gemm_bf16_t<64, 64><<<dim3(8, 32, 2), 256, 0, stream>>>(ym, base + OFF_MWOUT,
        nullptr, nullptr, nullptr, nullptr, yp, M, DD, DD, DD, DD,
        U, 262144, 0, U, 0, 0);
    combine_kernel<<<(int)(U / 256), 256, 0, stream>>>(yp, proj, ycomb);
    gemm_bf16_t<64, 64><<<dim3(8, 32, 1), 256, 0, stream>>>(ycomb, base + OFF_WOUT,
        b_out + layer * DD, cur, nullptr, nullptr, xB, M, DD, DD, DD, DD, 0, 0, 0, 0, 0, 0);

    // ---- attention block ----
    rmsinv_kernel<<<M / 4, 256, 0, stream>>>(xB, inva);
    gemm_bf16_t<64, 64><<<dim3(8, 32, 3), 256, 0, stream>>>(xB, base + OFF_QKV,
        nullptr, nullptr, inva, rms_a + layer * DD, qb, M, DD, DD, DD, DD,
        0, 262144, 0, U, 0, 0);
    qw_kernel<<<dim3(16, 16), 256, 0, stream>>>(qb, w_rel, Sbuf, layer);
    vw_kernel<<<1, 256, 0, stream>>>(v_p, w_rel, VSbuf, layer);
    uk_kernel<<<(BB * HH * SEQL) / 4, 256, 0, stream>>>(u_p, kb, ukbuf, layer);
    attn_mfma_kernel<<<dim3(SEQL / 64, BB * HH), 256, 0, stream>>>(
        qb, kb, vb, Sbuf, VSbuf, ukbuf, tabg, attnout);

    float* outp = (layer == LL - 1) ? out : xA;
    gemm_bf16_t<64, 64><<<dim3(8, 32, 1), 256, 0, stream>>>(attnout, base + OFF_WO,
        b_o + layer * DD, xB, nullptr, nullptr, outp, M, DD, DD, DD, DD, 0, 0, 0, 0, 0, 0);
  }
}

// Round 8
// 614.473 us; speedup vs baseline: 7.9193x; 1.0696x over previous
//
#include <hip/hip_runtime.h>

#define LL 2
#define BB 2
#define SEQL 1024
#define DD 512
#define NN 16
#define HH 8
#define DHH 64
#define PPB 32
#define KCC 4
#define DTRR 32

#define GBS 4              // g*BB+b combinations
#define TC 64              // scan chunk length
#define NC (SEQL / TC)     // 16 chunks
#define NR (GBS * DD * NN) // 32768 recurrences
#define BHN (BB * HH * SEQL) // 16384 attention rows

// weight arena (shorts), per layer
#define AR_L     4325376L
#define OFF_WIN  0L
#define OFF_MWIN 786432L
#define OFF_WT2  1835008L
#define OFF_MWOUT 2490368L
#define OFF_WOUT 3014656L
#define OFF_QKV  3276800L
#define OFF_WO   4063232L

typedef __attribute__((ext_vector_type(8))) short bf16x8;
typedef __attribute__((ext_vector_type(4))) short short4v;
typedef __attribute__((ext_vector_type(4))) float f32x4;

__device__ __forceinline__ float siluf(float x) { return x / (1.f + __expf(-x)); }
__device__ __forceinline__ float softplusf(float x) { return x > 20.f ? x : log1pf(__expf(x)); }

__device__ __forceinline__ unsigned short f2bf(float x) {
  union { float f; unsigned u; } v; v.f = x;
  unsigned r = v.u + 0x7fff + ((v.u >> 16) & 1);
  return (unsigned short)(r >> 16);
}

__device__ __forceinline__ bf16x8 ld_frag(const unsigned short* p) {
  short4v a = *(const short4v*)(p);
  short4v b = *(const short4v*)(p + 4);
  bf16x8 r;
  r[0]=a[0]; r[1]=a[1]; r[2]=a[2]; r[3]=a[3];
  r[4]=b[0]; r[5]=b[1]; r[6]=b[2]; r[7]=b[3];
  return r;
}

__device__ __forceinline__ bf16x8 pack8(const float* p) {
  bf16x8 r;
  #pragma unroll
  for (int e = 0; e < 8; e++) r[e] = (short)f2bf(p[e]);
  return r;
}

// ---------------------------------------------------------------- batched weight transpose
struct TD { const float* src; unsigned short* dst; int ldsrc; int K; int N; int t0; };
struct TDs { TD a[24]; };

__global__ __launch_bounds__(256) void wtrans_all(TDs ds)
{
  int bid = blockIdx.x;
  int mi = 0;
  #pragma unroll 1
  for (int i = 1; i < 24; i++) if (bid >= ds.a[i].t0) mi = i;
  TD d = ds.a[mi];
  int local = bid - d.t0;
  int tilesN = d.N >> 5;
  int tn = local % tilesN, tk = local / tilesN;
  __shared__ float t[32][33];
  int tx = threadIdx.x & 31, ty = threadIdx.x >> 5;
  int n0 = tn * 32, k0 = tk * 32;
  #pragma unroll
  for (int i = 0; i < 4; i++)
    t[ty + 8 * i][tx] = d.src[(long)(k0 + ty + 8 * i) * d.ldsrc + n0 + tx];
  __syncthreads();
  #pragma unroll
  for (int i = 0; i < 4; i++)
    d.dst[(long)(n0 + ty + 8 * i) * d.K + k0 + tx] = f2bf(t[tx][ty + 8 * i]);
}

// ---------------------------------------------------------------- Weff = Wx[:, :32] @ Wdt
__global__ __launch_bounds__(256) void weff_kernel(
    const float* __restrict__ Wx, const float* __restrict__ Wdt,
    unsigned short* __restrict__ WTA)
{
  int lg = blockIdx.z;
  int l = lg >> 1, g = lg & 1;
  const float* wx = Wx + (long)(l * 2 + g) * DD * 64;
  const float* wd = Wdt + (long)(l * 2 + g) * DTRR * DD;
  unsigned short* wt = WTA + (long)l * AR_L + OFF_WT2 + (long)g * 327680;
  int n0 = blockIdx.x * 32, k0 = blockIdx.y * 32;
  __shared__ float wx_s[32][33];
  __shared__ float wd_s[32][33];
  int tx = threadIdx.x & 31, ty = threadIdx.x >> 5;
  #pragma unroll
  for (int i = 0; i < 4; i++) {
    wx_s[ty + 8 * i][tx] = wx[(long)(k0 + ty + 8 * i) * 64 + tx];
    wd_s[ty + 8 * i][tx] = wd[(long)(ty + 8 * i) * DD + n0 + tx];
  }
  __syncthreads();
  #pragma unroll
  for (int i = 0; i < 4; i++) {
    int nl = ty + 8 * i;
    float s = 0.f;
    #pragma unroll
    for (int r = 0; r < 32; r++) s = fmaf(wx_s[tx][r], wd_s[r][nl], s);
    wt[(long)(n0 + nl) * DD + k0 + tx] = f2bf(s);
  }
}

// ---------------------------------------------------------------- RMS inverse-norm (per row)
__global__ __launch_bounds__(256) void rmsinv_kernel(
    const float* __restrict__ x, float* __restrict__ inv)
{
  int row = blockIdx.x * 4 + (threadIdx.x >> 6);
  int lane = threadIdx.x & 63;
  const float* xr = x + (long)row * DD;
  float4 a = *(const float4*)(xr + lane * 4);
  float4 b = *(const float4*)(xr + 256 + lane * 4);
  float s = a.x*a.x + a.y*a.y + a.z*a.z + a.w*a.w + b.x*b.x + b.y*b.y + b.z*b.z + b.w*b.w;
  for (int o = 32; o; o >>= 1) s += __shfl_down(s, o);
  if (lane == 0) inv[row] = rsqrtf(s / (float)DD + 1e-6f);
}

// ---------------------------------------------------------------- GEMM (bf16 MFMA, tiled)
template<int BM, int BN>
__global__ __launch_bounds__(256) void gemm_bf16_t(
    const float* __restrict__ A, const unsigned short* __restrict__ WT,
    const float* __restrict__ bias, const float* __restrict__ resid,
    const float* __restrict__ invrow, const float* __restrict__ colw,
    float* __restrict__ C,
    int M, int N, int K, int lda, int ldc,
    long aBatch, long wBatch, long biasBatch, long cBatch,
    int aflipL, int act)
{
  constexpr int FM = BM / 32;
  constexpr int FN = BN / 32;
  int g = blockIdx.z;
  A  += (long)g * aBatch;
  WT += (long)g * wBatch;
  C  += (long)g * cBatch;
  if (bias) bias += (long)g * biasBatch;
  const bool flip = (aflipL > 0) && (g == 1);

  __shared__ unsigned short A_lds[BM][72];
  __shared__ unsigned short B_lds[BN][72];
  int tid = threadIdx.x;
  int w = tid >> 6, lane = tid & 63, li = lane & 15, lg = lane >> 4;
  int bm = blockIdx.y * BM, bn = blockIdx.x * BN;
  int wm = (w & 1) * (BM / 2), wn = (w >> 1) * (BN / 2);
  f32x4 acc[FM][FN] = {};

  const int kqA = (tid & 15) * 4, r0A = tid >> 4;
  const int kqB = (tid & 7) * 8,  r0B = tid >> 3;

  for (int k0 = 0; k0 < K; k0 += 64) {
    __syncthreads();
    float4 cw4 = {1.f, 1.f, 1.f, 1.f};
    if (colw) cw4 = *(const float4*)(colw + k0 + kqA);
    #pragma unroll
    for (int i = 0; i < BM / 16; i++) {
      int m = bm + r0A + 16 * i;
      int mm = m;
      if (flip) { int bb = m / aflipL; int t = m - bb * aflipL; mm = bb * aflipL + (aflipL - 1 - t); }
      float4 av = *(const float4*)(A + (long)mm * lda + k0 + kqA);
      float sc = invrow ? invrow[mm] : 1.f;
      short4v ap = { (short)f2bf(av.x * sc * cw4.x), (short)f2bf(av.y * sc * cw4.y),
                     (short)f2bf(av.z * sc * cw4.z), (short)f2bf(av.w * sc * cw4.w) };
      *(short4v*)(&A_lds[r0A + 16 * i][kqA]) = ap;
    }
    #pragma unroll
    for (int i = 0; i < BN / 32; i++) {
      int n = bn + r0B + 32 * i;
      bf16x8 bv = *(const bf16x8*)(WT + (long)n * K + k0 + kqB);
      *(bf16x8*)(&B_lds[r0B + 32 * i][kqB]) = bv;
    }
    __syncthreads();
    #pragma unroll
    for (int ks = 0; ks < 2; ks++) {
      bf16x8 af[FM], bfr[FN];
      #pragma unroll
      for (int fm = 0; fm < FM; fm++)
        af[fm] = *(const bf16x8*)(&A_lds[wm + fm * 16 + li][ks * 32 + lg * 8]);
      #pragma unroll
      for (int fn = 0; fn < FN; fn++)
        bfr[fn] = *(const bf16x8*)(&B_lds[wn + fn * 16 + li][ks * 32 + lg * 8]);
      #pragma unroll
      for (int fm = 0; fm < FM; fm++)
        #pragma unroll
        for (int fn = 0; fn < FN; fn++)
          acc[fm][fn] = __builtin_amdgcn_mfma_f32_16x16x32_bf16(af[fm], bfr[fn], acc[fm][fn], 0, 0, 0);
    }
  }
  #pragma unroll
  for (int fm = 0; fm < FM; fm++) {
    #pragma unroll
    for (int fn = 0; fn < FN; fn++) {
      int n = bn + wn + fn * 16 + li;
      float bv = bias ? bias[n] : 0.f;
      #pragma unroll
      for (int r = 0; r < 4; r++) {
        int m = bm + wm + fm * 16 + 4 * lg + r;
        float v = acc[fm][fn][r] + bv;
        if (act == 1) v = softplusf(v);
        if (resid) v += resid[(long)m * ldc + n];
        C[(long)m * ldc + n] = v;
      }
    }
  }
}

// ---------------------------------------------------------------- fused dt/B/C GEMM (64x64 tile)
__global__ __launch_bounds__(256) void gemm_dtbc(
    const float* __restrict__ A, const unsigned short* __restrict__ WT2,
    const float* __restrict__ bdt, float* __restrict__ dtv, float* __restrict__ bc,
    int layer)
{
  int g = blockIdx.z;
  A   += (long)g * BB * SEQL * DD;
  WT2 += (long)g * 640 * DD;
  dtv += (long)g * BB * SEQL * DD;
  bc  += (long)g * BB * SEQL * 32;
  bdt += (long)(layer * 2 + g) * DD;

  __shared__ unsigned short A_lds[64][72];
  __shared__ unsigned short B_lds[64][72];
  int tid = threadIdx.x;
  int w = tid >> 6, lane = tid & 63, li = lane & 15, lg = lane >> 4;
  int bm = blockIdx.y * 64, bn = blockIdx.x * 64;
  int wm = (w & 1) * 32, wn = (w >> 1) * 32;
  f32x4 acc[2][2] = {};

  const int kqA = (tid & 15) * 4, r0A = tid >> 4;
  const int kqB = (tid & 7) * 8,  r0B = tid >> 3;

  for (int k0 = 0; k0 < DD; k0 += 64) {
    __syncthreads();
    #pragma unroll
    for (int i = 0; i < 4; i++) {
      int m = bm + r0A + 16 * i;
      float4 av = *(const float4*)(A + (long)m * DD + k0 + kqA);
      short4v ap = { (short)f2bf(av.x), (short)f2bf(av.y), (short)f2bf(av.z), (short)f2bf(av.w) };
      *(short4v*)(&A_lds[r0A + 16 * i][kqA]) = ap;
    }
    #pragma unroll
    for (int i = 0; i < 2; i++) {
      int n = bn + r0B + 32 * i;
      bf16x8 bv = *(const bf16x8*)(WT2 + (long)n * DD + k0 + kqB);
      *(bf16x8*)(&B_lds[r0B + 32 * i][kqB]) = bv;
    }
    __syncthreads();
    #pragma unroll
    for (int ks = 0; ks < 2; ks++) {
      bf16x8 af[2], bfr[2];
      #pragma unroll
      for (int fm = 0; fm < 2; fm++)
        af[fm] = *(const bf16x8*)(&A_lds[wm + fm * 16 + li][ks * 32 + lg * 8]);
      #pragma unroll
      for (int fn = 0; fn < 2; fn++)
        bfr[fn] = *(const bf16x8*)(&B_lds[wn + fn * 16 + li][ks * 32 + lg * 8]);
      #pragma unroll
      for (int fm = 0; fm < 2; fm++)
        #pragma unroll
        for (int fn = 0; fn < 2; fn++)
          acc[fm][fn] = __builtin_amdgcn_mfma_f32_16x16x32_bf16(af[fm], bfr[fn], acc[fm][fn], 0, 0, 0);
    }
  }
  #pragma unroll
  for (int fm = 0; fm < 2; fm++) {
    #pragma unroll
    for (int fn = 0; fn < 2; fn++) {
      int n = bn + wn + fn * 16 + li;
      if (n < 512) {
        float bv = bdt[n];
        #pragma unroll
        for (int r = 0; r < 4; r++) {
          int m = bm + wm + fm * 16 + 4 * lg + r;
          dtv[(long)m * DD + n] = softplusf(acc[fm][fn][r] + bv);
        }
      } else if (n < 544) {
        #pragma unroll
        for (int r = 0; r < 4; r++) {
          int m = bm + wm + fm * 16 + 4 * lg + r;
          bc[(long)m * 32 + (n - 512)] = acc[fm][fn][r];
        }
      }
    }
  }
}

// ---------------------------------------------------------------- conv + SiLU
__global__ __launch_bounds__(256) void conv_silu_kernel(
    const float* __restrict__ xz, const float* __restrict__ cw, const float* __restrict__ cb,
    float* __restrict__ xc, int layer)
{
  long idx = (long)blockIdx.x * 256 + threadIdx.x;  // (g,b,t,c)
  int c = idx % DD;
  long r = idx / DD;
  int t = r % SEQL;
  long gb = r / SEQL;
  int g = (int)(gb / BB);
  const float* w = cw + ((long)(layer * 2 + g) * DD + c) * KCC;
  float acc = cb[(long)(layer * 2 + g) * DD + c];
  const float* xp = xz + (r - t) * 2 * DD + c;
  #pragma unroll
  for (int k = 0; k < KCC; k++) {
    int tt = t - (KCC - 1) + k;
    if (tt >= 0) acc = fmaf(xp[(long)tt * 2 * DD], w[k], acc);
  }
  xc[idx] = siluf(acc);
}

// ---------------------------------------------------------------- chunked scan
__global__ __launch_bounds__(256) void scan_chunk_kernel(
    const float* __restrict__ dtv, const float* __restrict__ xc,
    const float* __restrict__ bc, const float* __restrict__ Alog,
    float* __restrict__ P, float* __restrict__ Hend, int layer)
{
  int chunk = blockIdx.x, dtile = blockIdx.y, gb = blockIdx.z;
  int g = gb / BB;
  int tid = threadIdx.x;
  int n = tid & 15, dl = tid >> 4;
  int d = dtile * 16 + dl;
  int t0 = chunk * TC;
  __shared__ float dtv_s[TC][16], xc_s[TC][16], B_s[TC][17];
  {
    int c = tid & 15, rr = tid >> 4;
    long base = ((long)gb * SEQL + t0) * DD + dtile * 16;
    long dbase = ((long)gb * SEQL + t0) * 32;
    #pragma unroll
    for (int i = 0; i < 4; i++) {
      int tl = rr + i * 16;
      dtv_s[tl][c] = dtv[base + (long)tl * DD + c];
      xc_s[tl][c]  = xc[base + (long)tl * DD + c];
      B_s[tl][c]   = bc[dbase + (long)tl * 32 + c];
    }
  }
  __syncthreads();
  float a = -__expf(Alog[((long)((layer * 2 + g) * DD) + d) * NN + n]);
  float h = 0.f, sdt = 0.f;
  #pragma unroll 4
  for (int t = 0; t < TC; t++) {
    float dt = dtv_s[t][dl];
    float dA = __expf(dt * a);
    h = fmaf(dA, h, dt * B_s[t][n] * xc_s[t][dl]);
    sdt += dt;
  }
  int r = (gb * DD + d) * NN + n;
  long o = (long)chunk * NR + r;
  P[o] = __expf(a * sdt);
  Hend[o] = h;
}

__global__ __launch_bounds__(256) void scan_combine_kernel(
    const float* __restrict__ P, const float* __restrict__ Hend, float* __restrict__ Hin)
{
  int r = blockIdx.x * 256 + threadIdx.x;
  float h = 0.f;
  #pragma unroll
  for (int c = 0; c < NC; c++) {
    Hin[(long)c * NR + r] = h;
    h = fmaf(P[(long)c * NR + r], h, Hend[(long)c * NR + r]);
  }
}

__global__ __launch_bounds__(256) void scan_apply_kernel(
    const float* __restrict__ dtv, const float* __restrict__ xc, const float* __restrict__ xz,
    const float* __restrict__ bc, const float* __restrict__ Alog, const float* __restrict__ Dp,
    const float* __restrict__ Hin, float* __restrict__ ym, int layer)
{
  int chunk = blockIdx.x, dtile = blockIdx.y, gb = blockIdx.z;
  int g = gb / BB;
  int tid = threadIdx.x;
  int n = tid & 15, dl = tid >> 4;
  int d = dtile * 16 + dl;
  int t0 = chunk * TC;
  __shared__ float dtv_s[TC][16], xc_s[TC][16], B_s[TC][17], C_s[TC][17], y_s[TC][16];
  {
    int c = tid & 15, rr = tid >> 4;
    long base = ((long)gb * SEQL + t0) * DD + dtile * 16;
    long dbase = ((long)gb * SEQL + t0) * 32;
    #pragma unroll
    for (int i = 0; i < 4; i++) {
      int tl = rr + i * 16;
      dtv_s[tl][c] = dtv[base + (long)tl * DD + c];
      xc_s[tl][c]  = xc[base + (long)tl * DD + c];
      B_s[tl][c]   = bc[dbase + (long)tl * 32 + c];
      C_s[tl][c]   = bc[dbase + (long)tl * 32 + 16 + c];
    }
  }
  __syncthreads();
  float a = -__expf(Alog[((long)((layer * 2 + g) * DD) + d) * NN + n]);
  int r = (gb * DD + d) * NN + n;
  float h = Hin[(long)chunk * NR + r];
  #pragma unroll 4
  for (int t = 0; t < TC; t++) {
    float dt = dtv_s[t][dl];
    float dA = __expf(dt * a);
    h = fmaf(dA, h, dt * B_s[t][n] * xc_s[t][dl]);
    float val = h * C_s[t][n];
    val += __shfl_xor(val, 1);
    val += __shfl_xor(val, 2);
    val += __shfl_xor(val, 4);
    val += __shfl_xor(val, 8);
    if (n == 0) y_s[t][dl] = val;
  }
  __syncthreads();
  {
    int c = tid & 15, rr = tid >> 4;
    long base = ((long)gb * SEQL + t0) * DD + dtile * 16;
    long zbase = ((long)gb * SEQL + t0) * 2 * DD + DD + dtile * 16;
    float Dpc = Dp[(long)(layer * 2 + g) * DD + dtile * 16 + c];
    #pragma unroll
    for (int i = 0; i < 4; i++) {
      int tl = rr + i * 16;
      float z = xz[zbase + (long)tl * 2 * DD + c];
      ym[base + (long)tl * DD + c] = (y_s[tl][c] + Dpc * xc_s[tl][c]) * siluf(z);
    }
  }
}

// ---------------------------------------------------------------- dir combine
__global__ __launch_bounds__(256) void combine_kernel(
    const float* __restrict__ yp, const float* __restrict__ proj, float* __restrict__ yc)
{
  long idx = (long)blockIdx.x * 256 + threadIdx.x;  // (b,t,d)
  int d = idx % DD;
  long r = idx / DD;
  int t = r % SEQL;
  long b = r / SEQL;
  float y0 = yp[idx];
  float y1 = yp[(long)BB * SEQL * DD + (b * SEQL + (SEQL - 1 - t)) * (long)DD + d];
  const float* pr = proj + r * 3 * DD;
  float zf = pr[DD + d];
  float zr = pr[2 * DD + d];
  yc[idx] = y0 * siluf(zf) + y1 * siluf(zr);
}

// ---------------------------------------------------------------- bias index table
__global__ void tab_kernel(unsigned short* __restrict__ tab)
{
  int idx = blockIdx.x * blockDim.x + threadIdx.x;
  if (idx >= 2047) return;
  int di = idx - 1023;
  int ad = di < 0 ? -di : di;
  float pr = expf(logf((SEQL + 1) * 0.5f) / 16.0f);
  int n0 = 16;
  for (int n = 15; n >= 0; n--) {
    float cw = powf(pr, (float)(n + 1));
    if ((float)ad <= cw) n0 = n;
  }
  tab[idx] = (unsigned short)(di == 0 ? 34 : (di < 0 ? n0 : 17 + n0));
}

// ---------------------------------------------------------------- qw suffix (dense)
__global__ __launch_bounds__(256) void qw_kernel(
    const float* __restrict__ q, const float* __restrict__ w_rel, float* __restrict__ S, int layer)
{
  int itile = blockIdx.x;
  int bh = blockIdx.y;
  int h = bh % HH, b = bh / HH;
  int i0 = itile * 64;
  __shared__ float q_s[64][65];
  __shared__ float w_s[64][33];
  __shared__ float qwn[64][33];
  int tid = threadIdx.x;
  {
    int r = tid >> 2, c4 = (tid & 3) * 16;
    const float* qr = q + ((long)(b * SEQL + i0 + r)) * DD + h * 64 + c4;
    #pragma unroll
    for (int e = 0; e < 4; e++) {
      float4 v = *(const float4*)(qr + e * 4);
      q_s[r][c4 + e * 4 + 0] = v.x; q_s[r][c4 + e * 4 + 1] = v.y;
      q_s[r][c4 + e * 4 + 2] = v.z; q_s[r][c4 + e * 4 + 3] = v.w;
    }
  }
  for (int idx = tid; idx < 64 * 32; idx += 256) {
    int d = idx >> 5, n = idx & 31;
    w_s[d][n] = w_rel[((long)(layer * HH + h) * DHH + d) * PPB + n];
  }
  __syncthreads();
  {
    int i = tid & 63, ngrp = tid >> 6;
    float acc[8] = {};
    #pragma unroll 8
    for (int d = 0; d < 64; d++) {
      float qv = q_s[i][d];
      #pragma unroll
      for (int e = 0; e < 8; e++) acc[e] = fmaf(qv, w_s[d][ngrp * 8 + e], acc[e]);
    }
    #pragma unroll
    for (int e = 0; e < 8; e++) qwn[i][ngrp * 8 + e] = acc[e];
  }
  __syncthreads();
  for (int idx = tid; idx < 64 * 17; idx += 256) {
    int il = idx / 17, m = idx % 17;
    float s1 = 0.f, s2 = 0.f;
    for (int n = m; n < 16; n++) { s1 += qwn[il][n]; s2 += qwn[il][16 + n]; }
    float* Sp = S + ((long)bh * SEQL + i0 + il) * 34;
    Sp[m] = s1;
    Sp[17 + m] = s2;
  }
}

__global__ __launch_bounds__(256) void vw_kernel(
    const float* __restrict__ vparam, const float* __restrict__ w_rel, float* __restrict__ VS)
{
  int layer = blockIdx.x;
  __shared__ float vws[HH][PPB];
  int tid = threadIdx.x;
  int h = tid / PPB, n = tid % PPB;
  const float* vp = vparam + (long)(layer * HH + h) * DHH;
  const float* wp = w_rel + ((long)(layer * HH + h) * DHH) * PPB + n;
  float s = 0.f;
  for (int d = 0; d < DHH; d++) s = fmaf(vp[d], wp[d * PPB], s);
  vws[h][n] = s;
  __syncthreads();
  if (tid < HH * 17) {
    int hh = tid / 17, m = tid % 17;
    float s1 = 0.f, s2 = 0.f;
    for (int nn = m; nn < 16; nn++) { s1 += vws[hh][nn]; s2 += vws[hh][16 + nn]; }
    VS[layer * 272 + hh * 34 + m] = s1;
    VS[layer * 272 + hh * 34 + 17 + m] = s2;
  }
}

__global__ __launch_bounds__(256) void uk_kernel(
    const float* __restrict__ u, const float* __restrict__ k, float* __restrict__ uk, int layer)
{
  int wid = (blockIdx.x * 256 + threadIdx.x) >> 6;
  int lane = threadIdx.x & 63;
  if (wid >= BB * HH * SEQL) return;
  int j = wid % SEQL;
  int bh = wid / SEQL;
  int h = bh % HH;
  int b = bh / HH;
  float vv = u[(long)(layer * HH + h) * DHH + lane] * k[((long)(b * SEQL + j) * HH + h) * DHH + lane];
  for (int o = 32; o; o >>= 1) vv += __shfl_down(vv, o);
  if (lane == 0) uk[(long)bh * SEQL + j] = vv;
}

// ---------------------------------------------------------------- MFMA attention (split-KV)
__global__ __launch_bounds__(256) void attn_mfma_kernel(
    const float* __restrict__ q, const float* __restrict__ k, const float* __restrict__ vv,
    const float* __restrict__ S, const float* __restrict__ VS, const float* __restrict__ uk,
    const unsigned short* __restrict__ tab,
    float* __restrict__ opart, float* __restrict__ mbuf, float* __restrict__ lbuf)
{
  __shared__ __align__(16) char smem[39680];
  unsigned short* K_lds  = (unsigned short*)(smem);
  unsigned short* VT_lds = (unsigned short*)(smem + 8704);
  unsigned short* PT_lds = (unsigned short*)(smem + 17408);
  float* E               = (float*)(smem + 26112);
  unsigned short* tab_s  = (unsigned short*)(smem + 35328);
  float* uk_s            = (float*)(smem + 39424);
  float* O_lds           = (float*)(smem);

  int itile = blockIdx.x;
  int bh = blockIdx.y;
  int split = blockIdx.z;
  int h = bh % HH, b = bh / HH;
  int i0 = itile * 64;
  int tid = threadIdx.x;
  int w = tid >> 6;
  int lane = tid & 63;
  int li = lane & 15, lg = lane >> 4;

  for (int idx = tid; idx < 64 * 17; idx += 256) {
    int il = idx / 17, m = idx % 17;
    long srow = ((long)bh * SEQL + i0 + il) * 34;
    float c0 = S[srow + m]      + VS[h * 34 + m];
    float c1 = S[srow + 17 + m] + VS[h * 34 + 17 + m];
    E[il * 36 + m]      = c0 - c1;
    E[il * 36 + 17 + m] = c0 + c1;
    if (m == 0) E[il * 36 + 34] = c0;
  }
  for (int idx = tid; idx < 2047; idx += 256) tab_s[idx] = tab[idx];

  int iq = i0 + w * 16 + li;
  const float* qrow = q + ((long)(b * SEQL + iq)) * DD + h * 64;
  bf16x8 qf0 = pack8(qrow + 8 * lg);
  bf16x8 qf1 = pack8(qrow + 32 + 8 * lg);

  f32x4 oacc[4] = {};
  float mrun = -1e30f, lrun = 0.f;
  const int ibase = i0 + w * 16 + li;
  unsigned short* PTw = PT_lds + w * 16 * 68;
  const float* Erow = E + (w * 16 + li) * 36;

  const int jbase = split * (SEQL / 2);
  for (int jt = 0; jt < SEQL / 2; jt += 64) {
    int j0 = jbase + jt;
    __syncthreads();
    {
      int jl = tid >> 4;
      int dq = (tid & 15) * 4;
      #pragma unroll
      for (int rr = 0; rr < 4; rr++) {
        int jj = jl + rr * 16;
        long grow = ((long)(b * SEQL + j0 + jj)) * DD + h * 64 + dq;
        float4 kv = *(const float4*)(k + grow);
        short4v kp = { (short)f2bf(kv.x), (short)f2bf(kv.y), (short)f2bf(kv.z), (short)f2bf(kv.w) };
        *(short4v*)(K_lds + jj * 68 + dq) = kp;
        float4 vvv = *(const float4*)(vv + grow);
        VT_lds[(dq + 0) * 68 + jj] = f2bf(vvv.x);
        VT_lds[(dq + 1) * 68 + jj] = f2bf(vvv.y);
        VT_lds[(dq + 2) * 68 + jj] = f2bf(vvv.z);
        VT_lds[(dq + 3) * 68 + jj] = f2bf(vvv.w);
      }
      if (tid < 64) uk_s[tid] = uk[(long)bh * SEQL + j0 + tid];
    }
    __syncthreads();

    f32x4 sf[4];
    #pragma unroll
    for (int jj = 0; jj < 4; jj++) {
      f32x4 c = {};
      c = __builtin_amdgcn_mfma_f32_16x16x32_bf16(
            ld_frag(K_lds + (jj * 16 + li) * 68 + 8 * lg), qf0, c, 0, 0, 0);
      c = __builtin_amdgcn_mfma_f32_16x16x32_bf16(
            ld_frag(K_lds + (jj * 16 + li) * 68 + 32 + 8 * lg), qf1, c, 0, 0, 0);
      sf[jj] = c;
    }

    float sv[4][4];
    float tmax = -1e30f;
    #pragma unroll
    for (int jj = 0; jj < 4; jj++) {
      #pragma unroll
      for (int r = 0; r < 4; r++) {
        int jloc = jj * 16 + 4 * lg + r;
        int di = (j0 + jloc) - ibase;
        int id = tab_s[1023 + di];
        float val = (sf[jj][r] + Erow[id] + uk_s[jloc]) * 0.125f;
        sv[jj][r] = val;
        tmax = fmaxf(tmax, val);
      }
    }
    tmax = fmaxf(tmax, __shfl_xor(tmax, 16));
    tmax = fmaxf(tmax, __shfl_xor(tmax, 32));
    float mnew = fmaxf(mrun, tmax);
    float fsc = __expf(mrun - mnew);
    mrun = mnew;
    lrun *= fsc;
    #pragma unroll
    for (int df = 0; df < 4; df++) oacc[df] *= fsc;

    float psum = 0.f;
    #pragma unroll
    for (int jj = 0; jj < 4; jj++) {
      short4v pk;
      #pragma unroll
      for (int r = 0; r < 4; r++) {
        float p = __expf(sv[jj][r] - mnew);
        psum += p;
        pk[r] = (short)f2bf(p);
      }
      *(short4v*)(PTw + li * 68 + jj * 16 + 4 * lg) = pk;
    }
    psum += __shfl_xor(psum, 16);
    psum += __shfl_xor(psum, 32);
    lrun += psum;

    asm volatile("s_waitcnt lgkmcnt(0)" ::: "memory");

    bf16x8 pf0 = ld_frag(PTw + li * 68 + 8 * lg);
    bf16x8 pf1 = ld_frag(PTw + li * 68 + 32 + 8 * lg);
    #pragma unroll
    for (int df = 0; df < 4; df++) {
      f32x4 c = oacc[df];
      c = __builtin_amdgcn_mfma_f32_16x16x32_bf16(
            ld_frag(VT_lds + (df * 16 + li) * 68 + 8 * lg), pf0, c, 0, 0, 0);
      c = __builtin_amdgcn_mfma_f32_16x16x32_bf16(
            ld_frag(VT_lds + (df * 16 + li) * 68 + 32 + 8 * lg), pf1, c, 0, 0, 0);
      oacc[df] = c;
    }
  }

  // ---- epilogue: write unnormalized O-partial + (m,l) ----
  __syncthreads();
  if (lg == 0) {
    long row = (long)split * BHN + (long)bh * SEQL + (i0 + w * 16 + li);
    mbuf[row] = mrun;
    lbuf[row] = lrun;
  }
  #pragma unroll
  for (int df = 0; df < 4; df++)
    *(f32x4*)(O_lds + (w * 16 + li) * 68 + df * 16 + 4 * lg) = oacc[df];
  __syncthreads();
  {
    int il = tid >> 2, c0 = (tid & 3) * 16;
    long orow = ((long)split * BHN + (long)bh * SEQL + i0 + il) * 64 + c0;
    #pragma unroll
    for (int c4 = 0; c4 < 4; c4++) {
      f32x4 o = *(const f32x4*)(O_lds + il * 68 + c0 + c4 * 4);
      *(f32x4*)(opart + orow + c4 * 4) = o;
    }
  }
}

// ---------------------------------------------------------------- attention split combine
__global__ __launch_bounds__(256) void attn_combine_kernel(
    const float* __restrict__ opart, const float* __restrict__ mbuf,
    const float* __restrict__ lbuf, float* __restrict__ out)
{
  int idx = blockIdx.x * 256 + threadIdx.x;   // BHN*64 = 1,048,576
  int row = idx >> 6, d = idx & 63;
  int bh = row >> 10, i = row & 1023;
  int b = bh >> 3, h = bh & 7;
  float m0 = mbuf[row], m1 = mbuf[BHN + row];
  float l0 = lbuf[row], l1 = lbuf[BHN + row];
  float m = fmaxf(m0, m1);
  float e0 = __expf(m0 - m), e1 = __expf(m1 - m);
  float inv = 1.f / (l0 * e0 + l1 * e1);
  float o = (opart[(long)row * 64 + d] * e0 + opart[((long)BHN + row) * 64 + d] * e1) * inv;
  out[((long)(b * SEQL + i)) * DD + h * 64 + d] = o;
}

// ---------------------------------------------------------------- launch
extern "C" void kernel_launch(void* const* d_in, const int* in_sizes, int n_in,
                              void* d_out, int out_size, void* d_ws, size_t ws_size,
                              hipStream_t stream) {
  const float* x_in     = (const float*)d_in[0];
  const float* rms_m    = (const float*)d_in[1];
  const float* W_in     = (const float*)d_in[2];
  const float* b_in     = (const float*)d_in[3];
  const float* m_Win    = (const float*)d_in[4];
  const float* m_conv_w = (const float*)d_in[5];
  const float* m_conv_b = (const float*)d_in[6];
  const float* m_Wx     = (const float*)d_in[7];
  const float* m_Wdt    = (const float*)d_in[8];
  const float* m_bdt    = (const float*)d_in[9];
  const float* m_Alog   = (const float*)d_in[10];
  const float* m_Dp     = (const float*)d_in[11];
  const float* m_Wout   = (const float*)d_in[12];
  const float* W_out    = (const float*)d_in[13];
  const float* b_out    = (const float*)d_in[14];
  const float* rms_a    = (const float*)d_in[15];
  const float* Wq       = (const float*)d_in[16];
  const float* Wk       = (const float*)d_in[17];
  const float* Wv       = (const float*)d_in[18];
  const float* u_p      = (const float*)d_in[19];
  const float* v_p      = (const float*)d_in[20];
  const float* w_rel    = (const float*)d_in[21];
  const float* Wo       = (const float*)d_in[22];
  const float* b_o      = (const float*)d_in[23];
  float* out = (float*)d_out;

  float* ws = (float*)d_ws;
  const long U = (long)BB * SEQL * DD;      // 1,048,576 floats
  float* xA    = ws;
  float* xB    = ws + 1 * U;
  float* xn    = ws + 2 * U;                // scan P/Hend scratch
  float* proj  = ws + 3 * U;                // 3U; later q,k,v
  float* xz    = ws + 6 * U;                // 4U; later yp (2U)
  float* xc    = ws + 10 * U;               // 2U; attn Opart scratch
  float* dtv   = ws + 12 * U;               // 2U; attn m/l scratch
  float* ym    = ws + 14 * U;               // 2U; later attnout
  float* ycomb = ws + 16 * U;               // 1U; also scan Hin scratch
  float* smallb= ws + 17 * U;               // 1U of small buffers
  float* bcbuf = smallb;                    // 131072
  float* ukbuf = smallb + 262144;           // 16384
  float* Sbuf  = smallb + 278528;           // 557056
  float* VSbuf = smallb + 835584;           // 2*272
  unsigned short* tabg = (unsigned short*)(smallb + 836880);  // 2047 u16
  float* invm  = smallb + 838928;           // 2048
  float* inva  = smallb + 840976;           // 2048
  unsigned short* WTA = (unsigned short*)(ws + 18 * U);       // 2 * AR_L shorts
  float* yp = xz;
  float* qb = proj;
  float* kb = proj + U;
  float* vb = proj + 2 * U;
  float* attnout = ym;
  float* Pbuf = xn;
  float* Hend = xn + (long)NC * NR;
  float* Hin  = ycomb;
  float* opart = xc;                        // 2*BHN*64 = 2M floats (2U)
  float* mbuf  = dtv;                       // 2*BHN = 32768
  float* lbuf  = dtv + 2 * BHN;             // 32768

  const int M = BB * SEQL;                  // 2048

  // ---- preamble: bias table + all weight preprocessing ----
  tab_kernel<<<8, 256, 0, stream>>>(tabg);

  TDs td;
  int cum = 0, idx = 0;
  auto add = [&](const float* s, unsigned short* dst, int ldsrc, int K, int N) {
    td.a[idx].src = s; td.a[idx].dst = dst; td.a[idx].ldsrc = ldsrc;
    td.a[idx].K = K; td.a[idx].N = N; td.a[idx].t0 = cum;
    cum += (N / 32) * (K / 32); idx++;
  };
  for (int l = 0; l < LL; l++) {
    unsigned short* base = WTA + (long)l * AR_L;
    add(W_in   + (long)l * DD * 3 * DD,        base + OFF_WIN,            3 * DD, DD, 3 * DD);
    add(m_Win  + (long)(l * 2 + 0) * DD * 2 * DD, base + OFF_MWIN,          2 * DD, DD, 2 * DD);
    add(m_Win  + (long)(l * 2 + 1) * DD * 2 * DD, base + OFF_MWIN + 524288, 2 * DD, DD, 2 * DD);
    add(m_Wout + (long)(l * 2 + 0) * DD * DD,  base + OFF_MWOUT,          DD, DD, DD);
    add(m_Wout + (long)(l * 2 + 1) * DD * DD,  base + OFF_MWOUT + 262144, DD, DD, DD);
    add(W_out  + (long)l * DD * DD,            base + OFF_WOUT,           DD, DD, DD);
    add(Wq     + (long)l * DD * DD,            base + OFF_QKV,            DD, DD, DD);
    add(Wk     + (long)l * DD * DD,            base + OFF_QKV + 262144,   DD, DD, DD);
    add(Wv     + (long)l * DD * DD,            base + OFF_QKV + 524288,   DD, DD, DD);
    add(Wo     + (long)l * DD * DD,            base + OFF_WO,             DD, DD, DD);
    add(m_Wx   + (long)(l * 2 + 0) * DD * 64 + 32, base + OFF_WT2 + 262144,          64, DD, 32);
    add(m_Wx   + (long)(l * 2 + 1) * DD * 64 + 32, base + OFF_WT2 + 327680 + 262144, 64, DD, 32);
  }
  wtrans_all<<<cum, 256, 0, stream>>>(td);
  weff_kernel<<<dim3(16, 16, 2 * LL), 256, 0, stream>>>(m_Wx, m_Wdt, WTA);
  vw_kernel<<<LL, 256, 0, stream>>>(v_p, w_rel, VSbuf);

  for (int layer = 0; layer < LL; layer++) {
    const float* cur = (layer == 0) ? x_in : xA;
    unsigned short* base = WTA + (long)layer * AR_L;
    // ---- mamba block ----
    rmsinv_kernel<<<M / 4, 256, 0, stream>>>(cur, invm);
    gemm_bf16_t<64, 64><<<dim3(24, 32, 1), 256, 0, stream>>>(cur, base + OFF_WIN,
        b_in + layer * 3 * DD, nullptr, invm, rms_m + layer * DD, proj,
        M, 3 * DD, DD, DD, 3 * DD, 0, 0, 0, 0, 0, 0);
    gemm_bf16_t<64, 64><<<dim3(16, 32, 2), 256, 0, stream>>>(proj, base + OFF_MWIN,
        nullptr, nullptr, nullptr, nullptr, xz, M, 2 * DD, DD, 3 * DD, 2 * DD,
        0, 524288, 0, (long)BB * SEQL * 2 * DD, SEQL, 0);
    conv_silu_kernel<<<(2 * BB * SEQL * DD) / 256, 256, 0, stream>>>(xz, m_conv_w, m_conv_b, xc, layer);
    gemm_dtbc<<<dim3(9, 32, 2), 256, 0, stream>>>(xc, base + OFF_WT2, m_bdt, dtv, bcbuf, layer);
    scan_chunk_kernel<<<dim3(NC, DD / 16, GBS), 256, 0, stream>>>(
        dtv, xc, bcbuf, m_Alog, Pbuf, Hend, layer);
    scan_combine_kernel<<<NR / 256, 256, 0, stream>>>(Pbuf, Hend, Hin);
    scan_apply_kernel<<<dim3(NC, DD / 16, GBS), 256, 0, stream>>>(
        dtv, xc, xz, bcbuf, m_Alog, m_Dp, Hin, ym, layer);
    gemm_bf16_t<64, 64><<<dim3(8, 32, 2), 256, 0, stream>>>(ym, base + OFF_MWOUT,
        nullptr, nullptr, nullptr, nullptr, yp, M, DD, DD, DD, DD,
        U, 262144, 0, U, 0, 0);
    combine_kernel<<<(int)(U / 256), 256, 0, stream>>>(yp, proj, ycomb);
    gemm_bf16_t<64, 64><<<dim3(8, 32, 1), 256, 0, stream>>>(ycomb, base + OFF_WOUT,
        b_out + layer * DD, cur, nullptr, nullptr, xB, M, DD, DD, DD, DD, 0, 0, 0, 0, 0, 0);

    // ---- attention block ----
    rmsinv_kernel<<<M / 4, 256, 0, stream>>>(xB, inva);
    gemm_bf16_t<64, 64><<<dim3(8, 32, 3), 256, 0, stream>>>(xB, base + OFF_QKV,
        nullptr, nullptr, inva, rms_a + layer * DD, qb, M, DD, DD, DD, DD,
        0, 262144, 0, U, 0, 0);
    qw_kernel<<<dim3(16, 16), 256, 0, stream>>>(qb, w_rel, Sbuf, layer);
    uk_kernel<<<(BB * HH * SEQL) / 4, 256, 0, stream>>>(u_p, kb, ukbuf, layer);
    attn_mfma_kernel<<<dim3(SEQL / 64, BB * HH, 2), 256, 0, stream>>>(
        qb, kb, vb, Sbuf, VSbuf + layer * 272, ukbuf, tabg, opart, mbuf, lbuf);
    attn_combine_kernel<<<(BHN * 64) / 256, 256, 0, stream>>>(opart, mbuf, lbuf, attnout);

    float* outp = (layer == LL - 1) ? out : xA;
    gemm_bf16_t<64, 64><<<dim3(8, 32, 1), 256, 0, stream>>>(attnout, base + OFF_WO,
        b_o + layer * DD, xB, nullptr, nullptr, outp, M, DD, DD, DD, DD, 0, 0, 0, 0, 0, 0);
  }
}

// Round 9
// 575.932 us; speedup vs baseline: 8.4493x; 1.0669x over previous
//
#include <hip/hip_runtime.h>

#define LL 2
#define BB 2
#define SEQL 1024
#define DD 512
#define NN 16
#define HH 8
#define DHH 64
#define PPB 32
#define KCC 4
#define DTRR 32

#define GBS 4              // g*BB+b combinations
#define TC 32              // scan chunk length
#define NC (SEQL / TC)     // 32 chunks
#define NR (GBS * DD * NN) // 32768 recurrences
#define BHN (BB * HH * SEQL) // 16384 attention rows

// weight arena (shorts), per layer
#define AR_L     4325376L
#define OFF_WIN  0L
#define OFF_MWIN 786432L
#define OFF_WT2  1835008L
#define OFF_MWOUT 2490368L
#define OFF_WOUT 3014656L
#define OFF_QKV  3276800L
#define OFF_WO   4063232L

typedef __attribute__((ext_vector_type(8))) short bf16x8;
typedef __attribute__((ext_vector_type(4))) short short4v;
typedef __attribute__((ext_vector_type(4))) float f32x4;

__device__ __forceinline__ float siluf(float x) { return x / (1.f + __expf(-x)); }
__device__ __forceinline__ float softplusf(float x) { return x > 20.f ? x : log1pf(__expf(x)); }

__device__ __forceinline__ unsigned short f2bf(float x) {
  union { float f; unsigned u; } v; v.f = x;
  unsigned r = v.u + 0x7fff + ((v.u >> 16) & 1);
  return (unsigned short)(r >> 16);
}

__device__ __forceinline__ bf16x8 ld_frag(const unsigned short* p) {
  short4v a = *(const short4v*)(p);
  short4v b = *(const short4v*)(p + 4);
  bf16x8 r;
  r[0]=a[0]; r[1]=a[1]; r[2]=a[2]; r[3]=a[3];
  r[4]=b[0]; r[5]=b[1]; r[6]=b[2]; r[7]=b[3];
  return r;
}

__device__ __forceinline__ bf16x8 pack8(const float* p) {
  bf16x8 r;
  #pragma unroll
  for (int e = 0; e < 8; e++) r[e] = (short)f2bf(p[e]);
  return r;
}

// ---------------------------------------------------------------- batched weight transpose
struct TD { const float* src; unsigned short* dst; int ldsrc; int K; int N; int t0; };
struct TDs { TD a[24]; };

__global__ __launch_bounds__(256) void wtrans_all(TDs ds)
{
  int bid = blockIdx.x;
  int mi = 0;
  #pragma unroll 1
  for (int i = 1; i < 24; i++) if (bid >= ds.a[i].t0) mi = i;
  TD d = ds.a[mi];
  int local = bid - d.t0;
  int tilesN = d.N >> 5;
  int tn = local % tilesN, tk = local / tilesN;
  __shared__ float t[32][33];
  int tx = threadIdx.x & 31, ty = threadIdx.x >> 5;
  int n0 = tn * 32, k0 = tk * 32;
  #pragma unroll
  for (int i = 0; i < 4; i++)
    t[ty + 8 * i][tx] = d.src[(long)(k0 + ty + 8 * i) * d.ldsrc + n0 + tx];
  __syncthreads();
  #pragma unroll
  for (int i = 0; i < 4; i++)
    d.dst[(long)(n0 + ty + 8 * i) * d.K + k0 + tx] = f2bf(t[tx][ty + 8 * i]);
}

// ---------------------------------------------------------------- Weff = Wx[:, :32] @ Wdt
__global__ __launch_bounds__(256) void weff_kernel(
    const float* __restrict__ Wx, const float* __restrict__ Wdt,
    unsigned short* __restrict__ WTA)
{
  int lg = blockIdx.z;
  int l = lg >> 1, g = lg & 1;
  const float* wx = Wx + (long)(l * 2 + g) * DD * 64;
  const float* wd = Wdt + (long)(l * 2 + g) * DTRR * DD;
  unsigned short* wt = WTA + (long)l * AR_L + OFF_WT2 + (long)g * 327680;
  int n0 = blockIdx.x * 32, k0 = blockIdx.y * 32;
  __shared__ float wx_s[32][33];
  __shared__ float wd_s[32][33];
  int tx = threadIdx.x & 31, ty = threadIdx.x >> 5;
  #pragma unroll
  for (int i = 0; i < 4; i++) {
    wx_s[ty + 8 * i][tx] = wx[(long)(k0 + ty + 8 * i) * 64 + tx];
    wd_s[ty + 8 * i][tx] = wd[(long)(ty + 8 * i) * DD + n0 + tx];
  }
  __syncthreads();
  #pragma unroll
  for (int i = 0; i < 4; i++) {
    int nl = ty + 8 * i;
    float s = 0.f;
    #pragma unroll
    for (int r = 0; r < 32; r++) s = fmaf(wx_s[tx][r], wd_s[r][nl], s);
    wt[(long)(n0 + nl) * DD + k0 + tx] = f2bf(s);
  }
}

// ---------------------------------------------------------------- RMS inverse-norm (per row)
__global__ __launch_bounds__(256) void rmsinv_kernel(
    const float* __restrict__ x, float* __restrict__ inv)
{
  int row = blockIdx.x * 4 + (threadIdx.x >> 6);
  int lane = threadIdx.x & 63;
  const float* xr = x + (long)row * DD;
  float4 a = *(const float4*)(xr + lane * 4);
  float4 b = *(const float4*)(xr + 256 + lane * 4);
  float s = a.x*a.x + a.y*a.y + a.z*a.z + a.w*a.w + b.x*b.x + b.y*b.y + b.z*b.z + b.w*b.w;
  for (int o = 32; o; o >>= 1) s += __shfl_down(s, o);
  if (lane == 0) inv[row] = rsqrtf(s / (float)DD + 1e-6f);
}

// ---------------------------------------------------------------- GEMM (bf16 MFMA, tiled)
template<int BM, int BN>
__global__ __launch_bounds__(256) void gemm_bf16_t(
    const float* __restrict__ A, const unsigned short* __restrict__ WT,
    const float* __restrict__ bias, const float* __restrict__ resid,
    const float* __restrict__ invrow, const float* __restrict__ colw,
    float* __restrict__ C,
    int M, int N, int K, int lda, int ldc,
    long aBatch, long wBatch, long biasBatch, long cBatch,
    int aflipL, int act)
{
  constexpr int FM = BM / 32;
  constexpr int FN = BN / 32;
  int g = blockIdx.z;
  A  += (long)g * aBatch;
  WT += (long)g * wBatch;
  C  += (long)g * cBatch;
  if (bias) bias += (long)g * biasBatch;
  const bool flip = (aflipL > 0) && (g == 1);

  __shared__ unsigned short A_lds[BM][72];
  __shared__ unsigned short B_lds[BN][72];
  int tid = threadIdx.x;
  int w = tid >> 6, lane = tid & 63, li = lane & 15, lg = lane >> 4;
  int bm = blockIdx.y * BM, bn = blockIdx.x * BN;
  int wm = (w & 1) * (BM / 2), wn = (w >> 1) * (BN / 2);
  f32x4 acc[FM][FN] = {};

  const int kqA = (tid & 15) * 4, r0A = tid >> 4;
  const int kqB = (tid & 7) * 8,  r0B = tid >> 3;

  for (int k0 = 0; k0 < K; k0 += 64) {
    __syncthreads();
    float4 cw4 = {1.f, 1.f, 1.f, 1.f};
    if (colw) cw4 = *(const float4*)(colw + k0 + kqA);
    #pragma unroll
    for (int i = 0; i < BM / 16; i++) {
      int m = bm + r0A + 16 * i;
      int mm = m;
      if (flip) { int bb = m / aflipL; int t = m - bb * aflipL; mm = bb * aflipL + (aflipL - 1 - t); }
      float4 av = *(const float4*)(A + (long)mm * lda + k0 + kqA);
      float sc = invrow ? invrow[mm] : 1.f;
      short4v ap = { (short)f2bf(av.x * sc * cw4.x), (short)f2bf(av.y * sc * cw4.y),
                     (short)f2bf(av.z * sc * cw4.z), (short)f2bf(av.w * sc * cw4.w) };
      *(short4v*)(&A_lds[r0A + 16 * i][kqA]) = ap;
    }
    #pragma unroll
    for (int i = 0; i < BN / 32; i++) {
      int n = bn + r0B + 32 * i;
      bf16x8 bv = *(const bf16x8*)(WT + (long)n * K + k0 + kqB);
      *(bf16x8*)(&B_lds[r0B + 32 * i][kqB]) = bv;
    }
    __syncthreads();
    #pragma unroll
    for (int ks = 0; ks < 2; ks++) {
      bf16x8 af[FM], bfr[FN];
      #pragma unroll
      for (int fm = 0; fm < FM; fm++)
        af[fm] = *(const bf16x8*)(&A_lds[wm + fm * 16 + li][ks * 32 + lg * 8]);
      #pragma unroll
      for (int fn = 0; fn < FN; fn++)
        bfr[fn] = *(const bf16x8*)(&B_lds[wn + fn * 16 + li][ks * 32 + lg * 8]);
      #pragma unroll
      for (int fm = 0; fm < FM; fm++)
        #pragma unroll
        for (int fn = 0; fn < FN; fn++)
          acc[fm][fn] = __builtin_amdgcn_mfma_f32_16x16x32_bf16(af[fm], bfr[fn], acc[fm][fn], 0, 0, 0);
    }
  }
  #pragma unroll
  for (int fm = 0; fm < FM; fm++) {
    #pragma unroll
    for (int fn = 0; fn < FN; fn++) {
      int n = bn + wn + fn * 16 + li;
      float bv = bias ? bias[n] : 0.f;
      #pragma unroll
      for (int r = 0; r < 4; r++) {
        int m = bm + wm + fm * 16 + 4 * lg + r;
        float v = acc[fm][fn][r] + bv;
        if (act == 1) v = softplusf(v);
        if (resid) v += resid[(long)m * ldc + n];
        C[(long)m * ldc + n] = v;
      }
    }
  }
}

// ---------------------------------------------------------------- fused dt/B/C GEMM (64x64 tile)
__global__ __launch_bounds__(256) void gemm_dtbc(
    const float* __restrict__ A, const unsigned short* __restrict__ WT2,
    const float* __restrict__ bdt, float* __restrict__ dtv, float* __restrict__ bc,
    int layer)
{
  int g = blockIdx.z;
  A   += (long)g * BB * SEQL * DD;
  WT2 += (long)g * 640 * DD;
  dtv += (long)g * BB * SEQL * DD;
  bc  += (long)g * BB * SEQL * 32;
  bdt += (long)(layer * 2 + g) * DD;

  __shared__ unsigned short A_lds[64][72];
  __shared__ unsigned short B_lds[64][72];
  int tid = threadIdx.x;
  int w = tid >> 6, lane = tid & 63, li = lane & 15, lg = lane >> 4;
  int bm = blockIdx.y * 64, bn = blockIdx.x * 64;
  int wm = (w & 1) * 32, wn = (w >> 1) * 32;
  f32x4 acc[2][2] = {};

  const int kqA = (tid & 15) * 4, r0A = tid >> 4;
  const int kqB = (tid & 7) * 8,  r0B = tid >> 3;

  for (int k0 = 0; k0 < DD; k0 += 64) {
    __syncthreads();
    #pragma unroll
    for (int i = 0; i < 4; i++) {
      int m = bm + r0A + 16 * i;
      float4 av = *(const float4*)(A + (long)m * DD + k0 + kqA);
      short4v ap = { (short)f2bf(av.x), (short)f2bf(av.y), (short)f2bf(av.z), (short)f2bf(av.w) };
      *(short4v*)(&A_lds[r0A + 16 * i][kqA]) = ap;
    }
    #pragma unroll
    for (int i = 0; i < 2; i++) {
      int n = bn + r0B + 32 * i;
      bf16x8 bv = *(const bf16x8*)(WT2 + (long)n * DD + k0 + kqB);
      *(bf16x8*)(&B_lds[r0B + 32 * i][kqB]) = bv;
    }
    __syncthreads();
    #pragma unroll
    for (int ks = 0; ks < 2; ks++) {
      bf16x8 af[2], bfr[2];
      #pragma unroll
      for (int fm = 0; fm < 2; fm++)
        af[fm] = *(const bf16x8*)(&A_lds[wm + fm * 16 + li][ks * 32 + lg * 8]);
      #pragma unroll
      for (int fn = 0; fn < 2; fn++)
        bfr[fn] = *(const bf16x8*)(&B_lds[wn + fn * 16 + li][ks * 32 + lg * 8]);
      #pragma unroll
      for (int fm = 0; fm < 2; fm++)
        #pragma unroll
        for (int fn = 0; fn < 2; fn++)
          acc[fm][fn] = __builtin_amdgcn_mfma_f32_16x16x32_bf16(af[fm], bfr[fn], acc[fm][fn], 0, 0, 0);
    }
  }
  #pragma unroll
  for (int fm = 0; fm < 2; fm++) {
    #pragma unroll
    for (int fn = 0; fn < 2; fn++) {
      int n = bn + wn + fn * 16 + li;
      if (n < 512) {
        float bv = bdt[n];
        #pragma unroll
        for (int r = 0; r < 4; r++) {
          int m = bm + wm + fm * 16 + 4 * lg + r;
          dtv[(long)m * DD + n] = softplusf(acc[fm][fn][r] + bv);
        }
      } else if (n < 544) {
        #pragma unroll
        for (int r = 0; r < 4; r++) {
          int m = bm + wm + fm * 16 + 4 * lg + r;
          bc[(long)m * 32 + (n - 512)] = acc[fm][fn][r];
        }
      }
    }
  }
}

// ---------------------------------------------------------------- conv + SiLU
__global__ __launch_bounds__(256) void conv_silu_kernel(
    const float* __restrict__ xz, const float* __restrict__ cw, const float* __restrict__ cb,
    float* __restrict__ xc, int layer)
{
  long idx = (long)blockIdx.x * 256 + threadIdx.x;  // (g,b,t,c)
  int c = idx % DD;
  long r = idx / DD;
  int t = r % SEQL;
  long gb = r / SEQL;
  int g = (int)(gb / BB);
  const float* w = cw + ((long)(layer * 2 + g) * DD + c) * KCC;
  float acc = cb[(long)(layer * 2 + g) * DD + c];
  const float* xp = xz + (r - t) * 2 * DD + c;
  #pragma unroll
  for (int k = 0; k < KCC; k++) {
    int tt = t - (KCC - 1) + k;
    if (tt >= 0) acc = fmaf(xp[(long)tt * 2 * DD], w[k], acc);
  }
  xc[idx] = siluf(acc);
}

// ---------------------------------------------------------------- chunked scan (8 states/thread)
// Block: 256 threads = 128 d-channels x 2 n-halves. Grid: (NC, DD/128, GBS).
__global__ __launch_bounds__(256) void scan_chunk_kernel(
    const float* __restrict__ dtv, const float* __restrict__ xc,
    const float* __restrict__ bc, const float* __restrict__ Alog,
    float* __restrict__ P, float* __restrict__ Hend, int layer)
{
  int chunk = blockIdx.x, dtile = blockIdx.y, gb = blockIdx.z;
  int g = gb / BB;
  int tid = threadIdx.x;
  int dl = tid >> 1, nh = (tid & 1) * 8;
  int d = dtile * 128 + dl;
  int t0 = chunk * TC;
  __shared__ float dtv_s[TC][128], xc_s[TC][128], BC_s[TC][32];
  {
    long base = ((long)gb * SEQL + t0) * DD + dtile * 128;
    int c4 = (tid & 31) * 4, r0 = tid >> 5;
    #pragma unroll
    for (int i = 0; i < 4; i++) {
      int tl = r0 + i * 8;
      *(float4*)&dtv_s[tl][c4] = *(const float4*)(dtv + base + (long)tl * DD + c4);
      *(float4*)&xc_s[tl][c4]  = *(const float4*)(xc + base + (long)tl * DD + c4);
    }
    long dbase = ((long)gb * SEQL + t0) * 32;
    int cc = (tid & 7) * 4, rr = tid >> 3;
    *(float4*)&BC_s[rr][cc] = *(const float4*)(bc + dbase + (long)rr * 32 + cc);
  }
  __syncthreads();
  const float* Al = Alog + ((long)((layer * 2 + g) * DD) + d) * NN + nh;
  float a[8], h[8] = {};
  #pragma unroll
  for (int n = 0; n < 8; n++) a[n] = -__expf(Al[n]);
  float sdt = 0.f;
  for (int t = 0; t < TC; t++) {
    float dt = dtv_s[t][dl];
    float dx = dt * xc_s[t][dl];
    float4 b0 = *(const float4*)&BC_s[t][nh];
    float4 b1 = *(const float4*)&BC_s[t][nh + 4];
    h[0] = fmaf(__expf(dt * a[0]), h[0], dx * b0.x);
    h[1] = fmaf(__expf(dt * a[1]), h[1], dx * b0.y);
    h[2] = fmaf(__expf(dt * a[2]), h[2], dx * b0.z);
    h[3] = fmaf(__expf(dt * a[3]), h[3], dx * b0.w);
    h[4] = fmaf(__expf(dt * a[4]), h[4], dx * b1.x);
    h[5] = fmaf(__expf(dt * a[5]), h[5], dx * b1.y);
    h[6] = fmaf(__expf(dt * a[6]), h[6], dx * b1.z);
    h[7] = fmaf(__expf(dt * a[7]), h[7], dx * b1.w);
    sdt += dt;
  }
  long o = (long)chunk * NR + ((long)(gb * DD + d)) * NN + nh;
  #pragma unroll
  for (int n = 0; n < 8; n++) {
    P[o + n] = __expf(a[n] * sdt);
    Hend[o + n] = h[n];
  }
}

__global__ __launch_bounds__(256) void scan_combine_kernel(
    const float* __restrict__ P, const float* __restrict__ Hend, float* __restrict__ Hin)
{
  int r = blockIdx.x * 256 + threadIdx.x;
  float h = 0.f;
  #pragma unroll
  for (int c = 0; c < NC; c++) {
    Hin[(long)c * NR + r] = h;
    h = fmaf(P[(long)c * NR + r], h, Hend[(long)c * NR + r]);
  }
}

// ---------------------------------------------------------------- scan apply (8 states/thread)
__global__ __launch_bounds__(256) void scan_apply_kernel(
    const float* __restrict__ dtv, const float* __restrict__ xc, const float* __restrict__ xz,
    const float* __restrict__ bc, const float* __restrict__ Alog, const float* __restrict__ Dp,
    const float* __restrict__ Hin, float* __restrict__ ym, int layer)
{
  int chunk = blockIdx.x, dtile = blockIdx.y, gb = blockIdx.z;
  int g = gb / BB;
  int tid = threadIdx.x;
  int dl = tid >> 1, nh = (tid & 1) * 8;
  int d = dtile * 128 + dl;
  int t0 = chunk * TC;
  __shared__ float dtv_s[TC][128], xc_s[TC][128], BC_s[TC][32], y_s[TC][128];
  {
    long base = ((long)gb * SEQL + t0) * DD + dtile * 128;
    int c4 = (tid & 31) * 4, r0 = tid >> 5;
    #pragma unroll
    for (int i = 0; i < 4; i++) {
      int tl = r0 + i * 8;
      *(float4*)&dtv_s[tl][c4] = *(const float4*)(dtv + base + (long)tl * DD + c4);
      *(float4*)&xc_s[tl][c4]  = *(const float4*)(xc + base + (long)tl * DD + c4);
    }
    long dbase = ((long)gb * SEQL + t0) * 32;
    int cc = (tid & 7) * 4, rr = tid >> 3;
    *(float4*)&BC_s[rr][cc] = *(const float4*)(bc + dbase + (long)rr * 32 + cc);
  }
  __syncthreads();
  const float* Al = Alog + ((long)((layer * 2 + g) * DD) + d) * NN + nh;
  float a[8], h[8];
  #pragma unroll
  for (int n = 0; n < 8; n++) a[n] = -__expf(Al[n]);
  {
    long r = (long)chunk * NR + ((long)(gb * DD + d)) * NN + nh;
    float4 h0 = *(const float4*)(Hin + r);
    float4 h1 = *(const float4*)(Hin + r + 4);
    h[0]=h0.x; h[1]=h0.y; h[2]=h0.z; h[3]=h0.w;
    h[4]=h1.x; h[5]=h1.y; h[6]=h1.z; h[7]=h1.w;
  }
  for (int t = 0; t < TC; t++) {
    float dt = dtv_s[t][dl];
    float dx = dt * xc_s[t][dl];
    float4 b0 = *(const float4*)&BC_s[t][nh];
    float4 b1 = *(const float4*)&BC_s[t][nh + 4];
    float4 c0 = *(const float4*)&BC_s[t][16 + nh];
    float4 c1 = *(const float4*)&BC_s[t][16 + nh + 4];
    h[0] = fmaf(__expf(dt * a[0]), h[0], dx * b0.x);
    h[1] = fmaf(__expf(dt * a[1]), h[1], dx * b0.y);
    h[2] = fmaf(__expf(dt * a[2]), h[2], dx * b0.z);
    h[3] = fmaf(__expf(dt * a[3]), h[3], dx * b0.w);
    h[4] = fmaf(__expf(dt * a[4]), h[4], dx * b1.x);
    h[5] = fmaf(__expf(dt * a[5]), h[5], dx * b1.y);
    h[6] = fmaf(__expf(dt * a[6]), h[6], dx * b1.z);
    h[7] = fmaf(__expf(dt * a[7]), h[7], dx * b1.w);
    float v0 = h[0] * c0.x + h[1] * c0.y;
    float v1 = h[2] * c0.z + h[3] * c0.w;
    float v2 = h[4] * c1.x + h[5] * c1.y;
    float v3 = h[6] * c1.z + h[7] * c1.w;
    float val = (v0 + v1) + (v2 + v3);
    val += __shfl_xor(val, 1);
    if ((tid & 1) == 0) y_s[t][dl] = val;
  }
  __syncthreads();
  {
    long base = ((long)gb * SEQL + t0) * DD + dtile * 128;
    long zbase = ((long)gb * SEQL + t0) * 2 * DD + DD + dtile * 128;
    int c4 = (tid & 31) * 4, r0 = tid >> 5;
    float4 Dp4 = *(const float4*)(Dp + (long)(layer * 2 + g) * DD + dtile * 128 + c4);
    #pragma unroll
    for (int i = 0; i < 4; i++) {
      int tl = r0 + i * 8;
      float4 y4 = *(const float4*)&y_s[tl][c4];
      float4 x4 = *(const float4*)&xc_s[tl][c4];
      float4 z4 = *(const float4*)(xz + zbase + (long)tl * 2 * DD + c4);
      float4 o;
      o.x = (y4.x + Dp4.x * x4.x) * siluf(z4.x);
      o.y = (y4.y + Dp4.y * x4.y) * siluf(z4.y);
      o.z = (y4.z + Dp4.z * x4.z) * siluf(z4.z);
      o.w = (y4.w + Dp4.w * x4.w) * siluf(z4.w);
      *(float4*)(ym + base + (long)tl * DD + c4) = o;
    }
  }
}

// ---------------------------------------------------------------- dir combine
__global__ __launch_bounds__(256) void combine_kernel(
    const float* __restrict__ yp, const float* __restrict__ proj, float* __restrict__ yc)
{
  long idx = (long)blockIdx.x * 256 + threadIdx.x;  // (b,t,d)
  int d = idx % DD;
  long r = idx / DD;
  int t = r % SEQL;
  long b = r / SEQL;
  float y0 = yp[idx];
  float y1 = yp[(long)BB * SEQL * DD + (b * SEQL + (SEQL - 1 - t)) * (long)DD + d];
  const float* pr = proj + r * 3 * DD;
  float zf = pr[DD + d];
  float zr = pr[2 * DD + d];
  yc[idx] = y0 * siluf(zf) + y1 * siluf(zr);
}

// ---------------------------------------------------------------- bias index table
__global__ void tab_kernel(unsigned short* __restrict__ tab)
{
  int idx = blockIdx.x * blockDim.x + threadIdx.x;
  if (idx >= 2047) return;
  int di = idx - 1023;
  int ad = di < 0 ? -di : di;
  float pr = expf(logf((SEQL + 1) * 0.5f) / 16.0f);
  int n0 = 16;
  for (int n = 15; n >= 0; n--) {
    float cw = powf(pr, (float)(n + 1));
    if ((float)ad <= cw) n0 = n;
  }
  tab[idx] = (unsigned short)(di == 0 ? 34 : (di < 0 ? n0 : 17 + n0));
}

// ---------------------------------------------------------------- qw suffix (dense)
__global__ __launch_bounds__(256) void qw_kernel(
    const float* __restrict__ q, const float* __restrict__ w_rel, float* __restrict__ S, int layer)
{
  int itile = blockIdx.x;
  int bh = blockIdx.y;
  int h = bh % HH, b = bh / HH;
  int i0 = itile * 64;
  __shared__ float q_s[64][65];
  __shared__ float w_s[64][33];
  __shared__ float qwn[64][33];
  int tid = threadIdx.x;
  {
    int r = tid >> 2, c4 = (tid & 3) * 16;
    const float* qr = q + ((long)(b * SEQL + i0 + r)) * DD + h * 64 + c4;
    #pragma unroll
    for (int e = 0; e < 4; e++) {
      float4 v = *(const float4*)(qr + e * 4);
      q_s[r][c4 + e * 4 + 0] = v.x; q_s[r][c4 + e * 4 + 1] = v.y;
      q_s[r][c4 + e * 4 + 2] = v.z; q_s[r][c4 + e * 4 + 3] = v.w;
    }
  }
  for (int idx = tid; idx < 64 * 32; idx += 256) {
    int d = idx >> 5, n = idx & 31;
    w_s[d][n] = w_rel[((long)(layer * HH + h) * DHH + d) * PPB + n];
  }
  __syncthreads();
  {
    int i = tid & 63, ngrp = tid >> 6;
    float acc[8] = {};
    #pragma unroll 8
    for (int d = 0; d < 64; d++) {
      float qv = q_s[i][d];
      #pragma unroll
      for (int e = 0; e < 8; e++) acc[e] = fmaf(qv, w_s[d][ngrp * 8 + e], acc[e]);
    }
    #pragma unroll
    for (int e = 0; e < 8; e++) qwn[i][ngrp * 8 + e] = acc[e];
  }
  __syncthreads();
  for (int idx = tid; idx < 64 * 17; idx += 256) {
    int il = idx / 17, m = idx % 17;
    float s1 = 0.f, s2 = 0.f;
    for (int n = m; n < 16; n++) { s1 += qwn[il][n]; s2 += qwn[il][16 + n]; }
    float* Sp = S + ((long)bh * SEQL + i0 + il) * 34;
    Sp[m] = s1;
    Sp[17 + m] = s2;
  }
}

__global__ __launch_bounds__(256) void vw_kernel(
    const float* __restrict__ vparam, const float* __restrict__ w_rel, float* __restrict__ VS)
{
  int layer = blockIdx.x;
  __shared__ float vws[HH][PPB];
  int tid = threadIdx.x;
  int h = tid / PPB, n = tid % PPB;
  const float* vp = vparam + (long)(layer * HH + h) * DHH;
  const float* wp = w_rel + ((long)(layer * HH + h) * DHH) * PPB + n;
  float s = 0.f;
  for (int d = 0; d < DHH; d++) s = fmaf(vp[d], wp[d * PPB], s);
  vws[h][n] = s;
  __syncthreads();
  if (tid < HH * 17) {
    int hh = tid / 17, m = tid % 17;
    float s1 = 0.f, s2 = 0.f;
    for (int nn = m; nn < 16; nn++) { s1 += vws[hh][nn]; s2 += vws[hh][16 + nn]; }
    VS[layer * 272 + hh * 34 + m] = s1;
    VS[layer * 272 + hh * 34 + 17 + m] = s2;
  }
}

__global__ __launch_bounds__(256) void uk_kernel(
    const float* __restrict__ u, const float* __restrict__ k, float* __restrict__ uk, int layer)
{
  int wid = (blockIdx.x * 256 + threadIdx.x) >> 6;
  int lane = threadIdx.x & 63;
  if (wid >= BB * HH * SEQL) return;
  int j = wid % SEQL;
  int bh = wid / SEQL;
  int h = bh % HH;
  int b = bh / HH;
  float vv = u[(long)(layer * HH + h) * DHH + lane] * k[((long)(b * SEQL + j) * HH + h) * DHH + lane];
  for (int o = 32; o; o >>= 1) vv += __shfl_down(vv, o);
  if (lane == 0) uk[(long)bh * SEQL + j] = vv;
}

// ---------------------------------------------------------------- MFMA attention (split-KV)
__global__ __launch_bounds__(256) void attn_mfma_kernel(
    const float* __restrict__ q, const float* __restrict__ k, const float* __restrict__ vv,
    const float* __restrict__ S, const float* __restrict__ VS, const float* __restrict__ uk,
    const unsigned short* __restrict__ tab,
    float* __restrict__ opart, float* __restrict__ mbuf, float* __restrict__ lbuf)
{
  __shared__ __align__(16) char smem[39680];
  unsigned short* K_lds  = (unsigned short*)(smem);
  unsigned short* VT_lds = (unsigned short*)(smem + 8704);
  unsigned short* PT_lds = (unsigned short*)(smem + 17408);
  float* E               = (float*)(smem + 26112);
  unsigned short* tab_s  = (unsigned short*)(smem + 35328);
  float* uk_s            = (float*)(smem + 39424);
  float* O_lds           = (float*)(smem);

  int itile = blockIdx.x;
  int bh = blockIdx.y;
  int split = blockIdx.z;
  int h = bh % HH, b = bh / HH;
  int i0 = itile * 64;
  int tid = threadIdx.x;
  int w = tid >> 6;
  int lane = tid & 63;
  int li = lane & 15, lg = lane >> 4;

  for (int idx = tid; idx < 64 * 17; idx += 256) {
    int il = idx / 17, m = idx % 17;
    long srow = ((long)bh * SEQL + i0 + il) * 34;
    float c0 = S[srow + m]      + VS[h * 34 + m];
    float c1 = S[srow + 17 + m] + VS[h * 34 + 17 + m];
    E[il * 36 + m]      = c0 - c1;
    E[il * 36 + 17 + m] = c0 + c1;
    if (m == 0) E[il * 36 + 34] = c0;
  }
  for (int idx = tid; idx < 2047; idx += 256) tab_s[idx] = tab[idx];

  int iq = i0 + w * 16 + li;
  const float* qrow = q + ((long)(b * SEQL + iq)) * DD + h * 64;
  bf16x8 qf0 = pack8(qrow + 8 * lg);
  bf16x8 qf1 = pack8(qrow + 32 + 8 * lg);

  f32x4 oacc[4] = {};
  float mrun = -1e30f, lrun = 0.f;
  const int ibase = i0 + w * 16 + li;
  unsigned short* PTw = PT_lds + w * 16 * 68;
  const float* Erow = E + (w * 16 + li) * 36;

  const int jbase = split * (SEQL / 2);
  for (int jt = 0; jt < SEQL / 2; jt += 64) {
    int j0 = jbase + jt;
    __syncthreads();
    {
      int jl = tid >> 4;
      int dq = (tid & 15) * 4;
      #pragma unroll
      for (int rr = 0; rr < 4; rr++) {
        int jj = jl + rr * 16;
        long grow = ((long)(b * SEQL + j0 + jj)) * DD + h * 64 + dq;
        float4 kv = *(const float4*)(k + grow);
        short4v kp = { (short)f2bf(kv.x), (short)f2bf(kv.y), (short)f2bf(kv.z), (short)f2bf(kv.w) };
        *(short4v*)(K_lds + jj * 68 + dq) = kp;
        float4 vvv = *(const float4*)(vv + grow);
        VT_lds[(dq + 0) * 68 + jj] = f2bf(vvv.x);
        VT_lds[(dq + 1) * 68 + jj] = f2bf(vvv.y);
        VT_lds[(dq + 2) * 68 + jj] = f2bf(vvv.z);
        VT_lds[(dq + 3) * 68 + jj] = f2bf(vvv.w);
      }
      if (tid < 64) uk_s[tid] = uk[(long)bh * SEQL + j0 + tid];
    }
    __syncthreads();

    f32x4 sf[4];
    #pragma unroll
    for (int jj = 0; jj < 4; jj++) {
      f32x4 c = {};
      c = __builtin_amdgcn_mfma_f32_16x16x32_bf16(
            ld_frag(K_lds + (jj * 16 + li) * 68 + 8 * lg), qf0, c, 0, 0, 0);
      c = __builtin_amdgcn_mfma_f32_16x16x32_bf16(
            ld_frag(K_lds + (jj * 16 + li) * 68 + 32 + 8 * lg), qf1, c, 0, 0, 0);
      sf[jj] = c;
    }

    float sv[4][4];
    float tmax = -1e30f;
    #pragma unroll
    for (int jj = 0; jj < 4; jj++) {
      #pragma unroll
      for (int r = 0; r < 4; r++) {
        int jloc = jj * 16 + 4 * lg + r;
        int di = (j0 + jloc) - ibase;
        int id = tab_s[1023 + di];
        float val = (sf[jj][r] + Erow[id] + uk_s[jloc]) * 0.125f;
        sv[jj][r] = val;
        tmax = fmaxf(tmax, val);
      }
    }
    tmax = fmaxf(tmax, __shfl_xor(tmax, 16));
    tmax = fmaxf(tmax, __shfl_xor(tmax, 32));
    float mnew = fmaxf(mrun, tmax);
    float fsc = __expf(mrun - mnew);
    mrun = mnew;
    lrun *= fsc;
    #pragma unroll
    for (int df = 0; df < 4; df++) oacc[df] *= fsc;

    float psum = 0.f;
    #pragma unroll
    for (int jj = 0; jj < 4; jj++) {
      short4v pk;
      #pragma unroll
      for (int r = 0; r < 4; r++) {
        float p = __expf(sv[jj][r] - mnew);
        psum += p;
        pk[r] = (short)f2bf(p);
      }
      *(short4v*)(PTw + li * 68 + jj * 16 + 4 * lg) = pk;
    }
    psum += __shfl_xor(psum, 16);
    psum += __shfl_xor(psum, 32);
    lrun += psum;

    asm volatile("s_waitcnt lgkmcnt(0)" ::: "memory");

    bf16x8 pf0 = ld_frag(PTw + li * 68 + 8 * lg);
    bf16x8 pf1 = ld_frag(PTw + li * 68 + 32 + 8 * lg);
    #pragma unroll
    for (int df = 0; df < 4; df++) {
      f32x4 c = oacc[df];
      c = __builtin_amdgcn_mfma_f32_16x16x32_bf16(
            ld_frag(VT_lds + (df * 16 + li) * 68 + 8 * lg), pf0, c, 0, 0, 0);
      c = __builtin_amdgcn_mfma_f32_16x16x32_bf16(
            ld_frag(VT_lds + (df * 16 + li) * 68 + 32 + 8 * lg), pf1, c, 0, 0, 0);
      oacc[df] = c;
    }
  }

  __syncthreads();
  if (lg == 0) {
    long row = (long)split * BHN + (long)bh * SEQL + (i0 + w * 16 + li);
    mbuf[row] = mrun;
    lbuf[row] = lrun;
  }
  #pragma unroll
  for (int df = 0; df < 4; df++)
    *(f32x4*)(O_lds + (w * 16 + li) * 68 + df * 16 + 4 * lg) = oacc[df];
  __syncthreads();
  {
    int il = tid >> 2, c0 = (tid & 3) * 16;
    long orow = ((long)split * BHN + (long)bh * SEQL + i0 + il) * 64 + c0;
    #pragma unroll
    for (int c4 = 0; c4 < 4; c4++) {
      f32x4 o = *(const f32x4*)(O_lds + il * 68 + c0 + c4 * 4);
      *(f32x4*)(opart + orow + c4 * 4) = o;
    }
  }
}

// ---------------------------------------------------------------- attention split combine
__global__ __launch_bounds__(256) void attn_combine_kernel(
    const float* __restrict__ opart, const float* __restrict__ mbuf,
    const float* __restrict__ lbuf, float* __restrict__ out)
{
  int idx = blockIdx.x * 256 + threadIdx.x;   // BHN*64 = 1,048,576
  int row = idx >> 6, d = idx & 63;
  int bh = row >> 10, i = row & 1023;
  int b = bh >> 3, h = bh & 7;
  float m0 = mbuf[row], m1 = mbuf[BHN + row];
  float l0 = lbuf[row], l1 = lbuf[BHN + row];
  float m = fmaxf(m0, m1);
  float e0 = __expf(m0 - m), e1 = __expf(m1 - m);
  float inv = 1.f / (l0 * e0 + l1 * e1);
  float o = (opart[(long)row * 64 + d] * e0 + opart[((long)BHN + row) * 64 + d] * e1) * inv;
  out[((long)(b * SEQL + i)) * DD + h * 64 + d] = o;
}

// ---------------------------------------------------------------- launch
extern "C" void kernel_launch(void* const* d_in, const int* in_sizes, int n_in,
                              void* d_out, int out_size, void* d_ws, size_t ws_size,
                              hipStream_t stream) {
  const float* x_in     = (const float*)d_in[0];
  const float* rms_m    = (const float*)d_in[1];
  const float* W_in     = (const float*)d_in[2];
  const float* b_in     = (const float*)d_in[3];
  const float* m_Win    = (const float*)d_in[4];
  const float* m_conv_w = (const float*)d_in[5];
  const float* m_conv_b = (const float*)d_in[6];
  const float* m_Wx     = (const float*)d_in[7];
  const float* m_Wdt    = (const float*)d_in[8];
  const float* m_bdt    = (const float*)d_in[9];
  const float* m_Alog   = (const float*)d_in[10];
  const float* m_Dp     = (const float*)d_in[11];
  const float* m_Wout   = (const float*)d_in[12];
  const float* W_out    = (const float*)d_in[13];
  const float* b_out    = (const float*)d_in[14];
  const float* rms_a    = (const float*)d_in[15];
  const float* Wq       = (const float*)d_in[16];
  const float* Wk       = (const float*)d_in[17];
  const float* Wv       = (const float*)d_in[18];
  const float* u_p      = (const float*)d_in[19];
  const float* v_p      = (const float*)d_in[20];
  const float* w_rel    = (const float*)d_in[21];
  const float* Wo       = (const float*)d_in[22];
  const float* b_o      = (const float*)d_in[23];
  float* out = (float*)d_out;

  float* ws = (float*)d_ws;
  const long U = (long)BB * SEQL * DD;      // 1,048,576 floats
  float* xA    = ws;
  float* xB    = ws + 1 * U;                // also scan Hend scratch (dead during scan)
  float* xn    = ws + 2 * U;                // scan P scratch
  float* proj  = ws + 3 * U;                // 3U; later q,k,v
  float* xz    = ws + 6 * U;                // 4U; later yp (2U)
  float* xc    = ws + 10 * U;               // 2U; attn Opart scratch
  float* dtv   = ws + 12 * U;               // 2U; attn m/l scratch
  float* ym    = ws + 14 * U;               // 2U; later attnout
  float* ycomb = ws + 16 * U;               // 1U; also scan Hin scratch
  float* smallb= ws + 17 * U;               // 1U of small buffers
  float* bcbuf = smallb;                    // 131072
  float* ukbuf = smallb + 262144;           // 16384
  float* Sbuf  = smallb + 278528;           // 557056
  float* VSbuf = smallb + 835584;           // 2*272
  unsigned short* tabg = (unsigned short*)(smallb + 836880);  // 2047 u16
  float* invm  = smallb + 838928;           // 2048
  float* inva  = smallb + 840976;           // 2048
  unsigned short* WTA = (unsigned short*)(ws + 18 * U);       // 2 * AR_L shorts
  float* yp = xz;
  float* qb = proj;
  float* kb = proj + U;
  float* vb = proj + 2 * U;
  float* attnout = ym;
  float* Pbuf = xn;                         // NC*NR = 1U
  float* Hend = xB;                         // NC*NR = 1U (xB dead during scan)
  float* Hin  = ycomb;                      // NC*NR = 1U
  float* opart = xc;                        // 2*BHN*64 = 2U
  float* mbuf  = dtv;                       // 2*BHN
  float* lbuf  = dtv + 2 * BHN;             // 2*BHN

  const int M = BB * SEQL;                  // 2048

  // ---- preamble: bias table + all weight preprocessing ----
  tab_kernel<<<8, 256, 0, stream>>>(tabg);

  TDs td;
  int cum = 0, idx = 0;
  auto add = [&](const float* s, unsigned short* dst, int ldsrc, int K, int N) {
    td.a[idx].src = s; td.a[idx].dst = dst; td.a[idx].ldsrc = ldsrc;
    td.a[idx].K = K; td.a[idx].N = N; td.a[idx].t0 = cum;
    cum += (N / 32) * (K / 32); idx++;
  };
  for (int l = 0; l < LL; l++) {
    unsigned short* base = WTA + (long)l * AR_L;
    add(W_in   + (long)l * DD * 3 * DD,        base + OFF_WIN,            3 * DD, DD, 3 * DD);
    add(m_Win  + (long)(l * 2 + 0) * DD * 2 * DD, base + OFF_MWIN,          2 * DD, DD, 2 * DD);
    add(m_Win  + (long)(l * 2 + 1) * DD * 2 * DD, base + OFF_MWIN + 524288, 2 * DD, DD, 2 * DD);
    add(m_Wout + (long)(l * 2 + 0) * DD * DD,  base + OFF_MWOUT,          DD, DD, DD);
    add(m_Wout + (long)(l * 2 + 1) * DD * DD,  base + OFF_MWOUT + 262144, DD, DD, DD);
    add(W_out  + (long)l * DD * DD,            base + OFF_WOUT,           DD, DD, DD);
    add(Wq     + (long)l * DD * DD,            base + OFF_QKV,            DD, DD, DD);
    add(Wk     + (long)l * DD * DD,            base + OFF_QKV + 262144,   DD, DD, DD);
    add(Wv     + (long)l * DD * DD,            base + OFF_QKV + 524288,   DD, DD, DD);
    add(Wo     + (long)l * DD * DD,            base + OFF_WO,             DD, DD, DD);
    add(m_Wx   + (long)(l * 2 + 0) * DD * 64 + 32, base + OFF_WT2 + 262144,          64, DD, 32);
    add(m_Wx   + (long)(l * 2 + 1) * DD * 64 + 32, base + OFF_WT2 + 327680 + 262144, 64, DD, 32);
  }
  wtrans_all<<<cum, 256, 0, stream>>>(td);
  weff_kernel<<<dim3(16, 16, 2 * LL), 256, 0, stream>>>(m_Wx, m_Wdt, WTA);
  vw_kernel<<<LL, 256, 0, stream>>>(v_p, w_rel, VSbuf);

  for (int layer = 0; layer < LL; layer++) {
    const float* cur = (layer == 0) ? x_in : xA;
    unsigned short* base = WTA + (long)layer * AR_L;
    // ---- mamba block ----
    rmsinv_kernel<<<M / 4, 256, 0, stream>>>(cur, invm);
    gemm_bf16_t<64, 64><<<dim3(24, 32, 1), 256, 0, stream>>>(cur, base + OFF_WIN,
        b_in + layer * 3 * DD, nullptr, invm, rms_m + layer * DD, proj,
        M, 3 * DD, DD, DD, 3 * DD, 0, 0, 0, 0, 0, 0);
    gemm_bf16_t<64, 64><<<dim3(16, 32, 2), 256, 0, stream>>>(proj, base + OFF_MWIN,
        nullptr, nullptr, nullptr, nullptr, xz, M, 2 * DD, DD, 3 * DD, 2 * DD,
        0, 524288, 0, (long)BB * SEQL * 2 * DD, SEQL, 0);
    conv_silu_kernel<<<(2 * BB * SEQL * DD) / 256, 256, 0, stream>>>(xz, m_conv_w, m_conv_b, xc, layer);
    gemm_dtbc<<<dim3(9, 32, 2), 256, 0, stream>>>(xc, base + OFF_WT2, m_bdt, dtv, bcbuf, layer);
    scan_chunk_kernel<<<dim3(NC, DD / 128, GBS), 256, 0, stream>>>(
        dtv, xc, bcbuf, m_Alog, Pbuf, Hend, layer);
    scan_combine_kernel<<<NR / 256, 256, 0, stream>>>(Pbuf, Hend, Hin);
    scan_apply_kernel<<<dim3(NC, DD / 128, GBS), 256, 0, stream>>>(
        dtv, xc, xz, bcbuf, m_Alog, m_Dp, Hin, ym, layer);
    gemm_bf16_t<64, 64><<<dim3(8, 32, 2), 256, 0, stream>>>(ym, base + OFF_MWOUT,
        nullptr, nullptr, nullptr, nullptr, yp, M, DD, DD, DD, DD,
        U, 262144, 0, U, 0, 0);
    combine_kernel<<<(int)(U / 256), 256, 0, stream>>>(yp, proj, ycomb);
    gemm_bf16_t<64, 64><<<dim3(8, 32, 1), 256, 0, stream>>>(ycomb, base + OFF_WOUT,
        b_out + layer * DD, cur, nullptr, nullptr, xB, M, DD, DD, DD, DD, 0, 0, 0, 0, 0, 0);

    // ---- attention block ----
    rmsinv_kernel<<<M / 4, 256, 0, stream>>>(xB, inva);
    gemm_bf16_t<64, 64><<<dim3(8, 32, 3), 256, 0, stream>>>(xB, base + OFF_QKV,
        nullptr, nullptr, inva, rms_a + layer * DD, qb, M, DD, DD, DD, DD,
        0, 262144, 0, U, 0, 0);
    qw_kernel<<<dim3(16, 16), 256, 0, stream>>>(qb, w_rel, Sbuf, layer);
    uk_kernel<<<(BB * HH * SEQL) / 4, 256, 0, stream>>>(u_p, kb, ukbuf, layer);
    attn_mfma_kernel<<<dim3(SEQL / 64, BB * HH, 2), 256, 0, stream>>>(
        qb, kb, vb, Sbuf, VSbuf + layer * 272, ukbuf, tabg, opart, mbuf, lbuf);
    attn_combine_kernel<<<(BHN * 64) / 256, 256, 0, stream>>>(opart, mbuf, lbuf, attnout);

    float* outp = (layer == LL - 1) ? out : xA;
    gemm_bf16_t<64, 64><<<dim3(8, 32, 1), 256, 0, stream>>>(attnout, base + OFF_WO,
        b_o + layer * DD, xB, nullptr, nullptr, outp, M, DD, DD, DD, DD, 0, 0, 0, 0, 0, 0);
  }
}

// Round 10
// 553.815 us; speedup vs baseline: 8.7867x; 1.0399x over previous
//
#include <hip/hip_runtime.h>

#define LL 2
#define BB 2
#define SEQL 1024
#define DD 512
#define NN 16
#define HH 8
#define DHH 64
#define PPB 32
#define KCC 4
#define DTRR 32

#define GBS 4              // g*BB+b combinations
#define TC 32              // scan chunk length
#define NC (SEQL / TC)     // 32 chunks
#define NR (GBS * DD * NN) // 32768 recurrences
#define BHN (BB * HH * SEQL) // 16384 attention rows

// weight arena (shorts), per layer
#define AR_L     4325376L
#define OFF_WIN  0L
#define OFF_MWIN 786432L
#define OFF_WT2  1835008L
#define OFF_MWOUT 2490368L
#define OFF_WOUT 3014656L
#define OFF_QKV  3276800L
#define OFF_WO   4063232L

typedef __attribute__((ext_vector_type(8))) short bf16x8;
typedef __attribute__((ext_vector_type(4))) short short4v;
typedef __attribute__((ext_vector_type(4))) float f32x4;

__device__ __forceinline__ float siluf(float x) { return x / (1.f + __expf(-x)); }
__device__ __forceinline__ float softplusf(float x) { return x > 20.f ? x : log1pf(__expf(x)); }

__device__ __forceinline__ unsigned short f2bf(float x) {
  union { float f; unsigned u; } v; v.f = x;
  unsigned r = v.u + 0x7fff + ((v.u >> 16) & 1);
  return (unsigned short)(r >> 16);
}

__device__ __forceinline__ bf16x8 ld_frag(const unsigned short* p) {
  short4v a = *(const short4v*)(p);
  short4v b = *(const short4v*)(p + 4);
  bf16x8 r;
  r[0]=a[0]; r[1]=a[1]; r[2]=a[2]; r[3]=a[3];
  r[4]=b[0]; r[5]=b[1]; r[6]=b[2]; r[7]=b[3];
  return r;
}

__device__ __forceinline__ bf16x8 pack8(const float* p) {
  bf16x8 r;
  #pragma unroll
  for (int e = 0; e < 8; e++) r[e] = (short)f2bf(p[e]);
  return r;
}

// ---------------------------------------------------------------- batched weight transpose
struct TD { const float* src; unsigned short* dst; int ldsrc; int K; int N; int t0; };
struct TDs { TD a[24]; };

__global__ __launch_bounds__(256) void wtrans_all(TDs ds)
{
  int bid = blockIdx.x;
  int mi = 0;
  #pragma unroll 1
  for (int i = 1; i < 24; i++) if (bid >= ds.a[i].t0) mi = i;
  TD d = ds.a[mi];
  int local = bid - d.t0;
  int tilesN = d.N >> 5;
  int tn = local % tilesN, tk = local / tilesN;
  __shared__ float t[32][33];
  int tx = threadIdx.x & 31, ty = threadIdx.x >> 5;
  int n0 = tn * 32, k0 = tk * 32;
  #pragma unroll
  for (int i = 0; i < 4; i++)
    t[ty + 8 * i][tx] = d.src[(long)(k0 + ty + 8 * i) * d.ldsrc + n0 + tx];
  __syncthreads();
  #pragma unroll
  for (int i = 0; i < 4; i++)
    d.dst[(long)(n0 + ty + 8 * i) * d.K + k0 + tx] = f2bf(t[tx][ty + 8 * i]);
}

// ---------------------------------------------------------------- Weff = Wx[:, :32] @ Wdt
__global__ __launch_bounds__(256) void weff_kernel(
    const float* __restrict__ Wx, const float* __restrict__ Wdt,
    unsigned short* __restrict__ WTA)
{
  int lg = blockIdx.z;
  int l = lg >> 1, g = lg & 1;
  const float* wx = Wx + (long)(l * 2 + g) * DD * 64;
  const float* wd = Wdt + (long)(l * 2 + g) * DTRR * DD;
  unsigned short* wt = WTA + (long)l * AR_L + OFF_WT2 + (long)g * 327680;
  int n0 = blockIdx.x * 32, k0 = blockIdx.y * 32;
  __shared__ float wx_s[32][33];
  __shared__ float wd_s[32][33];
  int tx = threadIdx.x & 31, ty = threadIdx.x >> 5;
  #pragma unroll
  for (int i = 0; i < 4; i++) {
    wx_s[ty + 8 * i][tx] = wx[(long)(k0 + ty + 8 * i) * 64 + tx];
    wd_s[ty + 8 * i][tx] = wd[(long)(ty + 8 * i) * DD + n0 + tx];
  }
  __syncthreads();
  #pragma unroll
  for (int i = 0; i < 4; i++) {
    int nl = ty + 8 * i;
    float s = 0.f;
    #pragma unroll
    for (int r = 0; r < 32; r++) s = fmaf(wx_s[tx][r], wd_s[r][nl], s);
    wt[(long)(n0 + nl) * DD + k0 + tx] = f2bf(s);
  }
}

// ---------------------------------------------------------------- RMS inverse-norm (per row)
__global__ __launch_bounds__(256) void rmsinv_kernel(
    const float* __restrict__ x, float* __restrict__ inv)
{
  int row = blockIdx.x * 4 + (threadIdx.x >> 6);
  int lane = threadIdx.x & 63;
  const float* xr = x + (long)row * DD;
  float4 a = *(const float4*)(xr + lane * 4);
  float4 b = *(const float4*)(xr + 256 + lane * 4);
  float s = a.x*a.x + a.y*a.y + a.z*a.z + a.w*a.w + b.x*b.x + b.y*b.y + b.z*b.z + b.w*b.w;
  for (int o = 32; o; o >>= 1) s += __shfl_down(s, o);
  if (lane == 0) inv[row] = rsqrtf(s / (float)DD + 1e-6f);
}

// ---------------------------------------------------------------- GEMM (bf16 MFMA, tiled)
template<int BM, int BN>
__global__ __launch_bounds__(256) void gemm_bf16_t(
    const float* __restrict__ A, const unsigned short* __restrict__ WT,
    const float* __restrict__ bias, const float* __restrict__ resid,
    const float* __restrict__ invrow, const float* __restrict__ colw,
    float* __restrict__ C,
    int M, int N, int K, int lda, int ldc,
    long aBatch, long wBatch, long biasBatch, long cBatch,
    int aflipL, int act)
{
  constexpr int FM = BM / 32;
  constexpr int FN = BN / 32;
  int g = blockIdx.z;
  A  += (long)g * aBatch;
  WT += (long)g * wBatch;
  C  += (long)g * cBatch;
  if (bias) bias += (long)g * biasBatch;
  const bool flip = (aflipL > 0) && (g == 1);

  __shared__ unsigned short A_lds[BM][72];
  __shared__ unsigned short B_lds[BN][72];
  int tid = threadIdx.x;
  int w = tid >> 6, lane = tid & 63, li = lane & 15, lg = lane >> 4;
  int bm = blockIdx.y * BM, bn = blockIdx.x * BN;
  int wm = (w & 1) * (BM / 2), wn = (w >> 1) * (BN / 2);
  f32x4 acc[FM][FN] = {};

  const int kqA = (tid & 15) * 4, r0A = tid >> 4;
  const int kqB = (tid & 7) * 8,  r0B = tid >> 3;

  for (int k0 = 0; k0 < K; k0 += 64) {
    __syncthreads();
    float4 cw4 = {1.f, 1.f, 1.f, 1.f};
    if (colw) cw4 = *(const float4*)(colw + k0 + kqA);
    #pragma unroll
    for (int i = 0; i < BM / 16; i++) {
      int m = bm + r0A + 16 * i;
      int mm = m;
      if (flip) { int bb = m / aflipL; int t = m - bb * aflipL; mm = bb * aflipL + (aflipL - 1 - t); }
      float4 av = *(const float4*)(A + (long)mm * lda + k0 + kqA);
      float sc = invrow ? invrow[mm] : 1.f;
      short4v ap = { (short)f2bf(av.x * sc * cw4.x), (short)f2bf(av.y * sc * cw4.y),
                     (short)f2bf(av.z * sc * cw4.z), (short)f2bf(av.w * sc * cw4.w) };
      *(short4v*)(&A_lds[r0A + 16 * i][kqA]) = ap;
    }
    #pragma unroll
    for (int i = 0; i < BN / 32; i++) {
      int n = bn + r0B + 32 * i;
      bf16x8 bv = *(const bf16x8*)(WT + (long)n * K + k0 + kqB);
      *(bf16x8*)(&B_lds[r0B + 32 * i][kqB]) = bv;
    }
    __syncthreads();
    #pragma unroll
    for (int ks = 0; ks < 2; ks++) {
      bf16x8 af[FM], bfr[FN];
      #pragma unroll
      for (int fm = 0; fm < FM; fm++)
        af[fm] = *(const bf16x8*)(&A_lds[wm + fm * 16 + li][ks * 32 + lg * 8]);
      #pragma unroll
      for (int fn = 0; fn < FN; fn++)
        bfr[fn] = *(const bf16x8*)(&B_lds[wn + fn * 16 + li][ks * 32 + lg * 8]);
      #pragma unroll
      for (int fm = 0; fm < FM; fm++)
        #pragma unroll
        for (int fn = 0; fn < FN; fn++)
          acc[fm][fn] = __builtin_amdgcn_mfma_f32_16x16x32_bf16(af[fm], bfr[fn], acc[fm][fn], 0, 0, 0);
    }
  }
  #pragma unroll
  for (int fm = 0; fm < FM; fm++) {
    #pragma unroll
    for (int fn = 0; fn < FN; fn++) {
      int n = bn + wn + fn * 16 + li;
      float bv = bias ? bias[n] : 0.f;
      #pragma unroll
      for (int r = 0; r < 4; r++) {
        int m = bm + wm + fm * 16 + 4 * lg + r;
        float v = acc[fm][fn][r] + bv;
        if (act == 1) v = softplusf(v);
        if (resid) v += resid[(long)m * ldc + n];
        C[(long)m * ldc + n] = v;
      }
    }
  }
}

// ---------------------------------------------------------------- GEMM with fused dir-combine A
// A[m][k] = yp[m][k]*silu(proj[m][DD+k]) + yp[U + flip(m)][k]*silu(proj[m][2DD+k])
__global__ __launch_bounds__(256) void gemm_comb(
    const float* __restrict__ yp, const float* __restrict__ proj,
    const unsigned short* __restrict__ WT,
    const float* __restrict__ bias, const float* __restrict__ resid,
    float* __restrict__ C)
{
  __shared__ unsigned short A_lds[64][72];
  __shared__ unsigned short B_lds[64][72];
  int tid = threadIdx.x;
  int w = tid >> 6, lane = tid & 63, li = lane & 15, lg = lane >> 4;
  int bm = blockIdx.y * 64, bn = blockIdx.x * 64;
  int wm = (w & 1) * 32, wn = (w >> 1) * 32;
  f32x4 acc[2][2] = {};
  const long U = (long)BB * SEQL * DD;

  const int kqA = (tid & 15) * 4, r0A = tid >> 4;
  const int kqB = (tid & 7) * 8,  r0B = tid >> 3;

  for (int k0 = 0; k0 < DD; k0 += 64) {
    __syncthreads();
    #pragma unroll
    for (int i = 0; i < 4; i++) {
      int m = bm + r0A + 16 * i;
      int t = m & (SEQL - 1), b = m >> 10;
      int mf = (b << 10) + (SEQL - 1 - t);
      float4 y0 = *(const float4*)(yp + (long)m * DD + k0 + kqA);
      float4 y1 = *(const float4*)(yp + U + (long)mf * DD + k0 + kqA);
      float4 zf = *(const float4*)(proj + (long)m * 3 * DD + DD + k0 + kqA);
      float4 zr = *(const float4*)(proj + (long)m * 3 * DD + 2 * DD + k0 + kqA);
      float4 v;
      v.x = y0.x * siluf(zf.x) + y1.x * siluf(zr.x);
      v.y = y0.y * siluf(zf.y) + y1.y * siluf(zr.y);
      v.z = y0.z * siluf(zf.z) + y1.z * siluf(zr.z);
      v.w = y0.w * siluf(zf.w) + y1.w * siluf(zr.w);
      short4v ap = { (short)f2bf(v.x), (short)f2bf(v.y), (short)f2bf(v.z), (short)f2bf(v.w) };
      *(short4v*)(&A_lds[r0A + 16 * i][kqA]) = ap;
    }
    #pragma unroll
    for (int i = 0; i < 2; i++) {
      int n = bn + r0B + 32 * i;
      bf16x8 bv = *(const bf16x8*)(WT + (long)n * DD + k0 + kqB);
      *(bf16x8*)(&B_lds[r0B + 32 * i][kqB]) = bv;
    }
    __syncthreads();
    #pragma unroll
    for (int ks = 0; ks < 2; ks++) {
      bf16x8 af[2], bfr[2];
      #pragma unroll
      for (int fm = 0; fm < 2; fm++)
        af[fm] = *(const bf16x8*)(&A_lds[wm + fm * 16 + li][ks * 32 + lg * 8]);
      #pragma unroll
      for (int fn = 0; fn < 2; fn++)
        bfr[fn] = *(const bf16x8*)(&B_lds[wn + fn * 16 + li][ks * 32 + lg * 8]);
      #pragma unroll
      for (int fm = 0; fm < 2; fm++)
        #pragma unroll
        for (int fn = 0; fn < 2; fn++)
          acc[fm][fn] = __builtin_amdgcn_mfma_f32_16x16x32_bf16(af[fm], bfr[fn], acc[fm][fn], 0, 0, 0);
    }
  }
  #pragma unroll
  for (int fm = 0; fm < 2; fm++) {
    #pragma unroll
    for (int fn = 0; fn < 2; fn++) {
      int n = bn + wn + fn * 16 + li;
      float bv = bias[n];
      #pragma unroll
      for (int r = 0; r < 4; r++) {
        int m = bm + wm + fm * 16 + 4 * lg + r;
        C[(long)m * DD + n] = acc[fm][fn][r] + bv + resid[(long)m * DD + n];
      }
    }
  }
}

// ---------------------------------------------------------------- GEMM with fused attn-combine A
// A[m][k]: h=k>>6, d=k&63, row=(b*8+h)*1024+i; combine opart splits.
__global__ __launch_bounds__(256) void gemm_attn(
    const float* __restrict__ opart, const float* __restrict__ mbuf, const float* __restrict__ lbuf,
    const unsigned short* __restrict__ WT,
    const float* __restrict__ bias, const float* __restrict__ resid,
    float* __restrict__ C)
{
  __shared__ unsigned short A_lds[64][72];
  __shared__ unsigned short B_lds[64][72];
  int tid = threadIdx.x;
  int w = tid >> 6, lane = tid & 63, li = lane & 15, lg = lane >> 4;
  int bm = blockIdx.y * 64, bn = blockIdx.x * 64;
  int wm = (w & 1) * 32, wn = (w >> 1) * 32;
  f32x4 acc[2][2] = {};

  const int kqA = (tid & 15) * 4, r0A = tid >> 4;
  const int kqB = (tid & 7) * 8,  r0B = tid >> 3;

  for (int k0 = 0; k0 < DD; k0 += 64) {
    __syncthreads();
    int h = k0 >> 6;
    #pragma unroll
    for (int i = 0; i < 4; i++) {
      int m = bm + r0A + 16 * i;
      int iseq = m & (SEQL - 1), b = m >> 10;
      long row = ((long)(b * HH + h) << 10) + iseq;
      float m0 = mbuf[row], m1 = mbuf[BHN + row];
      float l0 = lbuf[row], l1 = lbuf[BHN + row];
      float mm = fmaxf(m0, m1);
      float e0 = __expf(m0 - mm), e1 = __expf(m1 - mm);
      float inv = 1.f / (l0 * e0 + l1 * e1);
      e0 *= inv; e1 *= inv;
      float4 o0 = *(const float4*)(opart + row * 64 + kqA);
      float4 o1 = *(const float4*)(opart + ((long)BHN + row) * 64 + kqA);
      float4 v;
      v.x = o0.x * e0 + o1.x * e1;
      v.y = o0.y * e0 + o1.y * e1;
      v.z = o0.z * e0 + o1.z * e1;
      v.w = o0.w * e0 + o1.w * e1;
      short4v ap = { (short)f2bf(v.x), (short)f2bf(v.y), (short)f2bf(v.z), (short)f2bf(v.w) };
      *(short4v*)(&A_lds[r0A + 16 * i][kqA]) = ap;
    }
    #pragma unroll
    for (int i = 0; i < 2; i++) {
      int n = bn + r0B + 32 * i;
      bf16x8 bv = *(const bf16x8*)(WT + (long)n * DD + k0 + kqB);
      *(bf16x8*)(&B_lds[r0B + 32 * i][kqB]) = bv;
    }
    __syncthreads();
    #pragma unroll
    for (int ks = 0; ks < 2; ks++) {
      bf16x8 af[2], bfr[2];
      #pragma unroll
      for (int fm = 0; fm < 2; fm++)
        af[fm] = *(const bf16x8*)(&A_lds[wm + fm * 16 + li][ks * 32 + lg * 8]);
      #pragma unroll
      for (int fn = 0; fn < 2; fn++)
        bfr[fn] = *(const bf16x8*)(&B_lds[wn + fn * 16 + li][ks * 32 + lg * 8]);
      #pragma unroll
      for (int fm = 0; fm < 2; fm++)
        #pragma unroll
        for (int fn = 0; fn < 2; fn++)
          acc[fm][fn] = __builtin_amdgcn_mfma_f32_16x16x32_bf16(af[fm], bfr[fn], acc[fm][fn], 0, 0, 0);
    }
  }
  #pragma unroll
  for (int fm = 0; fm < 2; fm++) {
    #pragma unroll
    for (int fn = 0; fn < 2; fn++) {
      int n = bn + wn + fn * 16 + li;
      float bv = bias[n];
      #pragma unroll
      for (int r = 0; r < 4; r++) {
        int m = bm + wm + fm * 16 + 4 * lg + r;
        C[(long)m * DD + n] = acc[fm][fn][r] + bv + resid[(long)m * DD + n];
      }
    }
  }
}

// ---------------------------------------------------------------- fused dt/B/C GEMM (64x64 tile)
__global__ __launch_bounds__(256) void gemm_dtbc(
    const float* __restrict__ A, const unsigned short* __restrict__ WT2,
    const float* __restrict__ bdt, float* __restrict__ dtv, float* __restrict__ bc,
    int layer)
{
  int g = blockIdx.z;
  A   += (long)g * BB * SEQL * DD;
  WT2 += (long)g * 640 * DD;
  dtv += (long)g * BB * SEQL * DD;
  bc  += (long)g * BB * SEQL * 32;
  bdt += (long)(layer * 2 + g) * DD;

  __shared__ unsigned short A_lds[64][72];
  __shared__ unsigned short B_lds[64][72];
  int tid = threadIdx.x;
  int w = tid >> 6, lane = tid & 63, li = lane & 15, lg = lane >> 4;
  int bm = blockIdx.y * 64, bn = blockIdx.x * 64;
  int wm = (w & 1) * 32, wn = (w >> 1) * 32;
  f32x4 acc[2][2] = {};

  const int kqA = (tid & 15) * 4, r0A = tid >> 4;
  const int kqB = (tid & 7) * 8,  r0B = tid >> 3;

  for (int k0 = 0; k0 < DD; k0 += 64) {
    __syncthreads();
    #pragma unroll
    for (int i = 0; i < 4; i++) {
      int m = bm + r0A + 16 * i;
      float4 av = *(const float4*)(A + (long)m * DD + k0 + kqA);
      short4v ap = { (short)f2bf(av.x), (short)f2bf(av.y), (short)f2bf(av.z), (short)f2bf(av.w) };
      *(short4v*)(&A_lds[r0A + 16 * i][kqA]) = ap;
    }
    #pragma unroll
    for (int i = 0; i < 2; i++) {
      int n = bn + r0B + 32 * i;
      bf16x8 bv = *(const bf16x8*)(WT2 + (long)n * DD + k0 + kqB);
      *(bf16x8*)(&B_lds[r0B + 32 * i][kqB]) = bv;
    }
    __syncthreads();
    #pragma unroll
    for (int ks = 0; ks < 2; ks++) {
      bf16x8 af[2], bfr[2];
      #pragma unroll
      for (int fm = 0; fm < 2; fm++)
        af[fm] = *(const bf16x8*)(&A_lds[wm + fm * 16 + li][ks * 32 + lg * 8]);
      #pragma unroll
      for (int fn = 0; fn < 2; fn++)
        bfr[fn] = *(const bf16x8*)(&B_lds[wn + fn * 16 + li][ks * 32 + lg * 8]);
      #pragma unroll
      for (int fm = 0; fm < 2; fm++)
        #pragma unroll
        for (int fn = 0; fn < 2; fn++)
          acc[fm][fn] = __builtin_amdgcn_mfma_f32_16x16x32_bf16(af[fm], bfr[fn], acc[fm][fn], 0, 0, 0);
    }
  }
  #pragma unroll
  for (int fm = 0; fm < 2; fm++) {
    #pragma unroll
    for (int fn = 0; fn < 2; fn++) {
      int n = bn + wn + fn * 16 + li;
      if (n < 512) {
        float bv = bdt[n];
        #pragma unroll
        for (int r = 0; r < 4; r++) {
          int m = bm + wm + fm * 16 + 4 * lg + r;
          dtv[(long)m * DD + n] = softplusf(acc[fm][fn][r] + bv);
        }
      } else if (n < 544) {
        #pragma unroll
        for (int r = 0; r < 4; r++) {
          int m = bm + wm + fm * 16 + 4 * lg + r;
          bc[(long)m * 32 + (n - 512)] = acc[fm][fn][r];
        }
      }
    }
  }
}

// ---------------------------------------------------------------- conv + SiLU
__global__ __launch_bounds__(256) void conv_silu_kernel(
    const float* __restrict__ xz, const float* __restrict__ cw, const float* __restrict__ cb,
    float* __restrict__ xc, int layer)
{
  long idx = (long)blockIdx.x * 256 + threadIdx.x;  // (g,b,t,c)
  int c = idx % DD;
  long r = idx / DD;
  int t = r % SEQL;
  long gb = r / SEQL;
  int g = (int)(gb / BB);
  const float* w = cw + ((long)(layer * 2 + g) * DD + c) * KCC;
  float acc = cb[(long)(layer * 2 + g) * DD + c];
  const float* xp = xz + (r - t) * 2 * DD + c;
  #pragma unroll
  for (int k = 0; k < KCC; k++) {
    int tt = t - (KCC - 1) + k;
    if (tt >= 0) acc = fmaf(xp[(long)tt * 2 * DD], w[k], acc);
  }
  xc[idx] = siluf(acc);
}

// ---------------------------------------------------------------- chunked scan (8 states/thread)
__global__ __launch_bounds__(256) void scan_chunk_kernel(
    const float* __restrict__ dtv, const float* __restrict__ xc,
    const float* __restrict__ bc, const float* __restrict__ Alog,
    float* __restrict__ P, float* __restrict__ Hend, int layer)
{
  int chunk = blockIdx.x, dtile = blockIdx.y, gb = blockIdx.z;
  int g = gb / BB;
  int tid = threadIdx.x;
  int dl = tid >> 1, nh = (tid & 1) * 8;
  int d = dtile * 128 + dl;
  int t0 = chunk * TC;
  __shared__ float dtv_s[TC][128], xc_s[TC][128], BC_s[TC][32];
  {
    long base = ((long)gb * SEQL + t0) * DD + dtile * 128;
    int c4 = (tid & 31) * 4, r0 = tid >> 5;
    #pragma unroll
    for (int i = 0; i < 4; i++) {
      int tl = r0 + i * 8;
      *(float4*)&dtv_s[tl][c4] = *(const float4*)(dtv + base + (long)tl * DD + c4);
      *(float4*)&xc_s[tl][c4]  = *(const float4*)(xc + base + (long)tl * DD + c4);
    }
    long dbase = ((long)gb * SEQL + t0) * 32;
    int cc = (tid & 7) * 4, rr = tid >> 3;
    *(float4*)&BC_s[rr][cc] = *(const float4*)(bc + dbase + (long)rr * 32 + cc);
  }
  __syncthreads();
  const float* Al = Alog + ((long)((layer * 2 + g) * DD) + d) * NN + nh;
  float a[8], h[8] = {};
  #pragma unroll
  for (int n = 0; n < 8; n++) a[n] = -__expf(Al[n]);
  float sdt = 0.f;
  for (int t = 0; t < TC; t++) {
    float dt = dtv_s[t][dl];
    float dx = dt * xc_s[t][dl];
    float4 b0 = *(const float4*)&BC_s[t][nh];
    float4 b1 = *(const float4*)&BC_s[t][nh + 4];
    h[0] = fmaf(__expf(dt * a[0]), h[0], dx * b0.x);
    h[1] = fmaf(__expf(dt * a[1]), h[1], dx * b0.y);
    h[2] = fmaf(__expf(dt * a[2]), h[2], dx * b0.z);
    h[3] = fmaf(__expf(dt * a[3]), h[3], dx * b0.w);
    h[4] = fmaf(__expf(dt * a[4]), h[4], dx * b1.x);
    h[5] = fmaf(__expf(dt * a[5]), h[5], dx * b1.y);
    h[6] = fmaf(__expf(dt * a[6]), h[6], dx * b1.z);
    h[7] = fmaf(__expf(dt * a[7]), h[7], dx * b1.w);
    sdt += dt;
  }
  long o = (long)chunk * NR + ((long)(gb * DD + d)) * NN + nh;
  #pragma unroll
  for (int n = 0; n < 8; n++) {
    P[o + n] = __expf(a[n] * sdt);
    Hend[o + n] = h[n];
  }
}

__global__ __launch_bounds__(256) void scan_combine_kernel(
    const float* __restrict__ P, const float* __restrict__ Hend, float* __restrict__ Hin)
{
  int r = blockIdx.x * 256 + threadIdx.x;
  float h = 0.f;
  #pragma unroll
  for (int c = 0; c < NC; c++) {
    Hin[(long)c * NR + r] = h;
    h = fmaf(P[(long)c * NR + r], h, Hend[(long)c * NR + r]);
  }
}

// ---------------------------------------------------------------- scan apply (8 states/thread)
__global__ __launch_bounds__(256) void scan_apply_kernel(
    const float* __restrict__ dtv, const float* __restrict__ xc, const float* __restrict__ xz,
    const float* __restrict__ bc, const float* __restrict__ Alog, const float* __restrict__ Dp,
    const float* __restrict__ Hin, float* __restrict__ ym, int layer)
{
  int chunk = blockIdx.x, dtile = blockIdx.y, gb = blockIdx.z;
  int g = gb / BB;
  int tid = threadIdx.x;
  int dl = tid >> 1, nh = (tid & 1) * 8;
  int d = dtile * 128 + dl;
  int t0 = chunk * TC;
  __shared__ float dtv_s[TC][128], xc_s[TC][128], BC_s[TC][32], y_s[TC][128];
  {
    long base = ((long)gb * SEQL + t0) * DD + dtile * 128;
    int c4 = (tid & 31) * 4, r0 = tid >> 5;
    #pragma unroll
    for (int i = 0; i < 4; i++) {
      int tl = r0 + i * 8;
      *(float4*)&dtv_s[tl][c4] = *(const float4*)(dtv + base + (long)tl * DD + c4);
      *(float4*)&xc_s[tl][c4]  = *(const float4*)(xc + base + (long)tl * DD + c4);
    }
    long dbase = ((long)gb * SEQL + t0) * 32;
    int cc = (tid & 7) * 4, rr = tid >> 3;
    *(float4*)&BC_s[rr][cc] = *(const float4*)(bc + dbase + (long)rr * 32 + cc);
  }
  __syncthreads();
  const float* Al = Alog + ((long)((layer * 2 + g) * DD) + d) * NN + nh;
  float a[8], h[8];
  #pragma unroll
  for (int n = 0; n < 8; n++) a[n] = -__expf(Al[n]);
  {
    long r = (long)chunk * NR + ((long)(gb * DD + d)) * NN + nh;
    float4 h0 = *(const float4*)(Hin + r);
    float4 h1 = *(const float4*)(Hin + r + 4);
    h[0]=h0.x; h[1]=h0.y; h[2]=h0.z; h[3]=h0.w;
    h[4]=h1.x; h[5]=h1.y; h[6]=h1.z; h[7]=h1.w;
  }
  for (int t = 0; t < TC; t++) {
    float dt = dtv_s[t][dl];
    float dx = dt * xc_s[t][dl];
    float4 b0 = *(const float4*)&BC_s[t][nh];
    float4 b1 = *(const float4*)&BC_s[t][nh + 4];
    float4 c0 = *(const float4*)&BC_s[t][16 + nh];
    float4 c1 = *(const float4*)&BC_s[t][16 + nh + 4];
    h[0] = fmaf(__expf(dt * a[0]), h[0], dx * b0.x);
    h[1] = fmaf(__expf(dt * a[1]), h[1], dx * b0.y);
    h[2] = fmaf(__expf(dt * a[2]), h[2], dx * b0.z);
    h[3] = fmaf(__expf(dt * a[3]), h[3], dx * b0.w);
    h[4] = fmaf(__expf(dt * a[4]), h[4], dx * b1.x);
    h[5] = fmaf(__expf(dt * a[5]), h[5], dx * b1.y);
    h[6] = fmaf(__expf(dt * a[6]), h[6], dx * b1.z);
    h[7] = fmaf(__expf(dt * a[7]), h[7], dx * b1.w);
    float v0 = h[0] * c0.x + h[1] * c0.y;
    float v1 = h[2] * c0.z + h[3] * c0.w;
    float v2 = h[4] * c1.x + h[5] * c1.y;
    float v3 = h[6] * c1.z + h[7] * c1.w;
    float val = (v0 + v1) + (v2 + v3);
    val += __shfl_xor(val, 1);
    if ((tid & 1) == 0) y_s[t][dl] = val;
  }
  __syncthreads();
  {
    long base = ((long)gb * SEQL + t0) * DD + dtile * 128;
    long zbase = ((long)gb * SEQL + t0) * 2 * DD + DD + dtile * 128;
    int c4 = (tid & 31) * 4, r0 = tid >> 5;
    float4 Dp4 = *(const float4*)(Dp + (long)(layer * 2 + g) * DD + dtile * 128 + c4);
    #pragma unroll
    for (int i = 0; i < 4; i++) {
      int tl = r0 + i * 8;
      float4 y4 = *(const float4*)&y_s[tl][c4];
      float4 x4 = *(const float4*)&xc_s[tl][c4];
      float4 z4 = *(const float4*)(xz + zbase + (long)tl * 2 * DD + c4);
      float4 o;
      o.x = (y4.x + Dp4.x * x4.x) * siluf(z4.x);
      o.y = (y4.y + Dp4.y * x4.y) * siluf(z4.y);
      o.z = (y4.z + Dp4.z * x4.z) * siluf(z4.z);
      o.w = (y4.w + Dp4.w * x4.w) * siluf(z4.w);
      *(float4*)(ym + base + (long)tl * DD + c4) = o;
    }
  }
}

// ---------------------------------------------------------------- bias index table
__global__ void tab_kernel(unsigned short* __restrict__ tab)
{
  int idx = blockIdx.x * blockDim.x + threadIdx.x;
  if (idx >= 2047) return;
  int di = idx - 1023;
  int ad = di < 0 ? -di : di;
  float pr = expf(logf((SEQL + 1) * 0.5f) / 16.0f);
  int n0 = 16;
  for (int n = 15; n >= 0; n--) {
    float cw = powf(pr, (float)(n + 1));
    if ((float)ad <= cw) n0 = n;
  }
  tab[idx] = (unsigned short)(di == 0 ? 34 : (di < 0 ? n0 : 17 + n0));
}

// ---------------------------------------------------------------- qw suffix (dense)
__global__ __launch_bounds__(256) void qw_kernel(
    const float* __restrict__ q, const float* __restrict__ w_rel, float* __restrict__ S, int layer)
{
  int itile = blockIdx.x;
  int bh = blockIdx.y;
  int h = bh % HH, b = bh / HH;
  int i0 = itile * 64;
  __shared__ float q_s[64][65];
  __shared__ float w_s[64][33];
  __shared__ float qwn[64][33];
  int tid = threadIdx.x;
  {
    int r = tid >> 2, c4 = (tid & 3) * 16;
    const float* qr = q + ((long)(b * SEQL + i0 + r)) * DD + h * 64 + c4;
    #pragma unroll
    for (int e = 0; e < 4; e++) {
      float4 v = *(const float4*)(qr + e * 4);
      q_s[r][c4 + e * 4 + 0] = v.x; q_s[r][c4 + e * 4 + 1] = v.y;
      q_s[r][c4 + e * 4 + 2] = v.z; q_s[r][c4 + e * 4 + 3] = v.w;
    }
  }
  for (int idx = tid; idx < 64 * 32; idx += 256) {
    int d = idx >> 5, n = idx & 31;
    w_s[d][n] = w_rel[((long)(layer * HH + h) * DHH + d) * PPB + n];
  }
  __syncthreads();
  {
    int i = tid & 63, ngrp = tid >> 6;
    float acc[8] = {};
    #pragma unroll 8
    for (int d = 0; d < 64; d++) {
      float qv = q_s[i][d];
      #pragma unroll
      for (int e = 0; e < 8; e++) acc[e] = fmaf(qv, w_s[d][ngrp * 8 + e], acc[e]);
    }
    #pragma unroll
    for (int e = 0; e < 8; e++) qwn[i][ngrp * 8 + e] = acc[e];
  }
  __syncthreads();
  for (int idx = tid; idx < 64 * 17; idx += 256) {
    int il = idx / 17, m = idx % 17;
    float s1 = 0.f, s2 = 0.f;
    for (int n = m; n < 16; n++) { s1 += qwn[il][n]; s2 += qwn[il][16 + n]; }
    float* Sp = S + ((long)bh * SEQL + i0 + il) * 34;
    Sp[m] = s1;
    Sp[17 + m] = s2;
  }
}

__global__ __launch_bounds__(256) void vw_kernel(
    const float* __restrict__ vparam, const float* __restrict__ w_rel, float* __restrict__ VS)
{
  int layer = blockIdx.x;
  __shared__ float vws[HH][PPB];
  int tid = threadIdx.x;
  int h = tid / PPB, n = tid % PPB;
  const float* vp = vparam + (long)(layer * HH + h) * DHH;
  const float* wp = w_rel + ((long)(layer * HH + h) * DHH) * PPB + n;
  float s = 0.f;
  for (int d = 0; d < DHH; d++) s = fmaf(vp[d], wp[d * PPB], s);
  vws[h][n] = s;
  __syncthreads();
  if (tid < HH * 17) {
    int hh = tid / 17, m = tid % 17;
    float s1 = 0.f, s2 = 0.f;
    for (int nn = m; nn < 16; nn++) { s1 += vws[hh][nn]; s2 += vws[hh][16 + nn]; }
    VS[layer * 272 + hh * 34 + m] = s1;
    VS[layer * 272 + hh * 34 + 17 + m] = s2;
  }
}

__global__ __launch_bounds__(256) void uk_kernel(
    const float* __restrict__ u, const float* __restrict__ k, float* __restrict__ uk, int layer)
{
  int wid = (blockIdx.x * 256 + threadIdx.x) >> 6;
  int lane = threadIdx.x & 63;
  if (wid >= BB * HH * SEQL) return;
  int j = wid % SEQL;
  int bh = wid / SEQL;
  int h = bh % HH;
  int b = bh / HH;
  float vv = u[(long)(layer * HH + h) * DHH + lane] * k[((long)(b * SEQL + j) * HH + h) * DHH + lane];
  for (int o = 32; o; o >>= 1) vv += __shfl_down(vv, o);
  if (lane == 0) uk[(long)bh * SEQL + j] = vv;
}

// ---------------------------------------------------------------- MFMA attention (split-KV)
__global__ __launch_bounds__(256) void attn_mfma_kernel(
    const float* __restrict__ q, const float* __restrict__ k, const float* __restrict__ vv,
    const float* __restrict__ S, const float* __restrict__ VS, const float* __restrict__ uk,
    const unsigned short* __restrict__ tab,
    float* __restrict__ opart, float* __restrict__ mbuf, float* __restrict__ lbuf)
{
  __shared__ __align__(16) char smem[39680];
  unsigned short* K_lds  = (unsigned short*)(smem);
  unsigned short* VT_lds = (unsigned short*)(smem + 8704);
  unsigned short* PT_lds = (unsigned short*)(smem + 17408);
  float* E               = (float*)(smem + 26112);
  unsigned short* tab_s  = (unsigned short*)(smem + 35328);
  float* uk_s            = (float*)(smem + 39424);
  float* O_lds           = (float*)(smem);

  int itile = blockIdx.x;
  int bh = blockIdx.y;
  int split = blockIdx.z;
  int h = bh % HH, b = bh / HH;
  int i0 = itile * 64;
  int tid = threadIdx.x;
  int w = tid >> 6;
  int lane = tid & 63;
  int li = lane & 15, lg = lane >> 4;

  for (int idx = tid; idx < 64 * 17; idx += 256) {
    int il = idx / 17, m = idx % 17;
    long srow = ((long)bh * SEQL + i0 + il) * 34;
    float c0 = S[srow + m]      + VS[h * 34 + m];
    float c1 = S[srow + 17 + m] + VS[h * 34 + 17 + m];
    E[il * 36 + m]      = c0 - c1;
    E[il * 36 + 17 + m] = c0 + c1;
    if (m == 0) E[il * 36 + 34] = c0;
  }
  for (int idx = tid; idx < 2047; idx += 256) tab_s[idx] = tab[idx];

  int iq = i0 + w * 16 + li;
  const float* qrow = q + ((long)(b * SEQL + iq)) * DD + h * 64;
  bf16x8 qf0 = pack8(qrow + 8 * lg);
  bf16x8 qf1 = pack8(qrow + 32 + 8 * lg);

  f32x4 oacc[4] = {};
  float mrun = -1e30f, lrun = 0.f;
  const int ibase = i0 + w * 16 + li;
  unsigned short* PTw = PT_lds + w * 16 * 68;
  const float* Erow = E + (w * 16 + li) * 36;

  const int jbase = split * (SEQL / 2);
  for (int jt = 0; jt < SEQL / 2; jt += 64) {
    int j0 = jbase + jt;
    __syncthreads();
    {
      int jl = tid >> 4;
      int dq = (tid & 15) * 4;
      #pragma unroll
      for (int rr = 0; rr < 4; rr++) {
        int jj = jl + rr * 16;
        long grow = ((long)(b * SEQL + j0 + jj)) * DD + h * 64 + dq;
        float4 kv = *(const float4*)(k + grow);
        short4v kp = { (short)f2bf(kv.x), (short)f2bf(kv.y), (short)f2bf(kv.z), (short)f2bf(kv.w) };
        *(short4v*)(K_lds + jj * 68 + dq) = kp;
        float4 vvv = *(const float4*)(vv + grow);
        VT_lds[(dq + 0) * 68 + jj] = f2bf(vvv.x);
        VT_lds[(dq + 1) * 68 + jj] = f2bf(vvv.y);
        VT_lds[(dq + 2) * 68 + jj] = f2bf(vvv.z);
        VT_lds[(dq + 3) * 68 + jj] = f2bf(vvv.w);
      }
      if (tid < 64) uk_s[tid] = uk[(long)bh * SEQL + j0 + tid];
    }
    __syncthreads();

    f32x4 sf[4];
    #pragma unroll
    for (int jj = 0; jj < 4; jj++) {
      f32x4 c = {};
      c = __builtin_amdgcn_mfma_f32_16x16x32_bf16(
            ld_frag(K_lds + (jj * 16 + li) * 68 + 8 * lg), qf0, c, 0, 0, 0);
      c = __builtin_amdgcn_mfma_f32_16x16x32_bf16(
            ld_frag(K_lds + (jj * 16 + li) * 68 + 32 + 8 * lg), qf1, c, 0, 0, 0);
      sf[jj] = c;
    }

    float sv[4][4];
    float tmax = -1e30f;
    #pragma unroll
    for (int jj = 0; jj < 4; jj++) {
      #pragma unroll
      for (int r = 0; r < 4; r++) {
        int jloc = jj * 16 + 4 * lg + r;
        int di = (j0 + jloc) - ibase;
        int id = tab_s[1023 + di];
        float val = (sf[jj][r] + Erow[id] + uk_s[jloc]) * 0.125f;
        sv[jj][r] = val;
        tmax = fmaxf(tmax, val);
      }
    }
    tmax = fmaxf(tmax, __shfl_xor(tmax, 16));
    tmax = fmaxf(tmax, __shfl_xor(tmax, 32));
    float mnew = fmaxf(mrun, tmax);
    float fsc = __expf(mrun - mnew);
    mrun = mnew;
    lrun *= fsc;
    #pragma unroll
    for (int df = 0; df < 4; df++) oacc[df] *= fsc;

    float psum = 0.f;
    #pragma unroll
    for (int jj = 0; jj < 4; jj++) {
      short4v pk;
      #pragma unroll
      for (int r = 0; r < 4; r++) {
        float p = __expf(sv[jj][r] - mnew);
        psum += p;
        pk[r] = (short)f2bf(p);
      }
      *(short4v*)(PTw + li * 68 + jj * 16 + 4 * lg) = pk;
    }
    psum += __shfl_xor(psum, 16);
    psum += __shfl_xor(psum, 32);
    lrun += psum;

    asm volatile("s_waitcnt lgkmcnt(0)" ::: "memory");

    bf16x8 pf0 = ld_frag(PTw + li * 68 + 8 * lg);
    bf16x8 pf1 = ld_frag(PTw + li * 68 + 32 + 8 * lg);
    #pragma unroll
    for (int df = 0; df < 4; df++) {
      f32x4 c = oacc[df];
      c = __builtin_amdgcn_mfma_f32_16x16x32_bf16(
            ld_frag(VT_lds + (df * 16 + li) * 68 + 8 * lg), pf0, c, 0, 0, 0);
      c = __builtin_amdgcn_mfma_f32_16x16x32_bf16(
            ld_frag(VT_lds + (df * 16 + li) * 68 + 32 + 8 * lg), pf1, c, 0, 0, 0);
      oacc[df] = c;
    }
  }

  __syncthreads();
  if (lg == 0) {
    long row = (long)split * BHN + (long)bh * SEQL + (i0 + w * 16 + li);
    mbuf[row] = mrun;
    lbuf[row] = lrun;
  }
  #pragma unroll
  for (int df = 0; df < 4; df++)
    *(f32x4*)(O_lds + (w * 16 + li) * 68 + df * 16 + 4 * lg) = oacc[df];
  __syncthreads();
  {
    int il = tid >> 2, c0 = (tid & 3) * 16;
    long orow = ((long)split * BHN + (long)bh * SEQL + i0 + il) * 64 + c0;
    #pragma unroll
    for (int c4 = 0; c4 < 4; c4++) {
      f32x4 o = *(const f32x4*)(O_lds + il * 68 + c0 + c4 * 4);
      *(f32x4*)(opart + orow + c4 * 4) = o;
    }
  }
}

// ---------------------------------------------------------------- launch
extern "C" void kernel_launch(void* const* d_in, const int* in_sizes, int n_in,
                              void* d_out, int out_size, void* d_ws, size_t ws_size,
                              hipStream_t stream) {
  const float* x_in     = (const float*)d_in[0];
  const float* rms_m    = (const float*)d_in[1];
  const float* W_in     = (const float*)d_in[2];
  const float* b_in     = (const float*)d_in[3];
  const float* m_Win    = (const float*)d_in[4];
  const float* m_conv_w = (const float*)d_in[5];
  const float* m_conv_b = (const float*)d_in[6];
  const float* m_Wx     = (const float*)d_in[7];
  const float* m_Wdt    = (const float*)d_in[8];
  const float* m_bdt    = (const float*)d_in[9];
  const float* m_Alog   = (const float*)d_in[10];
  const float* m_Dp     = (const float*)d_in[11];
  const float* m_Wout   = (const float*)d_in[12];
  const float* W_out    = (const float*)d_in[13];
  const float* b_out    = (const float*)d_in[14];
  const float* rms_a    = (const float*)d_in[15];
  const float* Wq       = (const float*)d_in[16];
  const float* Wk       = (const float*)d_in[17];
  const float* Wv       = (const float*)d_in[18];
  const float* u_p      = (const float*)d_in[19];
  const float* v_p      = (const float*)d_in[20];
  const float* w_rel    = (const float*)d_in[21];
  const float* Wo       = (const float*)d_in[22];
  const float* b_o      = (const float*)d_in[23];
  float* out = (float*)d_out;

  float* ws = (float*)d_ws;
  const long U = (long)BB * SEQL * DD;      // 1,048,576 floats
  float* xA    = ws;
  float* xB    = ws + 1 * U;                // also scan Hend scratch (dead during scan)
  float* xn    = ws + 2 * U;                // scan P scratch
  float* proj  = ws + 3 * U;                // 3U; later q,k,v
  float* xz    = ws + 6 * U;                // 4U; later yp (2U)
  float* xc    = ws + 10 * U;               // 2U; attn Opart scratch
  float* dtv   = ws + 12 * U;               // 2U; attn m/l scratch
  float* ym    = ws + 14 * U;               // 2U
  float* ycomb = ws + 16 * U;               // 1U; scan Hin scratch
  float* smallb= ws + 17 * U;               // 1U of small buffers
  float* bcbuf = smallb;                    // 131072
  float* ukbuf = smallb + 262144;           // 16384
  float* Sbuf  = smallb + 278528;           // 557056
  float* VSbuf = smallb + 835584;           // 2*272
  unsigned short* tabg = (unsigned short*)(smallb + 836880);  // 2047 u16
  float* invm  = smallb + 838928;           // 2048
  float* inva  = smallb + 840976;           // 2048
  unsigned short* WTA = (unsigned short*)(ws + 18 * U);       // 2 * AR_L shorts
  float* yp = xz;
  float* qb = proj;
  float* kb = proj + U;
  float* vb = proj + 2 * U;
  float* Pbuf = xn;                         // NC*NR = 1U
  float* Hend = xB;                         // 1U (xB dead during scan)
  float* Hin  = ycomb;                      // 1U
  float* opart = xc;                        // 2*BHN*64 = 2U
  float* mbuf  = dtv;                       // 2*BHN
  float* lbuf  = dtv + 2 * BHN;             // 2*BHN

  const int M = BB * SEQL;                  // 2048

  // ---- preamble: bias table + all weight preprocessing ----
  tab_kernel<<<8, 256, 0, stream>>>(tabg);

  TDs td;
  int cum = 0, idx = 0;
  auto add = [&](const float* s, unsigned short* dst, int ldsrc, int K, int N) {
    td.a[idx].src = s; td.a[idx].dst = dst; td.a[idx].ldsrc = ldsrc;
    td.a[idx].K = K; td.a[idx].N = N; td.a[idx].t0 = cum;
    cum += (N / 32) * (K / 32); idx++;
  };
  for (int l = 0; l < LL; l++) {
    unsigned short* base = WTA + (long)l * AR_L;
    add(W_in   + (long)l * DD * 3 * DD,        base + OFF_WIN,            3 * DD, DD, 3 * DD);
    add(m_Win  + (long)(l * 2 + 0) * DD * 2 * DD, base + OFF_MWIN,          2 * DD, DD, 2 * DD);
    add(m_Win  + (long)(l * 2 + 1) * DD * 2 * DD, base + OFF_MWIN + 524288, 2 * DD, DD, 2 * DD);
    add(m_Wout + (long)(l * 2 + 0) * DD * DD,  base + OFF_MWOUT,          DD, DD, DD);
    add(m_Wout + (long)(l * 2 + 1) * DD * DD,  base + OFF_MWOUT + 262144, DD, DD, DD);
    add(W_out  + (long)l * DD * DD,            base + OFF_WOUT,           DD, DD, DD);
    add(Wq     + (long)l * DD * DD,            base + OFF_QKV,            DD, DD, DD);
    add(Wk     + (long)l * DD * DD,            base + OFF_QKV + 262144,   DD, DD, DD);
    add(Wv     + (long)l * DD * DD,            base + OFF_QKV + 524288,   DD, DD, DD);
    add(Wo     + (long)l * DD * DD,            base + OFF_WO,             DD, DD, DD);
    add(m_Wx   + (long)(l * 2 + 0) * DD * 64 + 32, base + OFF_WT2 + 262144,          64, DD, 32);
    add(m_Wx   + (long)(l * 2 + 1) * DD * 64 + 32, base + OFF_WT2 + 327680 + 262144, 64, DD, 32);
  }
  wtrans_all<<<cum, 256, 0, stream>>>(td);
  weff_kernel<<<dim3(16, 16, 2 * LL), 256, 0, stream>>>(m_Wx, m_Wdt, WTA);
  vw_kernel<<<LL, 256, 0, stream>>>(v_p, w_rel, VSbuf);

  for (int layer = 0; layer < LL; layer++) {
    const float* cur = (layer == 0) ? x_in : xA;
    unsigned short* base = WTA + (long)layer * AR_L;
    // ---- mamba block ----
    rmsinv_kernel<<<M / 4, 256, 0, stream>>>(cur, invm);
    gemm_bf16_t<64, 64><<<dim3(24, 32, 1), 256, 0, stream>>>(cur, base + OFF_WIN,
        b_in + layer * 3 * DD, nullptr, invm, rms_m + layer * DD, proj,
        M, 3 * DD, DD, DD, 3 * DD, 0, 0, 0, 0, 0, 0);
    gemm_bf16_t<64, 64><<<dim3(16, 32, 2), 256, 0, stream>>>(proj, base + OFF_MWIN,
        nullptr, nullptr, nullptr, nullptr, xz, M, 2 * DD, DD, 3 * DD, 2 * DD,
        0, 524288, 0, (long)BB * SEQL * 2 * DD, SEQL, 0);
    conv_silu_kernel<<<(2 * BB * SEQL * DD) / 256, 256, 0, stream>>>(xz, m_conv_w, m_conv_b, xc, layer);
    gemm_dtbc<<<dim3(9, 32, 2), 256, 0, stream>>>(xc, base + OFF_WT2, m_bdt, dtv, bcbuf, layer);
    scan_chunk_kernel<<<dim3(NC, DD / 128, GBS), 256, 0, stream>>>(
        dtv, xc, bcbuf, m_Alog, Pbuf, Hend, layer);
    scan_combine_kernel<<<NR / 256, 256, 0, stream>>>(Pbuf, Hend, Hin);
    scan_apply_kernel<<<dim3(NC, DD / 128, GBS), 256, 0, stream>>>(
        dtv, xc, xz, bcbuf, m_Alog, m_Dp, Hin, ym, layer);
    gemm_bf16_t<64, 64><<<dim3(8, 32, 2), 256, 0, stream>>>(ym, base + OFF_MWOUT,
        nullptr, nullptr, nullptr, nullptr, yp, M, DD, DD, DD, DD,
        U, 262144, 0, U, 0, 0);
    gemm_comb<<<dim3(8, 32), 256, 0, stream>>>(yp, proj, base + OFF_WOUT,
        b_out + layer * DD, cur, xB);

    // ---- attention block ----
    rmsinv_kernel<<<M / 4, 256, 0, stream>>>(xB, inva);
    gemm_bf16_t<64, 64><<<dim3(8, 32, 3), 256, 0, stream>>>(xB, base + OFF_QKV,
        nullptr, nullptr, inva, rms_a + layer * DD, qb, M, DD, DD, DD, DD,
        0, 262144, 0, U, 0, 0);
    qw_kernel<<<dim3(16, 16), 256, 0, stream>>>(qb, w_rel, Sbuf, layer);
    uk_kernel<<<(BB * HH * SEQL) / 4, 256, 0, stream>>>(u_p, kb, ukbuf, layer);
    attn_mfma_kernel<<<dim3(SEQL / 64, BB * HH, 2), 256, 0, stream>>>(
        qb, kb, vb, Sbuf, VSbuf + layer * 272, ukbuf, tabg, opart, mbuf, lbuf);

    float* outp = (layer == LL - 1) ? out : xA;
    gemm_attn<<<dim3(8, 32), 256, 0, stream>>>(opart, mbuf, lbuf, base + OFF_WO,
        b_o + layer * DD, xB, outp);
  }
}